// Round 4
// baseline (875.380 us; speedup 1.0000x reference)
//
#include <hip/hip_runtime.h>
#include <math.h>

#define L 4096
#define LDD 4488            // padded D stride (66 groups x 68)
#define LDP 4544            // padded fp16 K stride (71*64), 16B-aligned rows
#define RPAD 4488

typedef _Float16 f16x8 __attribute__((ext_vector_type(8)));
typedef _Float16 f16x2 __attribute__((ext_vector_type(2)));
typedef float    f32x4 __attribute__((ext_vector_type(4)));

__device__ __forceinline__ float wave_max(float v){
  #pragma unroll
  for(int o=32;o;o>>=1) v = fmaxf(v, __shfl_xor(v,o));
  return v;
}
__device__ __forceinline__ float wave_sum(float v){
  #pragma unroll
  for(int o=32;o;o>>=1) v += __shfl_xor(v,o);
  return v;
}
__device__ __forceinline__ void gload16(const void* g, void* l){
  __builtin_amdgcn_global_load_lds((const __attribute__((address_space(1))) unsigned int*)g,
                                   (__attribute__((address_space(3))) unsigned int*)l,
                                   16, 0, 0);
}
__device__ __forceinline__ int pmap(int i){ return ((i>>6)*68) + (i&63) + 70; }

// ---------------- zero helpers ----------------
__global__ __launch_bounds__(256) void zero_f16k(_Float16* p, size_t n){
  size_t i = (size_t)blockIdx.x*256 + threadIdx.x; if(i<n) p[i] = (_Float16)0.f;
}
__global__ __launch_bounds__(256) void zero_f32k(float* p, size_t n){
  size_t i = (size_t)blockIdx.x*256 + threadIdx.x; if(i<n) p[i] = 0.f;
}
__device__ __forceinline__ int padrow_id(int k){
  if(k < 68) return k;                    // y=-1 halo group
  if(k < 136) return 4420 + (k-68);       // y=64 halo group
  const int k2 = k - 136;
  const int g = (k2>>2) + 1;
  const int us4[4] = {0,1,66,67};
  return g*68 + us4[k2&3];
}
__global__ __launch_bounds__(256) void zero_pad_rows(_Float16* p, size_t zs, int ld){
  const int c = blockIdx.x*256 + threadIdx.x; if(c>=ld) return;
  const int r = padrow_id(blockIdx.y);
  p[(size_t)blockIdx.z*zs + (size_t)r*ld + c] = (_Float16)0.f;
}
__global__ __launch_bounds__(256) void zero_pad_cols(_Float16* p, size_t zs, int ld){
  const int q = blockIdx.x*256 + threadIdx.x; if(q>=4096) return;
  const int r = pmap(q);
  const int c = padrow_id(blockIdx.y);
  p[(size_t)blockIdx.z*zs + (size_t)r*ld + c] = (_Float16)0.f;
}

// ---------------- prep1: transposes + per-pixel stats ----------------
__global__ __launch_bounds__(256) void prep1(const float* __restrict__ fg,
                                             const float* __restrict__ mask,
                                             _Float16* __restrict__ fgT16,
                                             _Float16* __restrict__ bgT16,
                                             _Float16* __restrict__ bg16,
                                             _Float16* __restrict__ bg16p,
                                             float* __restrict__ nsq,
                                             float* __restrict__ sfg,
                                             float* __restrict__ rn1){
  __shared__ float tile[64][65];
  __shared__ float msh[64];
  const int z = blockIdx.y, s0 = blockIdx.x*64, t = threadIdx.x;
  const float* fgz = fg + (size_t)z*64*L;
  if(t<64) msh[t] = mask[(size_t)z*L + s0 + t];
  #pragma unroll
  for(int i=0;i<16;i++){
    const int c = i*4 + (t>>6), s = t&63;
    tile[c][s] = fgz[(size_t)c*L + s0 + s];
  }
  __syncthreads();
  #pragma unroll
  for(int i=0;i<16;i++){
    const int c = i*4 + (t>>6), s = t&63;
    const float b = tile[c][s]*(1.0f - msh[s]);
    bg16[((size_t)z*128 + c)*L + s0 + s] = (_Float16)b;
    const int l = s0+s;
    bg16p[((size_t)z*128 + c)*LDP + pmap(l)] = (_Float16)b;
  }
  #pragma unroll
  for(int i=0;i<16;i++){
    const int s = i*4 + (t>>6), c = t&63;
    const float f = tile[c][s];
    const float b = f*(1.0f - msh[s]);
    fgT16[((size_t)z*L + s0+s)*64 + c] = (_Float16)f;
    bgT16[((size_t)z*L + s0+s)*64 + c] = (_Float16)b;
    const float bp = b + 1e-7f;
    const float ns = wave_sum(bp*bp);
    const float sf = wave_sum(f);
    if(c==0){
      nsq[(size_t)z*L + s0+s] = ns;
      sfg[(size_t)z*L + s0+s] = sf;
      rn1[(size_t)z*L + s0+s] = rsqrtf(ns);
    }
  }
}

// ---------------- prep2: rn3 / sfg9 / allm3 ----------------
__global__ __launch_bounds__(256) void prep2(const float* __restrict__ nsq,
                                             const float* __restrict__ sfg,
                                             const float* __restrict__ mask,
                                             float* __restrict__ rn3,
                                             float* __restrict__ sfg9,
                                             float* __restrict__ allm3){
  const int idx = blockIdx.x*256 + threadIdx.x;
  const int z = idx>>12, l = idx&4095;
  const int y = l>>6, x = l&63;
  const float* nz = nsq + (size_t)z*L;
  const float* sz = sfg + (size_t)z*L;
  const float* mz = mask + (size_t)z*L;
  float ns = 0.f, s9 = 0.f, allm = 1.f;
  #pragma unroll
  for(int di=-1;di<=1;di++)
    #pragma unroll
    for(int dj=-1;dj<=1;dj++){
      const int yy=y+di, xx=x+dj;
      if(yy>=0&&yy<64&&xx>=0&&xx<64){
        const int ll = yy*64+xx;
        ns += nz[ll]; s9 += sz[ll];
        if(mz[ll] < 0.5f) allm = 0.f;
      } else ns += 6.4e-13f;   // 64 * (1e-7)^2 per OOB slot
    }
  rn3[idx] = rsqrtf(ns);
  sfg9[idx] = s9;
  allm3[idx] = allm;
}
__global__ __launch_bounds__(256) void prep2b(const float* __restrict__ sfg9,
                                              float* __restrict__ sfg81){
  const int idx = blockIdx.x*256 + threadIdx.x;
  const int z = idx>>12, l = idx&4095;
  const int y = l>>6, x = l&63;
  const float* sz = sfg9 + (size_t)z*L;
  float s = 0.f;
  #pragma unroll
  for(int di=-1;di<=1;di++)
    #pragma unroll
    for(int dj=-1;dj<=1;dj++){
      const int yy=y+di, xx=x+dj;
      if(yy>=0&&yy<64&&xx>=0&&xx<64) s += sz[yy*64+xx];
    }
  sfg81[idx] = s;
}

// ---------------- fp16 NT MFMA GEMM (OM=0: f32 C; OM=1: fp16 padded D) ----------------
template<int OM>
__global__ __launch_bounds__(256) void gemm_h16(const _Float16* __restrict__ A, int lda, size_t sAz,
                                                const _Float16* __restrict__ B, int ldb, size_t sBz,
                                                void* __restrict__ C, int ldc, size_t sCz,
                                                int K){
  __shared__ _Float16 As[128*64];
  __shared__ _Float16 Bs[128*64];
  const int z = blockIdx.z;
  A += z*sAz; B += z*sBz;
  const int bm = blockIdx.y*128, bn = blockIdx.x*128;
  const int t = threadIdx.x, lane = t & 63, wave = t >> 6;
  const int wr = wave >> 1, wc = wave & 1;
  const int r16 = lane & 15, g4 = lane >> 4;
  const int srow = t >> 3;
  const int schunk = t & 7;
  f32x4 acc[4][4] = {};

  for(int k0=0;k0<K;k0+=64){
    #pragma unroll
    for(int u=0;u<4;u++){
      const int rowA = u*32 + srow;
      const int colh = ((schunk ^ (rowA & 7)) << 3);
      gload16(A + (size_t)(bm+rowA)*lda + k0 + colh, (char*)As + u*4096 + wave*1024);
      gload16(B + (size_t)(bn+rowA)*ldb + k0 + colh, (char*)Bs + u*4096 + wave*1024);
    }
    __syncthreads();
    #pragma unroll
    for(int kk=0;kk<2;kk++){
      f16x8 af[4], bf[4];
      #pragma unroll
      for(int i=0;i<4;i++){
        const int row = wr*64 + i*16 + r16;
        const int off = ((row<<7) + kk*64 + (g4<<4)) ^ ((row&7)<<4);
        af[i] = *(const f16x8*)((const char*)As + off);
      }
      #pragma unroll
      for(int j=0;j<4;j++){
        const int row = wc*64 + j*16 + r16;
        const int off = ((row<<7) + kk*64 + (g4<<4)) ^ ((row&7)<<4);
        bf[j] = *(const f16x8*)((const char*)Bs + off);
      }
      #pragma unroll
      for(int i=0;i<4;i++)
        #pragma unroll
        for(int j=0;j<4;j++)
          acc[i][j] = __builtin_amdgcn_mfma_f32_16x16x32_f16(af[i], bf[j], acc[i][j], 0, 0, 0);
    }
    __syncthreads();
  }
  #pragma unroll
  for(int i=0;i<4;i++){
    const int row0 = bm + wr*64 + i*16 + g4*4;
    #pragma unroll
    for(int j=0;j<4;j++){
      const int col = bn + wc*64 + j*16 + r16;
      #pragma unroll
      for(int r=0;r<4;r++){
        if(OM==0){
          ((float*)C)[z*sCz + (size_t)(row0+r)*ldc + col] = acc[i][j][r];
        } else {
          ((_Float16*)C)[z*sCz + (size_t)pmap(row0+r)*LDD + pmap(col)] = (_Float16)acc[i][j][r];
        }
      }
    }
  }
}

// ---------------- stencil: D* -> scores (fp16) ----------------
// MODE1: S = rn1[l]*(box9_q(D) + eps*sfg9[q])
// MODE3: E0 = diag9(D); S = rn3[l]*(box9_q(E0) + eps*sfg81[q])
template<int MODE>
__global__ __launch_bounds__(256) void stencil_scores(const _Float16* __restrict__ Dp,
                                                      const float* __restrict__ rn,
                                                      const float* __restrict__ sfgB,
                                                      _Float16* __restrict__ S){
  __shared__ _Float16 E0[204*128];
  const int z = blockIdx.z, yq = blockIdx.y, lt = blockIdx.x*128, t = threadIdx.x;
  const _Float16* D = Dp + (size_t)z*RPAD*LDD;
  const int w0 = yq*68;
  const int DKD[9] = {-69*(LDD+1),-68*(LDD+1),-67*(LDD+1),-(LDD+1),0,(LDD+1),67*(LDD+1),68*(LDD+1),69*(LDD+1)};
  for(int i=0;i<102;i++){
    const int idx = i*256+t;
    const int wrr = idx>>7, j = idx&127;
    const int l = lt + j;
    const int cl = l + 70 + ((l>>6)<<2);
    const int r = w0 + wrr;
    float acc = 0.f;
    if(MODE==1){
      acc = (float)D[(size_t)r*LDD + cl];
    } else {
      const int wr68 = (wrr>=136)?2:((wrr>=68)?1:0);
      const int gy = yq - 1 + wr68;
      const int u = wrr - wr68*68;
      if(gy>=0 && gy<64 && u>=2 && u<=65){
        const _Float16* base = D + (size_t)r*LDD + cl;
        #pragma unroll
        for(int k=0;k<9;k++) acc += (float)base[DKD[k]];
      }
    }
    E0[wrr*128 + j] = (_Float16)acc;
  }
  __syncthreads();
  const float* rnz = rn + (size_t)z*L;
  const float* sB = sfgB + (size_t)z*L;
  _Float16* Sz = S + (size_t)z*L*L;
  const int DK[9] = {-69,-68,-67,-1,0,1,67,68,69};
  #pragma unroll
  for(int i=0;i<32;i++){
    const int idx = i*256+t;
    const int j = idx&127, xq = idx>>7;
    const int q = yq*64+xq, l = lt+j;
    float acc = 0.f;
    #pragma unroll
    for(int k=0;k<9;k++) acc += (float)E0[(70+xq+DK[k])*128 + j];
    Sz[(size_t)q*L + l] = (_Float16)(rnz[l]*(acc + 1e-7f*sB[q]));
  }
}

// ---------------- softmax: S(fp16) -> normalized attn*rn (fp16) + rowscale/psum ----------------
template<int PADOUT>
__global__ __launch_bounds__(256) void softmax_fp(const _Float16* __restrict__ S,
                                                  const float* __restrict__ rn,
                                                  const float* __restrict__ skip,
                                                  _Float16* __restrict__ Fp,
                                                  float* __restrict__ rsc,
                                                  float* __restrict__ psum){
  __shared__ float red[4];
  const int q = blockIdx.x, z = blockIdx.y, t = threadIdx.x;
  const int lane = t & 63, wv_ = t >> 6;
  const _Float16* row = S + ((size_t)z*L + q)*L;
  float v[16];
  {
    f16x8 a = *(const f16x8*)(row + t*16);
    f16x8 b = *(const f16x8*)(row + t*16 + 8);
    #pragma unroll
    for(int i=0;i<8;i++){ v[i] = (float)a[i]; v[8+i] = (float)b[i]; }
  }
  float mx = -3.0e38f;
  #pragma unroll
  for(int i=0;i<16;i++) mx = fmaxf(mx, v[i]);
  mx = wave_max(mx);
  if(lane==0) red[wv_] = mx;
  __syncthreads();
  mx = fmaxf(fmaxf(red[0],red[1]), fmaxf(red[2],red[3]));
  __syncthreads();
  float sum = 0.f;
  #pragma unroll
  for(int i=0;i<16;i++){ v[i] = __expf(v[i]-mx); sum += v[i]; }
  sum = wave_sum(sum);
  if(lane==0) red[wv_] = sum;
  __syncthreads();
  sum = red[0]+red[1]+red[2]+red[3];
  __syncthreads();
  const float* rnz = rn + (size_t)z*L + t*16;
  const float* skz = skip + (size_t)z*L + t*16;
  float wvv[16]; float wm = 0.f, ws = 0.f;
  #pragma unroll
  for(int i=0;i<16;i++){
    const float wi = v[i]*rnz[i];
    wvv[i] = wi; ws += wi;
    if(skz[i] < 0.5f) wm = fmaxf(wm, wi);
  }
  wm = wave_max(wm);
  if(lane==0) red[wv_] = wm;
  __syncthreads();
  wm = fmaxf(fmaxf(red[0],red[1]),fmaxf(red[2],red[3]));
  __syncthreads();
  ws = wave_sum(ws);
  if(lane==0) red[wv_] = ws;
  __syncthreads();
  ws = red[0]+red[1]+red[2]+red[3];
  wm = fmaxf(wm, 1e-30f);
  const float inv = 1.0f/wm;
  size_t base;
  if(PADOUT) base = ((size_t)z*RPAD + pmap(q))*LDP;
  else       base = ((size_t)z*L + q)*L;
  #pragma unroll
  for(int j=0;j<8;j++){
    const int l0 = t*16 + 2*j;
    const float f0 = (skz[2*j]   < 0.5f) ? wvv[2*j]*inv   : 0.f;
    const float f1 = (skz[2*j+1] < 0.5f) ? wvv[2*j+1]*inv : 0.f;
    f16x2 h; h[0] = (_Float16)f0; h[1] = (_Float16)f1;
    const size_t off = PADOUT ? (base + (size_t)pmap(l0)) : (base + l0);
    *(f16x2*)(Fp + off) = h;
  }
  if(t==0){
    const int NR = PADOUT ? RPAD : L;
    const int ri = PADOUT ? pmap(q) : q;
    rsc[(size_t)z*NR + ri] = wm/sum;
    psum[(size_t)z*NR + ri] = ws/sum;
  }
}

// ---------------- rowstats3: Bq, eps3 ----------------
__global__ __launch_bounds__(256) void rowstats3(const float* __restrict__ rscp,
                                                 const float* __restrict__ psp,
                                                 float* __restrict__ Bq,
                                                 float* __restrict__ eps3){
  const int idx = blockIdx.x*256 + threadIdx.x;
  const int z = idx>>12, q = idx&4095;
  const int rq = pmap(q);
  const float* rz = rscp + (size_t)z*RPAD;
  const float* pz = psp + (size_t)z*RPAD;
  const int DK[9] = {-69,-68,-67,-1,0,1,67,68,69};
  float b=0.f, e=0.f;
  #pragma unroll
  for(int k=0;k<9;k++){ b += rz[rq-DK[k]]; e += pz[rq-DK[k]]; }
  Bq[idx] = fmaxf(b, 1e-30f);
  eps3[idx] = e;
}

// ---------------- stencil_F: diag9 of attn*rn -> F3 (fp16, row-normalized by Bq) ----------------
__global__ __launch_bounds__(256) void stencil_F(const _Float16* __restrict__ Fp3,
                                                 const float* __restrict__ rscp,
                                                 const float* __restrict__ Bq,
                                                 _Float16* __restrict__ F3){
  const int z = blockIdx.z, yq = blockIdx.y, lt = blockIdx.x*128, t = threadIdx.x;
  const _Float16* P = Fp3 + (size_t)z*RPAD*LDP;
  const float* rz = rscp + (size_t)z*RPAD;
  const int DK[9] = {-69,-68,-67,-1,0,1,67,68,69};
  #pragma unroll
  for(int i=0;i<32;i++){
    const int idx = i*256+t;
    const int j = idx&127, xq = idx>>7;
    const int q = yq*64+xq, l = lt+j;
    const int rq = yq*68 + xq + 70;
    const int cl = l + 70 + ((l>>6)<<2);
    const _Float16* base = P + (size_t)rq*LDP + cl;
    float acc = 0.f;
    #pragma unroll
    for(int k=0;k<9;k++) acc += rz[rq - DK[k]] * (float)base[-DK[k]*(LDP+1)];
    const float bq = Bq[(size_t)z*L + q];
    F3[((size_t)z*L + q)*LDP + cl] = (_Float16)(acc/bq);
  }
}

// ---------------- PV epilogue: scale + eps + mask-mix + transpose to outs ----------------
__global__ __launch_bounds__(256) void pv_epilogue(const float* __restrict__ C,
                                                   const float* __restrict__ rsc,
                                                   const float* __restrict__ eps,
                                                   const float* __restrict__ fg,
                                                   const float* __restrict__ mask,
                                                   float* __restrict__ outs,
                                                   int choff, float mdiv){
  __shared__ float tile[64][65];
  const int z = blockIdx.y, q0 = blockIdx.x*64, t = threadIdx.x;
  {
    const int c = t&63, qi = t>>6;
    #pragma unroll
    for(int i=0;i<16;i++){
      const int q = q0 + qi + i*4;
      float v = C[((size_t)z*L + q)*128 + c];
      v = v*rsc[(size_t)z*L + q] + 1e-7f*eps[(size_t)z*L + q];
      tile[qi + i*4][c] = v;
    }
  }
  __syncthreads();
  {
    const int qq = t&63, ci = t>>6;
    const int q = q0 + qq;
    const float m = mask[(size_t)z*L + q];
    #pragma unroll
    for(int i=0;i<16;i++){
      const int cc = ci + i*4;
      const float o = tile[qq][cc]*(m*mdiv) + fg[((size_t)z*64 + cc)*L + q]*(1.0f-m);
      outs[((size_t)z*128 + choff + cc)*L + q] = o;
    }
  }
}

// ---------------- SE module + combiner (unchanged) ----------------
__global__ __launch_bounds__(256) void se_reduce(const float* __restrict__ outs,
                                                 float* __restrict__ svec){
  __shared__ float red[4];
  const int ch = blockIdx.x, z = blockIdx.y;
  const float* p = outs + ((size_t)z*128 + ch)*L;
  const int t = threadIdx.x;
  float s = 0.f;
  #pragma unroll
  for(int i=0;i<4;i++){
    const float4 vv = ((const float4*)p)[i*256+t];
    s += vv.x+vv.y+vv.z+vv.w;
  }
  s = wave_sum(s);
  if((t&63)==0) red[t>>6]=s;
  __syncthreads();
  if(t==0) svec[z*128+ch] = (red[0]+red[1]+red[2]+red[3])*(1.0f/4096.0f);
}
__global__ __launch_bounds__(128) void se_mlp(const float* __restrict__ svec,
                                              const float* __restrict__ W1, const float* __restrict__ b1,
                                              const float* __restrict__ W2, const float* __restrict__ b2,
                                              float* __restrict__ g){
  __shared__ float s[128], h[128];
  const int z = blockIdx.x, i = threadIdx.x;
  s[i] = svec[z*128+i];
  __syncthreads();
  float a = b1[i];
  const float* w = W1 + (size_t)i*128;
  for(int j=0;j<128;j++) a = fmaf(w[j], s[j], a);
  h[i] = fmaxf(a, 0.f);
  __syncthreads();
  float o = b2[i];
  w = W2 + (size_t)i*128;
  for(int j=0;j<128;j++) o = fmaf(w[j], h[j], o);
  g[z*128+i] = 1.0f/(1.0f + __expf(-o));
}
__global__ __launch_bounds__(256) void combiner(const float* __restrict__ outs,
                                                const float* __restrict__ g,
                                                const float* __restrict__ Wc,
                                                const float* __restrict__ bc,
                                                float* __restrict__ out){
  const size_t idx = (size_t)blockIdx.x*256 + threadIdx.x;
  const int q = (int)(idx & 4095);
  const int o = (int)((idx >> 12) & 63);
  const int z = (int)(idx >> 18);
  const float* ob = outs + (size_t)z*128*L + q;
  const float* gz = g + z*128;
  const float* wr = Wc + (size_t)o*128;
  float acc = bc[o];
  for(int ch=0; ch<128; ++ch) acc = fmaf(ob[(size_t)ch*L]*gz[ch], wr[ch], acc);
  out[idx] = acc;
}

// ---------------- host orchestration ----------------
extern "C" void kernel_launch(void* const* d_in, const int* in_sizes, int n_in,
                              void* d_out, int out_size, void* d_ws, size_t ws_size,
                              hipStream_t stream){
  const float* fg   = (const float*)d_in[0];
  const float* mask = (const float*)d_in[1];
  const float* W1   = (const float*)d_in[2];
  const float* b1   = (const float*)d_in[3];
  const float* W2   = (const float*)d_in[4];
  const float* b2   = (const float*)d_in[5];
  const float* Wc   = (const float*)d_in[6];
  const float* bc   = (const float*)d_in[7];
  float* out = (float*)d_out;

  char* w = (char*)d_ws; size_t off = 0;
  auto alloc = [&](size_t bytes)->void*{
    void* p = (void*)(w + off);
    off += (bytes + 255) & ~(size_t)255;
    return p;
  };
  _Float16* Dp    = (_Float16*)alloc(2ull*RPAD*LDD*2);   // reused later as F3
  _Float16* FpA   = (_Float16*)alloc(2ull*RPAD*LDP*2);   // Fp1 then Fp3
  _Float16* S     = (_Float16*)alloc(2ull*L*L*2);
  float* C1   = (float*)alloc(2ull*L*128*4);
  float* C3   = (float*)alloc(2ull*L*128*4);
  _Float16* bg16  = (_Float16*)alloc(2ull*128*L*2);
  _Float16* bg16p = (_Float16*)alloc(2ull*128*LDP*2);
  _Float16* fgT16 = (_Float16*)alloc(2ull*L*64*2);
  _Float16* bgT16 = (_Float16*)alloc(2ull*L*64*2);
  float* outs  = (float*)alloc(2ull*128*L*4);
  float* nsq   = (float*)alloc(2ull*L*4);
  float* sfg   = (float*)alloc(2ull*L*4);
  float* rn1v  = (float*)alloc(2ull*L*4);
  float* rn3v  = (float*)alloc(2ull*L*4);
  float* sfg9  = (float*)alloc(2ull*L*4);
  float* sfg81 = (float*)alloc(2ull*L*4);
  float* allm3 = (float*)alloc(2ull*L*4);
  float* rsc3p = (float*)alloc(2ull*RPAD*4);
  float* psum3p= (float*)alloc(2ull*RPAD*4);
  float* rsc1  = (float*)alloc(2ull*L*4);
  float* psum1 = (float*)alloc(2ull*L*4);
  float* Bq    = (float*)alloc(2ull*L*4);
  float* eps3  = (float*)alloc(2ull*L*4);
  float* svec  = (float*)alloc(1024);
  float* gbuf  = (float*)alloc(1024);
  _Float16* Fp1 = FpA;
  _Float16* Fp3 = FpA;
  _Float16* F3  = Dp;

  // ---- init pads & small buffers ----
  zero_pad_rows<<<dim3((LDD+255)/256,392,2),256,0,stream>>>(Dp, (size_t)RPAD*LDD, LDD);
  zero_pad_cols<<<dim3(16,392,2),256,0,stream>>>(Dp, (size_t)RPAD*LDD, LDD);
  zero_f16k<<<(unsigned)((2ull*128*L+255)/256),256,0,stream>>>(bg16, 2ull*128*L);
  zero_f16k<<<(unsigned)((2ull*128*LDP+255)/256),256,0,stream>>>(bg16p, 2ull*128*LDP);
  zero_f32k<<<(unsigned)((2ull*RPAD+255)/256),256,0,stream>>>(rsc3p, 2ull*RPAD);
  zero_f32k<<<(unsigned)((2ull*RPAD+255)/256),256,0,stream>>>(psum3p, 2ull*RPAD);

  // ---- prep ----
  prep1<<<dim3(64,2),256,0,stream>>>(fg, mask, fgT16, bgT16, bg16, bg16p, nsq, sfg, rn1v);
  prep2<<<32,256,0,stream>>>(nsq, sfg, mask, rn3v, sfg9, allm3);
  prep2b<<<32,256,0,stream>>>(sfg9, sfg81);

  // ---- D = fg^T * bg (K=64), padded fp16 output ----
  gemm_h16<1><<<dim3(32,32,2),256,0,stream>>>(fgT16, 64, (size_t)L*64,
                                              bgT16, 64, (size_t)L*64,
                                              (void*)Dp, LDD, (size_t)RPAD*LDD, 64);

  // ---- p=1 branch ----
  stencil_scores<1><<<dim3(32,64,2),256,0,stream>>>(Dp, rn1v, sfg9, S);
  softmax_fp<0><<<dim3(4096,2),256,0,stream>>>(S, rn1v, mask, Fp1, rsc1, psum1);
  gemm_h16<0><<<dim3(1,32,2),256,0,stream>>>(Fp1, L, (size_t)L*L,
                                             bg16, L, (size_t)128*L,
                                             (void*)C1, 128, (size_t)L*128, L);

  // ---- p=3 branch ----
  zero_pad_rows<<<dim3((LDP+255)/256,392,2),256,0,stream>>>(Fp3, (size_t)RPAD*LDP, LDP);
  zero_pad_cols<<<dim3(16,392,2),256,0,stream>>>(Fp3, (size_t)RPAD*LDP, LDP);
  stencil_scores<3><<<dim3(32,64,2),256,0,stream>>>(Dp, rn3v, sfg81, S);
  softmax_fp<1><<<dim3(4096,2),256,0,stream>>>(S, rn3v, allm3, Fp3, rsc3p, psum3p);
  rowstats3<<<32,256,0,stream>>>(rsc3p, psum3p, Bq, eps3);
  stencil_F<<<dim3(32,64,2),256,0,stream>>>(Fp3, rsc3p, Bq, F3);
  gemm_h16<0><<<dim3(1,32,2),256,0,stream>>>(F3, LDP, (size_t)L*LDP,
                                             bg16p, LDP, (size_t)128*LDP,
                                             (void*)C3, 128, (size_t)L*128, LDP);

  // ---- epilogues ----
  pv_epilogue<<<dim3(64,2),256,0,stream>>>(C1, rsc1, psum1, fg, mask, outs, 0, 1.0f);
  pv_epilogue<<<dim3(64,2),256,0,stream>>>(C3, Bq, eps3, fg, mask, outs, 64, 1.0f/9.0f);

  // ---- SE + combiner ----
  se_reduce<<<dim3(128,2),256,0,stream>>>(outs, svec);
  se_mlp<<<2,128,0,stream>>>(svec, W1, b1, W2, b2, gbuf);
  combiner<<<(2*64*L)/256,256,0,stream>>>(outs, gbuf, Wc, bc, out);
}

// Round 5
// 336.429 us; speedup vs baseline: 2.6020x; 2.6020x over previous
//
#include <hip/hip_runtime.h>
#include <math.h>

#define WW 64
#define HH 64
#define L 4096
#define NC 64
#define D3 576

typedef _Float16 f16x8 __attribute__((ext_vector_type(8)));
typedef _Float16 f16x4 __attribute__((ext_vector_type(4)));
typedef float    f32x4 __attribute__((ext_vector_type(4)));

__device__ __forceinline__ float wave_max(float v){
  #pragma unroll
  for(int o=32;o;o>>=1) v = fmaxf(v, __shfl_xor(v,o));
  return v;
}
__device__ __forceinline__ float wave_sum(float v){
  #pragma unroll
  for(int o=32;o;o>>=1) v += __shfl_xor(v,o);
  return v;
}
__device__ __forceinline__ void gload16(const void* g, void* l){
  __builtin_amdgcn_global_load_lds((const __attribute__((address_space(1))) unsigned int*)g,
                                   (__attribute__((address_space(3))) unsigned int*)l,
                                   16, 0, 0);
}

// ---------------- fg transpose: (z,c,q) -> (z,q,c) ----------------
__global__ __launch_bounds__(256) void transpose_fg(const float* __restrict__ fg,
                                                    float* __restrict__ fgT){
  __shared__ float tile[64][65];
  const int z = blockIdx.y;
  const int q0 = blockIdx.x*64;
  const int tx = threadIdx.x & 63, ty = threadIdx.x >> 6;
  #pragma unroll
  for(int i=0;i<16;i++){
    const int c = ty*16 + i;
    tile[c][tx] = fg[((size_t)z*64 + c)*L + q0 + tx];
  }
  __syncthreads();
  #pragma unroll
  for(int i=0;i<16;i++){
    const int q = ty*16 + i;
    fgT[((size_t)z*L + q0 + q)*64 + tx] = tile[tx][q];
  }
}

// ---------------- builders (fp16 outputs, coalesced via fgT) ----------------
__global__ __launch_bounds__(256) void build_p1(const float* __restrict__ fgT,
                                               const float* __restrict__ mask,
                                               _Float16* __restrict__ BhatH1,
                                               _Float16* __restrict__ PfgH1){
  const int t = threadIdx.x, c = t & 63, sub = t >> 6;
  const int l = blockIdx.x*4 + sub, z = blockIdx.y;
  const float* fgz = fgT + (size_t)z*L*64;
  const float m = mask[(size_t)z*L + l];
  const float K = fgz[(size_t)l*64 + c]*(1.0f-m) + 1e-7f;
  const float ss = wave_sum(K*K);
  BhatH1[((size_t)z*L + l)*NC + c] = (_Float16)(K*rsqrtf(ss));

  const int y = l >> 6, x = l & 63;
  float s = 0.f;
  #pragma unroll
  for(int dy=-1;dy<=1;dy++){
    const int yy = y+dy;
    if(yy<0||yy>=HH) continue;
    #pragma unroll
    for(int dx=-1;dx<=1;dx++){
      const int xx = x+dx;
      if(xx<0||xx>=WW) continue;
      s += fgz[(size_t)(yy*WW+xx)*64 + c];
    }
  }
  PfgH1[((size_t)z*L + l)*NC + c] = (_Float16)s;
}

__global__ __launch_bounds__(256) void build_bhat3(const float* __restrict__ fgT,
                                                   const float* __restrict__ mask,
                                                   _Float16* __restrict__ BhatH3){
  const int t = threadIdx.x, c = t & 63, sub = t >> 6;
  const int l = blockIdx.x*4 + sub, z = blockIdx.y;
  const float* fgz = fgT + (size_t)z*L*64;
  const float* mz  = mask + (size_t)z*L;
  const int y = l >> 6, x = l & 63;
  float K[9]; float ss = 0.f;
  #pragma unroll
  for(int i=0;i<3;i++){
    #pragma unroll
    for(int j=0;j<3;j++){
      const int yy = y+i-1, xx = x+j-1;
      float v = 0.f;
      if(yy>=0&&yy<HH&&xx>=0&&xx<WW){
        const int q = yy*WW+xx;
        v = fgz[(size_t)q*64 + c]*(1.0f - mz[q]);
      }
      v += 1e-7f;
      K[i*3+j] = v; ss += v*v;
    }
  }
  ss = wave_sum(ss);
  const float rn = rsqrtf(ss);
  _Float16* outp = BhatH3 + ((size_t)z*L + l)*D3 + c*9;
  #pragma unroll
  for(int k=0;k<9;k++) outp[k] = (_Float16)(K[k]*rn);
}

__global__ __launch_bounds__(256) void build_pfgbox3(const float* __restrict__ fgT,
                                                     _Float16* __restrict__ PfgH3){
  const int t = threadIdx.x, c = t & 63, sub = t >> 6;
  const int l = blockIdx.x*4 + sub, z = blockIdx.y;
  const float* fgz = fgT + (size_t)z*L*64;
  const int y = l >> 6, x = l & 63;
  float Wn[5][5];
  #pragma unroll
  for(int u=0;u<5;u++){
    const int yy = y+u-2;
    #pragma unroll
    for(int v=0;v<5;v++){
      const int xx = x+v-2;
      Wn[u][v] = (yy>=0 && yy<HH && xx>=0 && xx<WW) ? fgz[(size_t)(yy*WW+xx)*64 + c] : 0.f;
    }
  }
  const bool dyok[3] = { y-1>=0, true, y+1<HH };
  const bool dxok[3] = { x-1>=0, true, x+1<WW };
  _Float16* outp = PfgH3 + ((size_t)z*L + l)*D3 + c*9;
  #pragma unroll
  for(int i=0;i<3;i++){
    #pragma unroll
    for(int j=0;j<3;j++){
      float acc = 0.f;
      #pragma unroll
      for(int a=0;a<3;a++){
        if(!dyok[a]) continue;
        #pragma unroll
        for(int b=0;b<3;b++){
          if(!dxok[b]) continue;
          acc += Wn[i+a][j+b];
        }
      }
      outp[i*3+j] = (_Float16)acc;
    }
  }
}

// ---------------- zero fill ----------------
__global__ __launch_bounds__(256) void zero_h(_Float16* __restrict__ p, size_t n){
  const size_t i = (size_t)blockIdx.x*256 + threadIdx.x;
  if(i < n) p[i] = (_Float16)0.f;
}

// ---------------- fp16 transpose: src (L x C) -> dst (C x L) ----------------
__global__ __launch_bounds__(256) void transpose_h(const ushort* __restrict__ src,
                                                   ushort* __restrict__ dst,
                                                   int C, size_t sSz, size_t sDz){
  __shared__ ushort tile[64][65];
  const int z = blockIdx.z;
  src += z*sSz; dst += z*sDz;
  const int bc = blockIdx.x*64, br = blockIdx.y*64;
  const int tx = threadIdx.x & 15, ty = threadIdx.x >> 4;
  #pragma unroll
  for(int i=0;i<4;i++){
    const ushort4 v = *(const ushort4*)(src + (size_t)(br+ty+16*i)*C + bc + tx*4);
    tile[ty+16*i][tx*4+0] = v.x;
    tile[ty+16*i][tx*4+1] = v.y;
    tile[ty+16*i][tx*4+2] = v.z;
    tile[ty+16*i][tx*4+3] = v.w;
  }
  __syncthreads();
  #pragma unroll
  for(int i=0;i<4;i++){
    ushort4 o;
    o.x = tile[tx*4+0][ty+16*i];
    o.y = tile[tx*4+1][ty+16*i];
    o.z = tile[tx*4+2][ty+16*i];
    o.w = tile[tx*4+3][ty+16*i];
    *(ushort4*)(dst + (size_t)(bc+ty+16*i)*L + br + tx*4) = o;
  }
}

// ---------------- fp16 NT MFMA GEMM, split-K capable ----------------
// OM=0: f32 partial output (C + ks*sPart + z*sCz); OM=2: fp16 output (KS must be 1).
// C[m,n] = sum_k A[m,k]*B[n,k]
template<int OM, int KS>
__global__ __launch_bounds__(256) void gemm_h16(const _Float16* __restrict__ A, int lda, size_t sAz,
                                                const _Float16* __restrict__ B, int ldb, size_t sBz,
                                                void* __restrict__ C, int ldc, size_t sCz,
                                                int K, size_t sPart){
  __shared__ _Float16 As[128*64];
  __shared__ _Float16 Bs[128*64];
  const int zz = blockIdx.z;
  const int z = zz / KS, ks = zz % KS;
  const int Kp = K / KS;
  A += (size_t)z*sAz + (size_t)ks*Kp;
  B += (size_t)z*sBz + (size_t)ks*Kp;
  const int bm = blockIdx.y*128, bn = blockIdx.x*128;
  const int t = threadIdx.x, lane = t & 63, wave = t >> 6;
  const int wr = wave >> 1, wc = wave & 1;
  const int r16 = lane & 15, g4 = lane >> 4;
  const int srow = t >> 3;
  const int schunk = t & 7;
  f32x4 acc[4][4] = {};

  for(int k0=0;k0<Kp;k0+=64){
    #pragma unroll
    for(int u=0;u<4;u++){
      const int rowA = u*32 + srow;
      const int colh = ((schunk ^ (rowA & 7)) << 3);
      gload16(A + (size_t)(bm+rowA)*lda + k0 + colh, (char*)As + u*4096 + wave*1024);
      gload16(B + (size_t)(bn+rowA)*ldb + k0 + colh, (char*)Bs + u*4096 + wave*1024);
    }
    __syncthreads();
    #pragma unroll
    for(int kk=0;kk<2;kk++){
      f16x8 af[4], bf[4];
      #pragma unroll
      for(int i=0;i<4;i++){
        const int row = wr*64 + i*16 + r16;
        const int off = ((row<<7) + kk*64 + (g4<<4)) ^ ((row&7)<<4);
        af[i] = *(const f16x8*)((const char*)As + off);
      }
      #pragma unroll
      for(int j=0;j<4;j++){
        const int row = wc*64 + j*16 + r16;
        const int off = ((row<<7) + kk*64 + (g4<<4)) ^ ((row&7)<<4);
        bf[j] = *(const f16x8*)((const char*)Bs + off);
      }
      #pragma unroll
      for(int i=0;i<4;i++)
        #pragma unroll
        for(int j=0;j<4;j++)
          acc[i][j] = __builtin_amdgcn_mfma_f32_16x16x32_f16(af[i], bf[j], acc[i][j], 0, 0, 0);
    }
    __syncthreads();
  }
  if(OM==0){
    float* Cz = (float*)C + (size_t)ks*sPart + (size_t)z*sCz;
    #pragma unroll
    for(int i=0;i<4;i++){
      const int row0 = bm + wr*64 + i*16 + g4*4;
      #pragma unroll
      for(int j=0;j<4;j++){
        const int col = bn + wc*64 + j*16 + r16;
        #pragma unroll
        for(int r=0;r<4;r++)
          Cz[(size_t)(row0+r)*ldc + col] = acc[i][j][r];
      }
    }
  } else {
    _Float16* Cz = (_Float16*)C + (size_t)z*sCz;
    #pragma unroll
    for(int i=0;i<4;i++){
      const int row0 = bm + wr*64 + i*16 + g4*4;
      #pragma unroll
      for(int j=0;j<4;j++){
        const int col = bn + wc*64 + j*16 + r16;
        #pragma unroll
        for(int r=0;r<4;r++)
          Cz[(size_t)(row0+r)*ldc + col] = (_Float16)acc[i][j][r];
      }
    }
  }
}

// ---------------- row softmax over 4096, fp16 in-place ----------------
__global__ __launch_bounds__(256) void softmax16(_Float16* __restrict__ S){
  __shared__ float red[4];
  _Float16* p = S + ((size_t)blockIdx.y*L + blockIdx.x)*L;
  const int t = threadIdx.x;
  float v[16];
  {
    const f16x8 a = *(const f16x8*)(p + t*16);
    const f16x8 b = *(const f16x8*)(p + t*16 + 8);
    #pragma unroll
    for(int i=0;i<8;i++){ v[i] = (float)a[i]; v[8+i] = (float)b[i]; }
  }
  float mx = -3.0e38f;
  #pragma unroll
  for(int i=0;i<16;i++) mx = fmaxf(mx, v[i]);
  mx = wave_max(mx);
  if((t&63)==0) red[t>>6]=mx;
  __syncthreads();
  mx = fmaxf(fmaxf(red[0],red[1]), fmaxf(red[2],red[3]));
  __syncthreads();
  float s = 0.f;
  #pragma unroll
  for(int i=0;i<16;i++){ v[i] = __expf(v[i]-mx); s += v[i]; }
  s = wave_sum(s);
  if((t&63)==0) red[t>>6]=s;
  __syncthreads();
  s = red[0]+red[1]+red[2]+red[3];
  const float inv = 1.0f/s;
  f16x8 a, b;
  #pragma unroll
  for(int i=0;i<8;i++){ a[i] = (_Float16)(v[i]*inv); b[i] = (_Float16)(v[8+i]*inv); }
  *(f16x8*)(p + t*16) = a;
  *(f16x8*)(p + t*16 + 8) = b;
}

// ---------------- split-K reduce ----------------
template<int KS>
__global__ __launch_bounds__(256) void red_k(const float* __restrict__ Cp,
                                             float* __restrict__ R,
                                             size_t sPart, size_t n){
  const size_t i = (size_t)blockIdx.x*256 + threadIdx.x;
  if(i >= n) return;
  float s = 0.f;
  #pragma unroll
  for(int k=0;k<KS;k++) s += Cp[(size_t)k*sPart + i];
  R[i] = s;
}

// ---------------- scatters (conv-transpose + mask mix) ----------------
__global__ __launch_bounds__(256) void scatter_p1(const float* __restrict__ R,
                                                  const float* __restrict__ fg,
                                                  const float* __restrict__ mask,
                                                  float* __restrict__ outs){
  const int z = blockIdx.y;
  const int idx = blockIdx.x*256 + threadIdx.x;
  const int c = idx >> 12, q = idx & 4095;
  const float m = mask[(size_t)z*L + q];
  const float rec = R[((size_t)z*L + q)*128 + c];
  const float f = fg[((size_t)z*NC + c)*L + q];
  outs[((size_t)z*128 + c)*L + q] = rec*m + f*(1.0f-m);
}

__global__ __launch_bounds__(256) void scatter_p3(const float* __restrict__ R,
                                                  const float* __restrict__ fg,
                                                  const float* __restrict__ mask,
                                                  float* __restrict__ outs){
  const int z = blockIdx.y;
  const int idx = blockIdx.x*256 + threadIdx.x;
  const int c = idx >> 12, q = idx & 4095;
  const int u = q >> 6, v = q & 63;
  float rec = 0.f;
  #pragma unroll
  for(int i=0;i<3;i++){
    const int yy = u+1-i;
    if(yy<0||yy>=HH) continue;
    #pragma unroll
    for(int j=0;j<3;j++){
      const int xx = v+1-j;
      if(xx<0||xx>=WW) continue;
      rec += R[((size_t)z*L + yy*WW+xx)*640 + c*9 + i*3 + j];
    }
  }
  const float m = mask[(size_t)z*L + q];
  const float f = fg[((size_t)z*NC + c)*L + q];
  outs[((size_t)z*128 + 64 + c)*L + q] = rec*m*(1.0f/9.0f) + f*(1.0f-m);
}

// ---------------- SE module ----------------
__global__ __launch_bounds__(256) void se_reduce(const float* __restrict__ outs,
                                                 float* __restrict__ svec){
  __shared__ float red[4];
  const int ch = blockIdx.x, z = blockIdx.y;
  const float* p = outs + ((size_t)z*128 + ch)*L;
  const int t = threadIdx.x;
  float s = 0.f;
  #pragma unroll
  for(int i=0;i<4;i++){
    const float4 vv = ((const float4*)p)[i*256+t];
    s += vv.x+vv.y+vv.z+vv.w;
  }
  s = wave_sum(s);
  if((t&63)==0) red[t>>6]=s;
  __syncthreads();
  if(t==0) svec[z*128+ch] = (red[0]+red[1]+red[2]+red[3])*(1.0f/4096.0f);
}

__global__ __launch_bounds__(128) void se_mlp(const float* __restrict__ svec,
                                              const float* __restrict__ W1, const float* __restrict__ b1,
                                              const float* __restrict__ W2, const float* __restrict__ b2,
                                              float* __restrict__ g){
  __shared__ float s[128], h[128];
  const int z = blockIdx.x, i = threadIdx.x;
  s[i] = svec[z*128+i];
  __syncthreads();
  float a = b1[i];
  const float* w = W1 + (size_t)i*128;
  for(int j=0;j<128;j++) a = fmaf(w[j], s[j], a);
  h[i] = fmaxf(a, 0.f);
  __syncthreads();
  float o = b2[i];
  w = W2 + (size_t)i*128;
  for(int j=0;j<128;j++) o = fmaf(w[j], h[j], o);
  g[z*128+i] = 1.0f/(1.0f + __expf(-o));
}

// ---------------- combiner 1x1 conv ----------------
__global__ __launch_bounds__(256) void combiner(const float* __restrict__ outs,
                                                const float* __restrict__ g,
                                                const float* __restrict__ Wc,
                                                const float* __restrict__ bc,
                                                float* __restrict__ out){
  const size_t idx = (size_t)blockIdx.x*256 + threadIdx.x;
  const int q = (int)(idx & 4095);
  const int o = (int)((idx >> 12) & 63);
  const int z = (int)(idx >> 18);
  const float* ob = outs + (size_t)z*128*L + q;
  const float* gz = g + z*128;
  const float* wr = Wc + (size_t)o*128;
  float acc = bc[o];
  for(int ch=0; ch<128; ++ch) acc = fmaf(ob[(size_t)ch*L]*gz[ch], wr[ch], acc);
  out[idx] = acc;
}

// ---------------- host orchestration ----------------
extern "C" void kernel_launch(void* const* d_in, const int* in_sizes, int n_in,
                              void* d_out, int out_size, void* d_ws, size_t ws_size,
                              hipStream_t stream){
  const float* fg   = (const float*)d_in[0];
  const float* mask = (const float*)d_in[1];
  const float* W1   = (const float*)d_in[2];
  const float* b1   = (const float*)d_in[3];
  const float* W2   = (const float*)d_in[4];
  const float* b2   = (const float*)d_in[5];
  const float* Wc   = (const float*)d_in[6];
  const float* bc   = (const float*)d_in[7];
  float* out = (float*)d_out;

  char* w = (char*)d_ws;
  size_t off = 0;
  auto alloc = [&](size_t bytes)->void*{
    void* p = (void*)(w + off);
    off += (bytes + 255) & ~(size_t)255;
    return p;
  };
  _Float16* BhatH3 = (_Float16*)alloc(2ull*L*D3*2);
  _Float16* BhatT3 = (_Float16*)alloc(2ull*640*L*2);   // padded N: 576->640
  _Float16* PfgH3  = (_Float16*)alloc(2ull*L*D3*2);
  _Float16* BhatH1 = (_Float16*)alloc(2ull*L*64*2);
  _Float16* BhatT1 = (_Float16*)alloc(2ull*128*L*2);   // padded N: 64->128
  _Float16* PfgH1  = (_Float16*)alloc(2ull*L*64*2);
  float* fgT   = (float*)alloc(2ull*L*64*4);
  float* Rbuf3 = (float*)alloc(2ull*L*640*4);
  float* Rbuf1 = (float*)alloc(2ull*L*128*4);
  float* outs  = (float*)alloc(2ull*128*L*4);
  float* svec  = (float*)alloc(1024);
  float* gbuf  = (float*)alloc(1024);
  _Float16* S  = (_Float16*)alloc(2ull*L*L*2);         // 67 MB, fp16 scores/attn
  const size_t sPart3 = 2ull*L*640;                    // elements per split-K partial (p3)
  const size_t sPart1 = 2ull*L*128;                    // (p1)
  float* Cp3 = (float*)alloc(4ull*sPart3*4);           // 4 partials
  float* Cp1 = (float*)alloc(8ull*sPart1*4);           // 8 partials

  transpose_fg<<<dim3(64,2),256,0,stream>>>(fg, fgT);

  // ================= p=1 branch (channels 0..63 of outs) =================
  build_p1<<<dim3(L/4,2),256,0,stream>>>(fgT, mask, BhatH1, PfgH1);
  zero_h<<<(unsigned)((2ull*128*L+255)/256),256,0,stream>>>(BhatT1, 2ull*128*L);
  transpose_h<<<dim3(1,64,2),256,0,stream>>>((const ushort*)BhatH1, (ushort*)BhatT1,
                                             64, (size_t)L*64, (size_t)128*L);
  gemm_h16<2,1><<<dim3(32,32,2),256,0,stream>>>(
      PfgH1, 64, (size_t)L*64,
      BhatH1, 64, (size_t)L*64,
      (void*)S, L, (size_t)L*L, 64, 0);
  softmax16<<<dim3(L,2),256,0,stream>>>(S);
  gemm_h16<0,8><<<dim3(1,32,16),256,0,stream>>>(
      S, L, (size_t)L*L,
      BhatT1, L, (size_t)128*L,
      (void*)Cp1, 128, (size_t)L*128, L, sPart1);
  red_k<8><<<(unsigned)((sPart1+255)/256),256,0,stream>>>(Cp1, Rbuf1, sPart1, sPart1);
  scatter_p1<<<dim3(NC*L/256,2),256,0,stream>>>(Rbuf1, fg, mask, outs);

  // ================= p=3 branch (channels 64..127 of outs) =================
  build_bhat3  <<<dim3(L/4,2),256,0,stream>>>(fgT, mask, BhatH3);
  zero_h<<<(unsigned)((2ull*640*L+255)/256),256,0,stream>>>(BhatT3, 2ull*640*L);
  transpose_h<<<dim3(9,64,2),256,0,stream>>>((const ushort*)BhatH3, (ushort*)BhatT3,
                                             D3, (size_t)L*D3, (size_t)640*L);
  build_pfgbox3<<<dim3(L/4,2),256,0,stream>>>(fgT, PfgH3);
  gemm_h16<2,1><<<dim3(32,32,2),256,0,stream>>>(
      PfgH3, D3, (size_t)L*D3,
      BhatH3, D3, (size_t)L*D3,
      (void*)S, L, (size_t)L*L, D3, 0);
  softmax16<<<dim3(L,2),256,0,stream>>>(S);
  gemm_h16<0,4><<<dim3(5,32,8),256,0,stream>>>(
      S, L, (size_t)L*L,
      BhatT3, L, (size_t)640*L,
      (void*)Cp3, 640, (size_t)L*640, L, sPart3);
  red_k<4><<<(unsigned)((sPart3+255)/256),256,0,stream>>>(Cp3, Rbuf3, sPart3, sPart3);
  scatter_p3<<<dim3(NC*L/256,2),256,0,stream>>>(Rbuf3, fg, mask, outs);

  // ================= SE + combiner =================
  se_reduce<<<dim3(128,2),256,0,stream>>>(outs, svec);
  se_mlp<<<2,128,0,stream>>>(svec, W1, b1, W2, b2, gbuf);
  combiner<<<(2*64*L)/256,256,0,stream>>>(outs, gbuf, Wc, bc, out);
}

// Round 6
// 323.250 us; speedup vs baseline: 2.7081x; 1.0408x over previous
//
#include <hip/hip_runtime.h>
#include <math.h>

#define WW 64
#define HH 64
#define L 4096
#define NC 64
#define D3 576
#define ASCALE (1.0f/128.0f)

typedef _Float16 f16x8 __attribute__((ext_vector_type(8)));
typedef float    f32x4 __attribute__((ext_vector_type(4)));

__device__ __forceinline__ float wave_max(float v){
  #pragma unroll
  for(int o=32;o;o>>=1) v = fmaxf(v, __shfl_xor(v,o));
  return v;
}
__device__ __forceinline__ float wave_sum(float v){
  #pragma unroll
  for(int o=32;o;o>>=1) v += __shfl_xor(v,o);
  return v;
}
__device__ __forceinline__ void gload16(const void* g, void* l){
  __builtin_amdgcn_global_load_lds((const __attribute__((address_space(1))) unsigned int*)g,
                                   (__attribute__((address_space(3))) unsigned int*)l,
                                   16, 0, 0);
}

__global__ __launch_bounds__(256) void transpose_fg(const float* __restrict__ fg,
                                                    float* __restrict__ fgT){
  __shared__ float tile[64][65];
  const int z = blockIdx.y;
  const int q0 = blockIdx.x*64;
  const int tx = threadIdx.x & 63, ty = threadIdx.x >> 6;
  #pragma unroll
  for(int i=0;i<16;i++){
    const int c = ty*16 + i;
    tile[c][tx] = fg[((size_t)z*64 + c)*L + q0 + tx];
  }
  __syncthreads();
  #pragma unroll
  for(int i=0;i<16;i++){
    const int q = ty*16 + i;
    fgT[((size_t)z*L + q0 + q)*64 + tx] = tile[tx][q];
  }
}

__global__ __launch_bounds__(256) void bg_build(const float* __restrict__ fg,
                                                const float* __restrict__ mask,
                                                _Float16* __restrict__ bgH){
  const int row = blockIdx.x, z = blockIdx.y, t = threadIdx.x;
  const int l0 = t*16;
  f16x8 o0, o1;
  if(row < 64){
    const float* fp = fg + ((size_t)z*64 + row)*L + l0;
    const float* mp = mask + (size_t)z*L + l0;
    #pragma unroll
    for(int i=0;i<8;i++){
      o0[i] = (_Float16)(fp[i]*(1.0f-mp[i])*128.0f);
      o1[i] = (_Float16)(fp[8+i]*(1.0f-mp[8+i])*128.0f);
    }
  } else {
    #pragma unroll
    for(int i=0;i<8;i++){ o0[i]=(_Float16)0.f; o1[i]=(_Float16)0.f; }
  }
  _Float16* op = bgH + ((size_t)z*128 + row)*L + l0;
  *(f16x8*)op = o0;
  *(f16x8*)(op+8) = o1;
}

__global__ __launch_bounds__(256) void build_p1(const float* __restrict__ fgT,
                                               const float* __restrict__ mask,
                                               _Float16* __restrict__ BhatH1,
                                               _Float16* __restrict__ PfgH1){
  const int t = threadIdx.x, c = t & 63, sub = t >> 6;
  const int l = blockIdx.x*4 + sub, z = blockIdx.y;
  const float* fgz = fgT + (size_t)z*L*64;
  const float m = mask[(size_t)z*L + l];
  const float K = fgz[(size_t)l*64 + c]*(1.0f-m) + 1e-7f;
  const float ss = wave_sum(K*K);
  BhatH1[((size_t)z*L + l)*NC + c] = (_Float16)(K*rsqrtf(ss));
  const int y = l >> 6, x = l & 63;
  float s = 0.f;
  #pragma unroll
  for(int dy=-1;dy<=1;dy++){
    const int yy = y+dy;
    if(yy<0||yy>=HH) continue;
    #pragma unroll
    for(int dx=-1;dx<=1;dx++){
      const int xx = x+dx;
      if(xx<0||xx>=WW) continue;
      s += fgz[(size_t)(yy*WW+xx)*64 + c];
    }
  }
  PfgH1[((size_t)z*L + l)*NC + c] = (_Float16)s;
}

__global__ __launch_bounds__(256) void build_bhat3(const float* __restrict__ fgT,
                                                   const float* __restrict__ mask,
                                                   _Float16* __restrict__ BhatH3,
                                                   float* __restrict__ rn3){
  const int t = threadIdx.x, c = t & 63, sub = t >> 6;
  const int l = blockIdx.x*4 + sub, z = blockIdx.y;
  const float* fgz = fgT + (size_t)z*L*64;
  const float* mz  = mask + (size_t)z*L;
  const int y = l >> 6, x = l & 63;
  float K[9]; float ss = 0.f;
  #pragma unroll
  for(int i=0;i<3;i++){
    #pragma unroll
    for(int j=0;j<3;j++){
      const int yy = y+i-1, xx = x+j-1;
      float v = 0.f;
      if(yy>=0&&yy<HH&&xx>=0&&xx<WW){
        const int q = yy*WW+xx;
        v = fgz[(size_t)q*64 + c]*(1.0f - mz[q]);
      }
      v += 1e-7f;
      K[i*3+j] = v; ss += v*v;
    }
  }
  ss = wave_sum(ss);
  const float rn = rsqrtf(ss);
  _Float16* outp = BhatH3 + ((size_t)z*L + l)*D3 + c*9;
  #pragma unroll
  for(int k=0;k<9;k++) outp[k] = (_Float16)(K[k]*rn);
  if(c==0) rn3[(size_t)z*L + l] = rn;
}

__global__ __launch_bounds__(256) void build_pfgbox3(const float* __restrict__ fgT,
                                                     _Float16* __restrict__ PfgH3){
  const int t = threadIdx.x, c = t & 63, sub = t >> 6;
  const int l = blockIdx.x*4 + sub, z = blockIdx.y;
  const float* fgz = fgT + (size_t)z*L*64;
  const int y = l >> 6, x = l & 63;
  float Wn[5][5];
  #pragma unroll
  for(int u=0;u<5;u++){
    const int yy = y+u-2;
    #pragma unroll
    for(int v=0;v<5;v++){
      const int xx = x+v-2;
      Wn[u][v] = (yy>=0 && yy<HH && xx>=0 && xx<WW) ? fgz[(size_t)(yy*WW+xx)*64 + c] : 0.f;
    }
  }
  const bool dyok[3] = { y-1>=0, true, y+1<HH };
  const bool dxok[3] = { x-1>=0, true, x+1<WW };
  _Float16* outp = PfgH3 + ((size_t)z*L + l)*D3 + c*9;
  #pragma unroll
  for(int i=0;i<3;i++){
    #pragma unroll
    for(int j=0;j<3;j++){
      float acc = 0.f;
      #pragma unroll
      for(int a=0;a<3;a++){
        if(!dyok[a]) continue;
        #pragma unroll
        for(int b=0;b<3;b++){
          if(!dxok[b]) continue;
          acc += Wn[i+a][j+b];
        }
      }
      outp[i*3+j] = (_Float16)acc;
    }
  }
}

__global__ __launch_bounds__(256) void zero_h(_Float16* __restrict__ p, size_t n){
  const size_t i = (size_t)blockIdx.x*256 + threadIdx.x;
  if(i < n) p[i] = (_Float16)0.f;
}

__global__ __launch_bounds__(256) void transpose_h(const ushort* __restrict__ src,
                                                   ushort* __restrict__ dst,
                                                   int C, size_t sSz, size_t sDz){
  __shared__ ushort tile[64][65];
  const int z = blockIdx.z;
  src += z*sSz; dst += z*sDz;
  const int bc = blockIdx.x*64, br = blockIdx.y*64;
  const int tx = threadIdx.x & 15, ty = threadIdx.x >> 4;
  #pragma unroll
  for(int i=0;i<4;i++){
    const ushort4 v = *(const ushort4*)(src + (size_t)(br+ty+16*i)*C + bc + tx*4);
    tile[ty+16*i][tx*4+0] = v.x;
    tile[ty+16*i][tx*4+1] = v.y;
    tile[ty+16*i][tx*4+2] = v.z;
    tile[ty+16*i][tx*4+3] = v.w;
  }
  __syncthreads();
  #pragma unroll
  for(int i=0;i<4;i++){
    ushort4 o;
    o.x = tile[tx*4+0][ty+16*i];
    o.y = tile[tx*4+1][ty+16*i];
    o.z = tile[tx*4+2][ty+16*i];
    o.w = tile[tx*4+3][ty+16*i];
    *(ushort4*)(dst + (size_t)(bc+ty+16*i)*L + br + tx*4) = o;
  }
}

template<int OM, int KS>
__global__ __launch_bounds__(256) void gemm_h16(const _Float16* __restrict__ A, int lda, size_t sAz,
                                                const _Float16* __restrict__ B, int ldb, size_t sBz,
                                                void* __restrict__ C, int ldc, size_t sCz,
                                                int K, size_t sPart){
  __shared__ _Float16 As[128*64];
  __shared__ _Float16 Bs[128*64];
  const int zz = blockIdx.z;
  const int z = zz / KS, ks = zz % KS;
  const int Kp = K / KS;
  A += (size_t)z*sAz + (size_t)ks*Kp;
  B += (size_t)z*sBz + (size_t)ks*Kp;
  const int bm = blockIdx.y*128, bn = blockIdx.x*128;
  const int t = threadIdx.x, lane = t & 63, wave = t >> 6;
  const int wr = wave >> 1, wc = wave & 1;
  const int r16 = lane & 15, g4 = lane >> 4;
  const int srow = t >> 3;
  const int schunk = t & 7;
  f32x4 acc[4][4] = {};
  for(int k0=0;k0<Kp;k0+=64){
    #pragma unroll
    for(int u=0;u<4;u++){
      const int rowA = u*32 + srow;
      const int colh = ((schunk ^ (rowA & 7)) << 3);
      gload16(A + (size_t)(bm+rowA)*lda + k0 + colh, (char*)As + u*4096 + wave*1024);
      gload16(B + (size_t)(bn+rowA)*ldb + k0 + colh, (char*)Bs + u*4096 + wave*1024);
    }
    __syncthreads();
    #pragma unroll
    for(int kk=0;kk<2;kk++){
      f16x8 af[4], bf[4];
      #pragma unroll
      for(int i=0;i<4;i++){
        const int row = wr*64 + i*16 + r16;
        const int off = ((row<<7) + kk*64 + (g4<<4)) ^ ((row&7)<<4);
        af[i] = *(const f16x8*)((const char*)As + off);
      }
      #pragma unroll
      for(int j=0;j<4;j++){
        const int row = wc*64 + j*16 + r16;
        const int off = ((row<<7) + kk*64 + (g4<<4)) ^ ((row&7)<<4);
        bf[j] = *(const f16x8*)((const char*)Bs + off);
      }
      #pragma unroll
      for(int i=0;i<4;i++)
        #pragma unroll
        for(int j=0;j<4;j++)
          acc[i][j] = __builtin_amdgcn_mfma_f32_16x16x32_f16(af[i], bf[j], acc[i][j], 0, 0, 0);
    }
    __syncthreads();
  }
  if(OM==0){
    float* Cz = (float*)C + (size_t)ks*sPart + (size_t)z*sCz;
    #pragma unroll
    for(int i=0;i<4;i++){
      const int row0 = bm + wr*64 + i*16 + g4*4;
      #pragma unroll
      for(int j=0;j<4;j++){
        const int col = bn + wc*64 + j*16 + r16;
        #pragma unroll
        for(int r=0;r<4;r++)
          Cz[(size_t)(row0+r)*ldc + col] = acc[i][j][r];
      }
    }
  } else {
    _Float16* Cz = (_Float16*)C + (size_t)z*sCz;
    #pragma unroll
    for(int i=0;i<4;i++){
      const int row0 = bm + wr*64 + i*16 + g4*4;
      #pragma unroll
      for(int j=0;j<4;j++){
        const int col = bn + wc*64 + j*16 + r16;
        #pragma unroll
        for(int r=0;r<4;r++)
          Cz[(size_t)(row0+r)*ldc + col] = (_Float16)acc[i][j][r];
      }
    }
  }
}

__global__ __launch_bounds__(256) void softmax16(_Float16* __restrict__ S){
  __shared__ float red[4];
  _Float16* p = S + ((size_t)blockIdx.y*L + blockIdx.x)*L;
  const int t = threadIdx.x;
  float v[16];
  {
    const f16x8 a = *(const f16x8*)(p + t*16);
    const f16x8 b = *(const f16x8*)(p + t*16 + 8);
    #pragma unroll
    for(int i=0;i<8;i++){ v[i] = (float)a[i]; v[8+i] = (float)b[i]; }
  }
  float mx = -3.0e38f;
  #pragma unroll
  for(int i=0;i<16;i++) mx = fmaxf(mx, v[i]);
  mx = wave_max(mx);
  if((t&63)==0) red[t>>6]=mx;
  __syncthreads();
  mx = fmaxf(fmaxf(red[0],red[1]), fmaxf(red[2],red[3]));
  __syncthreads();
  float s = 0.f;
  #pragma unroll
  for(int i=0;i<16;i++){ v[i] = __expf(v[i]-mx); s += v[i]; }
  s = wave_sum(s);
  if((t&63)==0) red[t>>6]=s;
  __syncthreads();
  s = red[0]+red[1]+red[2]+red[3];
  const float inv = 1.0f/s;
  f16x8 a, b;
  #pragma unroll
  for(int i=0;i<8;i++){ a[i] = (_Float16)(v[i]*inv); b[i] = (_Float16)(v[8+i]*inv); }
  *(f16x8*)(p + t*16) = a;
  *(f16x8*)(p + t*16 + 8) = b;
}

__global__ __launch_bounds__(256) void softmax_rn(_Float16* __restrict__ S,
                                                  const float* __restrict__ rn3,
                                                  float* __restrict__ Tq){
  __shared__ float red[4];
  const int q = blockIdx.x, z = blockIdx.y, t = threadIdx.x;
  _Float16* p = S + ((size_t)z*L + q)*L;
  float v[16];
  {
    const f16x8 a = *(const f16x8*)(p + t*16);
    const f16x8 b = *(const f16x8*)(p + t*16 + 8);
    #pragma unroll
    for(int i=0;i<8;i++){ v[i] = (float)a[i]; v[8+i] = (float)b[i]; }
  }
  float mx = -3.0e38f;
  #pragma unroll
  for(int i=0;i<16;i++) mx = fmaxf(mx, v[i]);
  mx = wave_max(mx);
  if((t&63)==0) red[t>>6]=mx;
  __syncthreads();
  mx = fmaxf(fmaxf(red[0],red[1]), fmaxf(red[2],red[3]));
  __syncthreads();
  float s = 0.f;
  #pragma unroll
  for(int i=0;i<16;i++){ v[i] = __expf(v[i]-mx); s += v[i]; }
  s = wave_sum(s);
  if((t&63)==0) red[t>>6]=s;
  __syncthreads();
  s = red[0]+red[1]+red[2]+red[3];
  __syncthreads();
  const float inv = 1.0f/s;
  const float* rnz = rn3 + (size_t)z*L + t*16;
  float T = 0.f;
  f16x8 a, b;
  #pragma unroll
  for(int i=0;i<8;i++){
    const float w0 = v[i]*inv*rnz[i];
    const float w1 = v[8+i]*inv*rnz[8+i];
    T += w0 + w1;
    a[i] = (_Float16)(w0*ASCALE);
    b[i] = (_Float16)(w1*ASCALE);
  }
  *(f16x8*)(p + t*16) = a;
  *(f16x8*)(p + t*16 + 8) = b;
  T = wave_sum(T);
  if((t&63)==0) red[t>>6]=T;
  __syncthreads();
  if(t==0) Tq[(size_t)z*L + q] = red[0]+red[1]+red[2]+red[3];
}

// out[a,m] = sum_{d=-1..1} [x-valid] in[a+d, m+d]
__global__ __launch_bounds__(256) void dx_pass(const _Float16* __restrict__ in,
                                               _Float16* __restrict__ out){
  const int a = blockIdx.x, z = blockIdx.y, t = threadIdx.x;
  const size_t rb = ((size_t)z*L + a)*(size_t)L;
  const int m0 = t*16, x0 = m0 & 63, xa = a & 63;
  float o[16];
  {
    const f16x8 r0 = *(const f16x8*)(in + rb + m0);
    const f16x8 r1 = *(const f16x8*)(in + rb + m0 + 8);
    #pragma unroll
    for(int i=0;i<8;i++){ o[i] = (float)r0[i]; o[8+i] = (float)r1[i]; }
  }
  if(xa != 0){
    const _Float16* pm = in + rb - L;
    const f16x8 b0 = *(const f16x8*)(pm + m0);
    const f16x8 b1 = *(const f16x8*)(pm + m0 + 8);
    o[0] += (x0 != 0) ? (float)pm[m0-1] : 0.f;
    #pragma unroll
    for(int i=1;i<8;i++) o[i] += (float)b0[i-1];
    o[8] += (float)b0[7];
    #pragma unroll
    for(int i=9;i<16;i++) o[i] += (float)b1[i-9];
  }
  if(xa != 63){
    const _Float16* pp = in + rb + L;
    const f16x8 c0 = *(const f16x8*)(pp + m0);
    const f16x8 c1 = *(const f16x8*)(pp + m0 + 8);
    #pragma unroll
    for(int i=0;i<7;i++) o[i] += (float)c0[i+1];
    o[7] += (float)c1[0];
    #pragma unroll
    for(int i=8;i<15;i++) o[i] += (float)c1[i-7];
    o[15] += (x0 != 48) ? (float)pp[m0+16] : 0.f;
  }
  f16x8 w0, w1;
  #pragma unroll
  for(int i=0;i<8;i++){ w0[i] = (_Float16)o[i]; w1[i] = (_Float16)o[8+i]; }
  *(f16x8*)(out + rb + m0) = w0;
  *(f16x8*)(out + rb + m0 + 8) = w1;
}

// out[a,m] = sum_{d=-1..1} [y-valid] in[a+64d, m+64d]
__global__ __launch_bounds__(256) void dy_pass(const _Float16* __restrict__ in,
                                               _Float16* __restrict__ out){
  const int a = blockIdx.x, z = blockIdx.y, t = threadIdx.x;
  const size_t rb = ((size_t)z*L + a)*(size_t)L;
  const int m0 = t*16, ym = m0 >> 6, ya = a >> 6;
  float o[16];
  {
    const f16x8 r0 = *(const f16x8*)(in + rb + m0);
    const f16x8 r1 = *(const f16x8*)(in + rb + m0 + 8);
    #pragma unroll
    for(int i=0;i<8;i++){ o[i] = (float)r0[i]; o[8+i] = (float)r1[i]; }
  }
  if(ya != 0 && ym != 0){
    const _Float16* pm = in + rb - (size_t)64*L + m0 - 64;
    const f16x8 b0 = *(const f16x8*)(pm);
    const f16x8 b1 = *(const f16x8*)(pm + 8);
    #pragma unroll
    for(int i=0;i<8;i++){ o[i] += (float)b0[i]; o[8+i] += (float)b1[i]; }
  }
  if(ya != 63 && ym != 63){
    const _Float16* pp = in + rb + (size_t)64*L + m0 + 64;
    const f16x8 c0 = *(const f16x8*)(pp);
    const f16x8 c1 = *(const f16x8*)(pp + 8);
    #pragma unroll
    for(int i=0;i<8;i++){ o[i] += (float)c0[i]; o[8+i] += (float)c1[i]; }
  }
  f16x8 w0, w1;
  #pragma unroll
  for(int i=0;i<8;i++){ w0[i] = (_Float16)o[i]; w1[i] = (_Float16)o[8+i]; }
  *(f16x8*)(out + rb + m0) = w0;
  *(f16x8*)(out + rb + m0 + 8) = w1;
}

template<int KS>
__global__ __launch_bounds__(256) void red_k(const float* __restrict__ Cp,
                                             float* __restrict__ R,
                                             size_t sPart, size_t n){
  const size_t i = (size_t)blockIdx.x*256 + threadIdx.x;
  if(i >= n) return;
  float s = 0.f;
  #pragma unroll
  for(int k=0;k<KS;k++) s += Cp[(size_t)k*sPart + i];
  R[i] = s;
}

__global__ __launch_bounds__(256) void scatter_p1n(const float* __restrict__ R,
                                                   const float* __restrict__ fgT,
                                                   const float* __restrict__ mask,
                                                   float* __restrict__ outs){
  const int z = blockIdx.y, t = threadIdx.x;
  const int q = blockIdx.x*4 + (t>>6), c = t & 63;
  const float m = mask[(size_t)z*L + q];
  const float rec = R[((size_t)z*L + q)*128 + c];
  const float f = fgT[((size_t)z*L + q)*64 + c];
  outs[((size_t)z*L + q)*128 + c] = rec*m + f*(1.0f-m);
}

__global__ __launch_bounds__(256) void scatter_p3n(const float* __restrict__ R,
                                                   const float* __restrict__ Tq,
                                                   const float* __restrict__ fgT,
                                                   const float* __restrict__ mask,
                                                   float* __restrict__ outs){
  const int z = blockIdx.y, t = threadIdx.x;
  const int q = blockIdx.x*4 + (t>>6), c = t & 63;
  const int y = q >> 6, x = q & 63;
  float tb = 0.f;
  #pragma unroll
  for(int dy=-1;dy<=1;dy++){
    const int yy = y+dy;
    if(yy<0||yy>=64) continue;
    #pragma unroll
    for(int dx=-1;dx<=1;dx++){
      const int xx = x+dx;
      if(xx<0||xx>=64) continue;
      tb += Tq[(size_t)z*L + yy*64+xx];
    }
  }
  const float m = mask[(size_t)z*L + q];
  const float rec = R[((size_t)z*L + q)*128 + c] + 1e-7f*tb;
  const float f = fgT[((size_t)z*L + q)*64 + c];
  outs[((size_t)z*L + q)*128 + 64 + c] = rec*(m*(1.0f/9.0f)) + f*(1.0f-m);
}

__global__ __launch_bounds__(256) void se_partial(const float* __restrict__ outs,
                                                  float* __restrict__ part){
  const int z = blockIdx.y, t = threadIdx.x;
  const int ch = t & 127, h = t >> 7;
  const int qb = blockIdx.x*128 + h*64;
  float s = 0.f;
  for(int j=0;j<64;j++) s += outs[((size_t)z*L + qb + j)*128 + ch];
  part[((size_t)z*64 + blockIdx.x*2 + h)*128 + ch] = s;
}

__global__ __launch_bounds__(128) void se_mlp(const float* __restrict__ part,
                                              const float* __restrict__ W1, const float* __restrict__ b1,
                                              const float* __restrict__ W2, const float* __restrict__ b2,
                                              float* __restrict__ g){
  __shared__ float s[128], h[128];
  const int z = blockIdx.x, i = threadIdx.x;
  float acc0 = 0.f;
  for(int j=0;j<64;j++) acc0 += part[((size_t)z*64 + j)*128 + i];
  s[i] = acc0*(1.0f/4096.0f);
  __syncthreads();
  float a = b1[i];
  const float* w = W1 + (size_t)i*128;
  for(int j=0;j<128;j++) a = fmaf(w[j], s[j], a);
  h[i] = fmaxf(a, 0.f);
  __syncthreads();
  float o = b2[i];
  w = W2 + (size_t)i*128;
  for(int j=0;j<128;j++) o = fmaf(w[j], h[j], o);
  g[z*128+i] = 1.0f/(1.0f + __expf(-o));
}

__global__ __launch_bounds__(256) void combiner(const float* __restrict__ outs,
                                                const float* __restrict__ g,
                                                const float* __restrict__ Wc,
                                                const float* __restrict__ bc,
                                                float* __restrict__ out){
  const size_t idx = (size_t)blockIdx.x*256 + threadIdx.x;
  const int q = (int)(idx & 4095);
  const int o = (int)((idx >> 12) & 63);
  const int z = (int)(idx >> 18);
  const float* ob = outs + ((size_t)z*L + q)*128;
  const float* gz = g + z*128;
  const float* wr = Wc + (size_t)o*128;
  float acc = bc[o];
  for(int ch=0; ch<128; ++ch) acc = fmaf(ob[ch]*gz[ch], wr[ch], acc);
  out[idx] = acc;
}

extern "C" void kernel_launch(void* const* d_in, const int* in_sizes, int n_in,
                              void* d_out, int out_size, void* d_ws, size_t ws_size,
                              hipStream_t stream){
  const float* fg   = (const float*)d_in[0];
  const float* mask = (const float*)d_in[1];
  const float* W1   = (const float*)d_in[2];
  const float* b1   = (const float*)d_in[3];
  const float* W2   = (const float*)d_in[4];
  const float* b2   = (const float*)d_in[5];
  const float* Wc   = (const float*)d_in[6];
  const float* bc   = (const float*)d_in[7];
  float* out = (float*)d_out;

  char* w = (char*)d_ws;
  size_t off = 0;
  auto alloc = [&](size_t bytes)->void*{
    void* p = (void*)(w + off);
    off += (bytes + 255) & ~(size_t)255;
    return p;
  };
  _Float16* S    = (_Float16*)alloc(2ull*L*L*2);   // scores / att / A'' / G
  _Float16* DxB  = (_Float16*)alloc(2ull*L*L*2);   // Dx intermediate
  float* Cp    = (float*)alloc(8ull*2*L*128*4);    // split-K partials
  float* Rbuf1 = (float*)alloc(2ull*L*128*4);
  float* RbufG = (float*)alloc(2ull*L*128*4);
  float* outs  = (float*)alloc(2ull*L*128*4);
  float* fgT   = (float*)alloc(2ull*L*64*4);
  _Float16* BhatH1 = (_Float16*)alloc(2ull*L*64*2);
  _Float16* BhatT1 = (_Float16*)alloc(2ull*128*L*2);
  _Float16* PfgH1  = (_Float16*)alloc(2ull*L*64*2);
  _Float16* BhatH3 = (_Float16*)alloc(2ull*L*D3*2);
  _Float16* PfgH3  = (_Float16*)alloc(2ull*L*D3*2);
  _Float16* bgH    = (_Float16*)alloc(2ull*128*L*2);
  float* rn3v = (float*)alloc(2ull*L*4);
  float* Tq   = (float*)alloc(2ull*L*4);
  float* part = (float*)alloc(2ull*64*128*4);
  float* gbuf = (float*)alloc(1024);
  const size_t sPart = 2ull*L*128;

  transpose_fg<<<dim3(64,2),256,0,stream>>>(fg, fgT);

  // ================= p=1 branch =================
  build_p1<<<dim3(L/4,2),256,0,stream>>>(fgT, mask, BhatH1, PfgH1);
  zero_h<<<(unsigned)((2ull*128*L+255)/256),256,0,stream>>>(BhatT1, 2ull*128*L);
  transpose_h<<<dim3(1,64,2),256,0,stream>>>((const ushort*)BhatH1, (ushort*)BhatT1,
                                             64, (size_t)L*64, (size_t)128*L);
  gemm_h16<2,1><<<dim3(32,32,2),256,0,stream>>>(
      PfgH1, 64, (size_t)L*64,
      BhatH1, 64, (size_t)L*64,
      (void*)S, L, (size_t)L*L, 64, 0);
  softmax16<<<dim3(L,2),256,0,stream>>>(S);
  gemm_h16<0,8><<<dim3(1,32,16),256,0,stream>>>(
      S, L, (size_t)L*L,
      BhatT1, L, (size_t)128*L,
      (void*)Cp, 128, (size_t)L*128, L, sPart);
  red_k<8><<<(unsigned)((sPart+255)/256),256,0,stream>>>(Cp, Rbuf1, sPart, sPart);
  scatter_p1n<<<dim3(L/4,2),256,0,stream>>>(Rbuf1, fgT, mask, outs);

  // ================= p=3 branch =================
  build_bhat3  <<<dim3(L/4,2),256,0,stream>>>(fgT, mask, BhatH3, rn3v);
  build_pfgbox3<<<dim3(L/4,2),256,0,stream>>>(fgT, PfgH3);
  bg_build<<<dim3(128,2),256,0,stream>>>(fg, mask, bgH);
  gemm_h16<2,1><<<dim3(32,32,2),256,0,stream>>>(
      PfgH3, D3, (size_t)L*D3,
      BhatH3, D3, (size_t)L*D3,
      (void*)S, L, (size_t)L*L, D3, 0);
  softmax_rn<<<dim3(L,2),256,0,stream>>>(S, rn3v, Tq);
  dx_pass<<<dim3(L,2),256,0,stream>>>(S, DxB);
  dy_pass<<<dim3(L,2),256,0,stream>>>(DxB, S);
  gemm_h16<0,8><<<dim3(1,32,16),256,0,stream>>>(
      S, L, (size_t)L*L,
      bgH, L, (size_t)128*L,
      (void*)Cp, 128, (size_t)L*128, L, sPart);
  red_k<8><<<(unsigned)((sPart+255)/256),256,0,stream>>>(Cp, RbufG, sPart, sPart);
  scatter_p3n<<<dim3(L/4,2),256,0,stream>>>(RbufG, Tq, fgT, mask, outs);

  // ================= SE + combiner =================
  se_partial<<<dim3(32,2),256,0,stream>>>(outs, part);
  se_mlp<<<2,128,0,stream>>>(part, W1, b1, W2, b2, gbuf);
  combiner<<<(2*64*L)/256,256,0,stream>>>(outs, gbuf, Wc, bc, out);
}

// Round 7
// 300.473 us; speedup vs baseline: 2.9133x; 1.0758x over previous
//
#include <hip/hip_runtime.h>
#include <math.h>

#define WW 64
#define HH 64
#define L 4096
#define NC 64
#define D3 576
#define ASCALE (1.0f/128.0f)

typedef _Float16 f16x8 __attribute__((ext_vector_type(8)));
typedef float    f32x4 __attribute__((ext_vector_type(4)));

__device__ __forceinline__ float wave_max(float v){
  #pragma unroll
  for(int o=32;o;o>>=1) v = fmaxf(v, __shfl_xor(v,o));
  return v;
}
__device__ __forceinline__ float wave_sum(float v){
  #pragma unroll
  for(int o=32;o;o>>=1) v += __shfl_xor(v,o);
  return v;
}
__device__ __forceinline__ void gload16(const void* g, void* l){
  __builtin_amdgcn_global_load_lds((const __attribute__((address_space(1))) unsigned int*)g,
                                   (__attribute__((address_space(3))) unsigned int*)l,
                                   16, 0, 0);
}

__global__ __launch_bounds__(256) void transpose_fg(const float* __restrict__ fg,
                                                    float* __restrict__ fgT){
  __shared__ float tile[64][65];
  const int z = blockIdx.y;
  const int q0 = blockIdx.x*64;
  const int tx = threadIdx.x & 63, ty = threadIdx.x >> 6;
  #pragma unroll
  for(int i=0;i<16;i++){
    const int c = ty*16 + i;
    tile[c][tx] = fg[((size_t)z*64 + c)*L + q0 + tx];
  }
  __syncthreads();
  #pragma unroll
  for(int i=0;i<16;i++){
    const int q = ty*16 + i;
    fgT[((size_t)z*L + q0 + q)*64 + tx] = tile[tx][q];
  }
}

__global__ __launch_bounds__(256) void bg_build(const float* __restrict__ fg,
                                                const float* __restrict__ mask,
                                                _Float16* __restrict__ bgH){
  const int row = blockIdx.x, z = blockIdx.y, t = threadIdx.x;
  const int l0 = t*16;
  f16x8 o0, o1;
  if(row < 64){
    const float* fp = fg + ((size_t)z*64 + row)*L + l0;
    const float* mp = mask + (size_t)z*L + l0;
    #pragma unroll
    for(int i=0;i<8;i++){
      o0[i] = (_Float16)(fp[i]*(1.0f-mp[i])*128.0f);
      o1[i] = (_Float16)(fp[8+i]*(1.0f-mp[8+i])*128.0f);
    }
  } else {
    #pragma unroll
    for(int i=0;i<8;i++){ o0[i]=(_Float16)0.f; o1[i]=(_Float16)0.f; }
  }
  _Float16* op = bgH + ((size_t)z*128 + row)*L + l0;
  *(f16x8*)op = o0;
  *(f16x8*)(op+8) = o1;
}

__global__ __launch_bounds__(256) void build_p1(const float* __restrict__ fgT,
                                               const float* __restrict__ mask,
                                               _Float16* __restrict__ BhatH1,
                                               _Float16* __restrict__ PfgH1){
  const int t = threadIdx.x, c = t & 63, sub = t >> 6;
  const int l = blockIdx.x*4 + sub, z = blockIdx.y;
  const float* fgz = fgT + (size_t)z*L*64;
  const float m = mask[(size_t)z*L + l];
  const float K = fgz[(size_t)l*64 + c]*(1.0f-m) + 1e-7f;
  const float ss = wave_sum(K*K);
  BhatH1[((size_t)z*L + l)*NC + c] = (_Float16)(K*rsqrtf(ss));
  const int y = l >> 6, x = l & 63;
  float s = 0.f;
  #pragma unroll
  for(int dy=-1;dy<=1;dy++){
    const int yy = y+dy;
    if(yy<0||yy>=HH) continue;
    #pragma unroll
    for(int dx=-1;dx<=1;dx++){
      const int xx = x+dx;
      if(xx<0||xx>=WW) continue;
      s += fgz[(size_t)(yy*WW+xx)*64 + c];
    }
  }
  PfgH1[((size_t)z*L + l)*NC + c] = (_Float16)s;
}

__global__ __launch_bounds__(256) void build_bhat3(const float* __restrict__ fgT,
                                                   const float* __restrict__ mask,
                                                   _Float16* __restrict__ BhatH3,
                                                   float* __restrict__ rn3){
  const int t = threadIdx.x, c = t & 63, sub = t >> 6;
  const int l = blockIdx.x*4 + sub, z = blockIdx.y;
  const float* fgz = fgT + (size_t)z*L*64;
  const float* mz  = mask + (size_t)z*L;
  const int y = l >> 6, x = l & 63;
  float K[9]; float ss = 0.f;
  #pragma unroll
  for(int i=0;i<3;i++){
    #pragma unroll
    for(int j=0;j<3;j++){
      const int yy = y+i-1, xx = x+j-1;
      float v = 0.f;
      if(yy>=0&&yy<HH&&xx>=0&&xx<WW){
        const int q = yy*WW+xx;
        v = fgz[(size_t)q*64 + c]*(1.0f - mz[q]);
      }
      v += 1e-7f;
      K[i*3+j] = v; ss += v*v;
    }
  }
  ss = wave_sum(ss);
  const float rn = rsqrtf(ss);
  _Float16* outp = BhatH3 + ((size_t)z*L + l)*D3 + c*9;
  #pragma unroll
  for(int k=0;k<9;k++) outp[k] = (_Float16)(K[k]*rn);
  if(c==0) rn3[(size_t)z*L + l] = rn;
}

__global__ __launch_bounds__(256) void build_pfgbox3(const float* __restrict__ fgT,
                                                     _Float16* __restrict__ PfgH3){
  const int t = threadIdx.x, c = t & 63, sub = t >> 6;
  const int l = blockIdx.x*4 + sub, z = blockIdx.y;
  const float* fgz = fgT + (size_t)z*L*64;
  const int y = l >> 6, x = l & 63;
  float Wn[5][5];
  #pragma unroll
  for(int u=0;u<5;u++){
    const int yy = y+u-2;
    #pragma unroll
    for(int v=0;v<5;v++){
      const int xx = x+v-2;
      Wn[u][v] = (yy>=0 && yy<HH && xx>=0 && xx<WW) ? fgz[(size_t)(yy*WW+xx)*64 + c] : 0.f;
    }
  }
  const bool dyok[3] = { y-1>=0, true, y+1<HH };
  const bool dxok[3] = { x-1>=0, true, x+1<WW };
  _Float16* outp = PfgH3 + ((size_t)z*L + l)*D3 + c*9;
  #pragma unroll
  for(int i=0;i<3;i++){
    #pragma unroll
    for(int j=0;j<3;j++){
      float acc = 0.f;
      #pragma unroll
      for(int a=0;a<3;a++){
        if(!dyok[a]) continue;
        #pragma unroll
        for(int b=0;b<3;b++){
          if(!dxok[b]) continue;
          acc += Wn[i+a][j+b];
        }
      }
      outp[i*3+j] = (_Float16)acc;
    }
  }
}

__global__ __launch_bounds__(256) void zero_h(_Float16* __restrict__ p, size_t n){
  const size_t i = (size_t)blockIdx.x*256 + threadIdx.x;
  if(i < n) p[i] = (_Float16)0.f;
}

__global__ __launch_bounds__(256) void transpose_h(const ushort* __restrict__ src,
                                                   ushort* __restrict__ dst,
                                                   int C, size_t sSz, size_t sDz){
  __shared__ ushort tile[64][65];
  const int z = blockIdx.z;
  src += z*sSz; dst += z*sDz;
  const int bc = blockIdx.x*64, br = blockIdx.y*64;
  const int tx = threadIdx.x & 15, ty = threadIdx.x >> 4;
  #pragma unroll
  for(int i=0;i<4;i++){
    const ushort4 v = *(const ushort4*)(src + (size_t)(br+ty+16*i)*C + bc + tx*4);
    tile[ty+16*i][tx*4+0] = v.x;
    tile[ty+16*i][tx*4+1] = v.y;
    tile[ty+16*i][tx*4+2] = v.z;
    tile[ty+16*i][tx*4+3] = v.w;
  }
  __syncthreads();
  #pragma unroll
  for(int i=0;i<4;i++){
    ushort4 o;
    o.x = tile[tx*4+0][ty+16*i];
    o.y = tile[tx*4+1][ty+16*i];
    o.z = tile[tx*4+2][ty+16*i];
    o.w = tile[tx*4+3][ty+16*i];
    *(ushort4*)(dst + (size_t)(bc+ty+16*i)*L + br + tx*4) = o;
  }
}

// OM=0: f32 split-K partials; OM=2: fp16 output with vectorized LDS-transpose epilogue
template<int OM, int KS>
__global__ __launch_bounds__(256) void gemm_h16(const _Float16* __restrict__ A, int lda, size_t sAz,
                                                const _Float16* __restrict__ B, int ldb, size_t sBz,
                                                void* __restrict__ C, int ldc, size_t sCz,
                                                int K, size_t sPart){
  __shared__ _Float16 sh[17408];   // As(8192) + Bs(8192); reused as 128x136 fp16 C-tile
  _Float16* As = sh;
  _Float16* Bs = sh + 8192;
  const int zz = blockIdx.z;
  const int z = zz / KS, ks = zz % KS;
  const int Kp = K / KS;
  A += (size_t)z*sAz + (size_t)ks*Kp;
  B += (size_t)z*sBz + (size_t)ks*Kp;
  const int bm = blockIdx.y*128, bn = blockIdx.x*128;
  const int t = threadIdx.x, lane = t & 63, wave = t >> 6;
  const int wr = wave >> 1, wc = wave & 1;
  const int r16 = lane & 15, g4 = lane >> 4;
  const int srow = t >> 3;
  const int schunk = t & 7;
  f32x4 acc[4][4] = {};
  for(int k0=0;k0<Kp;k0+=64){
    #pragma unroll
    for(int u=0;u<4;u++){
      const int rowA = u*32 + srow;
      const int colh = ((schunk ^ (rowA & 7)) << 3);
      gload16(A + (size_t)(bm+rowA)*lda + k0 + colh, (char*)As + u*4096 + wave*1024);
      gload16(B + (size_t)(bn+rowA)*ldb + k0 + colh, (char*)Bs + u*4096 + wave*1024);
    }
    __syncthreads();
    #pragma unroll
    for(int kk=0;kk<2;kk++){
      f16x8 af[4], bf[4];
      #pragma unroll
      for(int i=0;i<4;i++){
        const int row = wr*64 + i*16 + r16;
        const int off = ((row<<7) + kk*64 + (g4<<4)) ^ ((row&7)<<4);
        af[i] = *(const f16x8*)((const char*)As + off);
      }
      #pragma unroll
      for(int j=0;j<4;j++){
        const int row = wc*64 + j*16 + r16;
        const int off = ((row<<7) + kk*64 + (g4<<4)) ^ ((row&7)<<4);
        bf[j] = *(const f16x8*)((const char*)Bs + off);
      }
      #pragma unroll
      for(int i=0;i<4;i++)
        #pragma unroll
        for(int j=0;j<4;j++)
          acc[i][j] = __builtin_amdgcn_mfma_f32_16x16x32_f16(af[i], bf[j], acc[i][j], 0, 0, 0);
    }
    __syncthreads();
  }
  if(OM==0){
    float* Cz = (float*)C + (size_t)ks*sPart + (size_t)z*sCz;
    #pragma unroll
    for(int i=0;i<4;i++){
      const int row0 = bm + wr*64 + i*16 + g4*4;
      #pragma unroll
      for(int j=0;j<4;j++){
        const int col = bn + wc*64 + j*16 + r16;
        #pragma unroll
        for(int r=0;r<4;r++)
          Cz[(size_t)(row0+r)*ldc + col] = acc[i][j][r];
      }
    }
  } else {
    // vectorized fp16 epilogue: acc -> LDS (128x136) -> f16x8 coalesced stores
    _Float16* Cz = (_Float16*)C + (size_t)z*sCz;
    #pragma unroll
    for(int i=0;i<4;i++){
      const int row0 = wr*64 + i*16 + g4*4;
      #pragma unroll
      for(int j=0;j<4;j++){
        const int col = wc*64 + j*16 + r16;
        #pragma unroll
        for(int r=0;r<4;r++)
          sh[(row0+r)*136 + col] = (_Float16)acc[i][j][r];
      }
    }
    __syncthreads();
    #pragma unroll
    for(int k=0;k<8;k++){
      const int row = k*16 + (t>>4);
      const int cg = (t&15)*8;
      const f16x8 v = *(const f16x8*)(sh + row*136 + cg);
      *(f16x8*)(Cz + (size_t)(bm+row)*ldc + bn + cg) = v;
    }
  }
}

__global__ __launch_bounds__(256) void softmax16(_Float16* __restrict__ S){
  __shared__ float red[4];
  _Float16* p = S + ((size_t)blockIdx.y*L + blockIdx.x)*L;
  const int t = threadIdx.x;
  float v[16];
  {
    const f16x8 a = *(const f16x8*)(p + t*16);
    const f16x8 b = *(const f16x8*)(p + t*16 + 8);
    #pragma unroll
    for(int i=0;i<8;i++){ v[i] = (float)a[i]; v[8+i] = (float)b[i]; }
  }
  float mx = -3.0e38f;
  #pragma unroll
  for(int i=0;i<16;i++) mx = fmaxf(mx, v[i]);
  mx = wave_max(mx);
  if((t&63)==0) red[t>>6]=mx;
  __syncthreads();
  mx = fmaxf(fmaxf(red[0],red[1]), fmaxf(red[2],red[3]));
  __syncthreads();
  float s = 0.f;
  #pragma unroll
  for(int i=0;i<16;i++){ v[i] = __expf(v[i]-mx); s += v[i]; }
  s = wave_sum(s);
  if((t&63)==0) red[t>>6]=s;
  __syncthreads();
  s = red[0]+red[1]+red[2]+red[3];
  const float inv = 1.0f/s;
  f16x8 a, b;
  #pragma unroll
  for(int i=0;i<8;i++){ a[i] = (_Float16)(v[i]*inv); b[i] = (_Float16)(v[8+i]*inv); }
  *(f16x8*)(p + t*16) = a;
  *(f16x8*)(p + t*16 + 8) = b;
}

__global__ __launch_bounds__(256) void softmax_rn(_Float16* __restrict__ S,
                                                  const float* __restrict__ rn3,
                                                  float* __restrict__ Tq){
  __shared__ float red[4];
  const int q = blockIdx.x, z = blockIdx.y, t = threadIdx.x;
  _Float16* p = S + ((size_t)z*L + q)*L;
  float v[16];
  {
    const f16x8 a = *(const f16x8*)(p + t*16);
    const f16x8 b = *(const f16x8*)(p + t*16 + 8);
    #pragma unroll
    for(int i=0;i<8;i++){ v[i] = (float)a[i]; v[8+i] = (float)b[i]; }
  }
  float mx = -3.0e38f;
  #pragma unroll
  for(int i=0;i<16;i++) mx = fmaxf(mx, v[i]);
  mx = wave_max(mx);
  if((t&63)==0) red[t>>6]=mx;
  __syncthreads();
  mx = fmaxf(fmaxf(red[0],red[1]), fmaxf(red[2],red[3]));
  __syncthreads();
  float s = 0.f;
  #pragma unroll
  for(int i=0;i<16;i++){ v[i] = __expf(v[i]-mx); s += v[i]; }
  s = wave_sum(s);
  if((t&63)==0) red[t>>6]=s;
  __syncthreads();
  s = red[0]+red[1]+red[2]+red[3];
  __syncthreads();
  const float inv = 1.0f/s;
  const float* rnz = rn3 + (size_t)z*L + t*16;
  float T = 0.f;
  f16x8 a, b;
  #pragma unroll
  for(int i=0;i<8;i++){
    const float w0 = v[i]*inv*rnz[i];
    const float w1 = v[8+i]*inv*rnz[8+i];
    T += w0 + w1;
    a[i] = (_Float16)(w0*ASCALE);
    b[i] = (_Float16)(w1*ASCALE);
  }
  *(f16x8*)(p + t*16) = a;
  *(f16x8*)(p + t*16 + 8) = b;
  T = wave_sum(T);
  if((t&63)==0) red[t>>6]=T;
  __syncthreads();
  if(t==0) Tq[(size_t)z*L + q] = red[0]+red[1]+red[2]+red[3];
}

// out[a,m] = sum_{d=-1..1} [x-valid] in[a+d, m+d]; a XCD-chunk swizzled
__global__ __launch_bounds__(256) void dx_pass(const _Float16* __restrict__ in,
                                               _Float16* __restrict__ out){
  const int b = blockIdx.x, z = blockIdx.y, t = threadIdx.x;
  const int a = (b&7)*512 + (b>>3);
  const size_t rb = ((size_t)z*L + a)*(size_t)L;
  const int m0 = t*16, x0 = m0 & 63, xa = a & 63;
  float o[16];
  {
    const f16x8 r0 = *(const f16x8*)(in + rb + m0);
    const f16x8 r1 = *(const f16x8*)(in + rb + m0 + 8);
    #pragma unroll
    for(int i=0;i<8;i++){ o[i] = (float)r0[i]; o[8+i] = (float)r1[i]; }
  }
  if(xa != 0){
    const _Float16* pm = in + rb - L;
    const f16x8 b0 = *(const f16x8*)(pm + m0);
    const f16x8 b1 = *(const f16x8*)(pm + m0 + 8);
    o[0] += (x0 != 0) ? (float)pm[m0-1] : 0.f;
    #pragma unroll
    for(int i=1;i<8;i++) o[i] += (float)b0[i-1];
    o[8] += (float)b0[7];
    #pragma unroll
    for(int i=9;i<16;i++) o[i] += (float)b1[i-9];
  }
  if(xa != 63){
    const _Float16* pp = in + rb + L;
    const f16x8 c0 = *(const f16x8*)(pp + m0);
    const f16x8 c1 = *(const f16x8*)(pp + m0 + 8);
    #pragma unroll
    for(int i=0;i<7;i++) o[i] += (float)c0[i+1];
    o[7] += (float)c1[0];
    #pragma unroll
    for(int i=8;i<15;i++) o[i] += (float)c1[i-7];
    o[15] += (x0 != 48) ? (float)pp[m0+16] : 0.f;
  }
  f16x8 w0, w1;
  #pragma unroll
  for(int i=0;i<8;i++){ w0[i] = (_Float16)o[i]; w1[i] = (_Float16)o[8+i]; }
  *(f16x8*)(out + rb + m0) = w0;
  *(f16x8*)(out + rb + m0 + 8) = w1;
}

// out[a,m] = sum_{d=-1..1} [y-valid] in[a+64d, m+64d]; a XCD-chunk swizzled
__global__ __launch_bounds__(256) void dy_pass(const _Float16* __restrict__ in,
                                               _Float16* __restrict__ out){
  const int b = blockIdx.x, z = blockIdx.y, t = threadIdx.x;
  const int a = (b&7)*512 + (b>>3);
  const size_t rb = ((size_t)z*L + a)*(size_t)L;
  const int m0 = t*16, ym = m0 >> 6, ya = a >> 6;
  float o[16];
  {
    const f16x8 r0 = *(const f16x8*)(in + rb + m0);
    const f16x8 r1 = *(const f16x8*)(in + rb + m0 + 8);
    #pragma unroll
    for(int i=0;i<8;i++){ o[i] = (float)r0[i]; o[8+i] = (float)r1[i]; }
  }
  if(ya != 0 && ym != 0){
    const _Float16* pm = in + rb - (size_t)64*L + m0 - 64;
    const f16x8 b0 = *(const f16x8*)(pm);
    const f16x8 b1 = *(const f16x8*)(pm + 8);
    #pragma unroll
    for(int i=0;i<8;i++){ o[i] += (float)b0[i]; o[8+i] += (float)b1[i]; }
  }
  if(ya != 63 && ym != 63){
    const _Float16* pp = in + rb + (size_t)64*L + m0 + 64;
    const f16x8 c0 = *(const f16x8*)(pp);
    const f16x8 c1 = *(const f16x8*)(pp + 8);
    #pragma unroll
    for(int i=0;i<8;i++){ o[i] += (float)c0[i]; o[8+i] += (float)c1[i]; }
  }
  f16x8 w0, w1;
  #pragma unroll
  for(int i=0;i<8;i++){ w0[i] = (_Float16)o[i]; w1[i] = (_Float16)o[8+i]; }
  *(f16x8*)(out + rb + m0) = w0;
  *(f16x8*)(out + rb + m0 + 8) = w1;
}

// scatters with fused 8-way split-K reduction
__global__ __launch_bounds__(256) void scatter_p1n(const float* __restrict__ Cp,
                                                   const float* __restrict__ fgT,
                                                   const float* __restrict__ mask,
                                                   float* __restrict__ outs,
                                                   size_t sPart){
  const int z = blockIdx.y, t = threadIdx.x;
  const int q = blockIdx.x*4 + (t>>6), c = t & 63;
  const size_t idx = ((size_t)z*L + q)*128 + c;
  float rec = 0.f;
  #pragma unroll
  for(int k=0;k<8;k++) rec += Cp[(size_t)k*sPart + idx];
  const float m = mask[(size_t)z*L + q];
  const float f = fgT[((size_t)z*L + q)*64 + c];
  outs[idx] = rec*m + f*(1.0f-m);
}

__global__ __launch_bounds__(256) void scatter_p3n(const float* __restrict__ Cp,
                                                   const float* __restrict__ Tq,
                                                   const float* __restrict__ fgT,
                                                   const float* __restrict__ mask,
                                                   float* __restrict__ outs,
                                                   size_t sPart){
  const int z = blockIdx.y, t = threadIdx.x;
  const int q = blockIdx.x*4 + (t>>6), c = t & 63;
  const int y = q >> 6, x = q & 63;
  const size_t idx = ((size_t)z*L + q)*128 + c;
  float rec = 0.f;
  #pragma unroll
  for(int k=0;k<8;k++) rec += Cp[(size_t)k*sPart + idx];
  float tb = 0.f;
  #pragma unroll
  for(int dy=-1;dy<=1;dy++){
    const int yy = y+dy;
    if(yy<0||yy>=64) continue;
    #pragma unroll
    for(int dx=-1;dx<=1;dx++){
      const int xx = x+dx;
      if(xx<0||xx>=64) continue;
      tb += Tq[(size_t)z*L + yy*64+xx];
    }
  }
  const float m = mask[(size_t)z*L + q];
  rec += 1e-7f*tb;
  const float f = fgT[((size_t)z*L + q)*64 + c];
  outs[((size_t)z*L + q)*128 + 64 + c] = rec*(m*(1.0f/9.0f)) + f*(1.0f-m);
}

__global__ __launch_bounds__(256) void se_partial(const float* __restrict__ outs,
                                                  float* __restrict__ part){
  const int z = blockIdx.y, t = threadIdx.x;
  const int ch = t & 127, h = t >> 7;
  const int qb = blockIdx.x*128 + h*64;
  float s = 0.f;
  for(int j=0;j<64;j++) s += outs[((size_t)z*L + qb + j)*128 + ch];
  part[((size_t)z*64 + blockIdx.x*2 + h)*128 + ch] = s;
}

__global__ __launch_bounds__(128) void se_mlp(const float* __restrict__ part,
                                              const float* __restrict__ W1, const float* __restrict__ b1,
                                              const float* __restrict__ W2, const float* __restrict__ b2,
                                              float* __restrict__ g){
  __shared__ float s[128], h[128];
  const int z = blockIdx.x, i = threadIdx.x;
  float acc0 = 0.f;
  for(int j=0;j<64;j++) acc0 += part[((size_t)z*64 + j)*128 + i];
  s[i] = acc0*(1.0f/4096.0f);
  __syncthreads();
  float a = b1[i];
  const float* w = W1 + (size_t)i*128;
  for(int j=0;j<128;j++) a = fmaf(w[j], s[j], a);
  h[i] = fmaxf(a, 0.f);
  __syncthreads();
  float o = b2[i];
  w = W2 + (size_t)i*128;
  for(int j=0;j<128;j++) o = fmaf(w[j], h[j], o);
  g[z*128+i] = 1.0f/(1.0f + __expf(-o));
}

__global__ __launch_bounds__(256) void combiner(const float* __restrict__ outs,
                                                const float* __restrict__ g,
                                                const float* __restrict__ Wc,
                                                const float* __restrict__ bc,
                                                float* __restrict__ out){
  const size_t idx = (size_t)blockIdx.x*256 + threadIdx.x;
  const int q = (int)(idx & 4095);
  const int o = (int)((idx >> 12) & 63);
  const int z = (int)(idx >> 18);
  const float* ob = outs + ((size_t)z*L + q)*128;
  const float* gz = g + z*128;
  const float* wr = Wc + (size_t)o*128;
  float acc = bc[o];
  for(int ch=0; ch<128; ++ch) acc = fmaf(ob[ch]*gz[ch], wr[ch], acc);
  out[idx] = acc;
}

extern "C" void kernel_launch(void* const* d_in, const int* in_sizes, int n_in,
                              void* d_out, int out_size, void* d_ws, size_t ws_size,
                              hipStream_t stream){
  const float* fg   = (const float*)d_in[0];
  const float* mask = (const float*)d_in[1];
  const float* W1   = (const float*)d_in[2];
  const float* b1   = (const float*)d_in[3];
  const float* W2   = (const float*)d_in[4];
  const float* b2   = (const float*)d_in[5];
  const float* Wc   = (const float*)d_in[6];
  const float* bc   = (const float*)d_in[7];
  float* out = (float*)d_out;

  char* w = (char*)d_ws;
  size_t off = 0;
  auto alloc = [&](size_t bytes)->void*{
    void* p = (void*)(w + off);
    off += (bytes + 255) & ~(size_t)255;
    return p;
  };
  _Float16* S    = (_Float16*)alloc(2ull*L*L*2);   // scores / att / A'' / G
  _Float16* DxB  = (_Float16*)alloc(2ull*L*L*2);   // Dx intermediate
  float* Cp    = (float*)alloc(8ull*2*L*128*4);    // split-K partials
  float* outs  = (float*)alloc(2ull*L*128*4);
  float* fgT   = (float*)alloc(2ull*L*64*4);
  _Float16* BhatH1 = (_Float16*)alloc(2ull*L*64*2);
  _Float16* BhatT1 = (_Float16*)alloc(2ull*128*L*2);
  _Float16* PfgH1  = (_Float16*)alloc(2ull*L*64*2);
  _Float16* BhatH3 = (_Float16*)alloc(2ull*L*D3*2);
  _Float16* PfgH3  = (_Float16*)alloc(2ull*L*D3*2);
  _Float16* bgH    = (_Float16*)alloc(2ull*128*L*2);
  float* rn3v = (float*)alloc(2ull*L*4);
  float* Tq   = (float*)alloc(2ull*L*4);
  float* part = (float*)alloc(2ull*64*128*4);
  float* gbuf = (float*)alloc(1024);
  const size_t sPart = 2ull*L*128;

  transpose_fg<<<dim3(64,2),256,0,stream>>>(fg, fgT);

  // ================= p=1 branch =================
  build_p1<<<dim3(L/4,2),256,0,stream>>>(fgT, mask, BhatH1, PfgH1);
  zero_h<<<(unsigned)((2ull*128*L+255)/256),256,0,stream>>>(BhatT1, 2ull*128*L);
  transpose_h<<<dim3(1,64,2),256,0,stream>>>((const ushort*)BhatH1, (ushort*)BhatT1,
                                             64, (size_t)L*64, (size_t)128*L);
  gemm_h16<2,1><<<dim3(32,32,2),256,0,stream>>>(
      PfgH1, 64, (size_t)L*64,
      BhatH1, 64, (size_t)L*64,
      (void*)S, L, (size_t)L*L, 64, 0);
  softmax16<<<dim3(L,2),256,0,stream>>>(S);
  gemm_h16<0,8><<<dim3(1,32,16),256,0,stream>>>(
      S, L, (size_t)L*L,
      BhatT1, L, (size_t)128*L,
      (void*)Cp, 128, (size_t)L*128, L, sPart);
  scatter_p1n<<<dim3(L/4,2),256,0,stream>>>(Cp, fgT, mask, outs, sPart);

  // ================= p=3 branch =================
  build_bhat3  <<<dim3(L/4,2),256,0,stream>>>(fgT, mask, BhatH3, rn3v);
  build_pfgbox3<<<dim3(L/4,2),256,0,stream>>>(fgT, PfgH3);
  bg_build<<<dim3(128,2),256,0,stream>>>(fg, mask, bgH);
  gemm_h16<2,1><<<dim3(32,32,2),256,0,stream>>>(
      PfgH3, D3, (size_t)L*D3,
      BhatH3, D3, (size_t)L*D3,
      (void*)S, L, (size_t)L*L, D3, 0);
  softmax_rn<<<dim3(L,2),256,0,stream>>>(S, rn3v, Tq);
  dx_pass<<<dim3(L,2),256,0,stream>>>(S, DxB);
  dy_pass<<<dim3(L,2),256,0,stream>>>(DxB, S);
  gemm_h16<0,8><<<dim3(1,32,16),256,0,stream>>>(
      S, L, (size_t)L*L,
      bgH, L, (size_t)128*L,
      (void*)Cp, 128, (size_t)L*128, L, sPart);
  scatter_p3n<<<dim3(L/4,2),256,0,stream>>>(Cp, Tq, fgT, mask, outs, sPart);

  // ================= SE + combiner =================
  se_partial<<<dim3(32,2),256,0,stream>>>(outs, part);
  se_mlp<<<2,128,0,stream>>>(part, W1, b1, W2, b2, gbuf);
  combiner<<<(2*64*L)/256,256,0,stream>>>(outs, gbuf, Wc, bc, out);
}

// Round 8
// 290.796 us; speedup vs baseline: 3.0103x; 1.0333x over previous
//
#include <hip/hip_runtime.h>
#include <math.h>

#define WW 64
#define HH 64
#define L 4096
#define NC 64
#define D3 576
#define ASCALE (1.0f/128.0f)
#define QB 32

typedef _Float16 f16x8 __attribute__((ext_vector_type(8)));
typedef _Float16 f16x4 __attribute__((ext_vector_type(4)));
typedef float    f32x4 __attribute__((ext_vector_type(4)));

__device__ __forceinline__ float wave_max(float v){
  #pragma unroll
  for(int o=32;o;o>>=1) v = fmaxf(v, __shfl_xor(v,o));
  return v;
}
__device__ __forceinline__ float wave_sum(float v){
  #pragma unroll
  for(int o=32;o;o>>=1) v += __shfl_xor(v,o);
  return v;
}
__device__ __forceinline__ void gload16(const void* g, void* l){
  __builtin_amdgcn_global_load_lds((const __attribute__((address_space(1))) unsigned int*)g,
                                   (__attribute__((address_space(3))) unsigned int*)l,
                                   16, 0, 0);
}

__global__ __launch_bounds__(256) void transpose_fg(const float* __restrict__ fg,
                                                    float* __restrict__ fgT){
  __shared__ float tile[64][65];
  const int z = blockIdx.y;
  const int q0 = blockIdx.x*64;
  const int tx = threadIdx.x & 63, ty = threadIdx.x >> 6;
  #pragma unroll
  for(int i=0;i<16;i++){
    const int c = ty*16 + i;
    tile[c][tx] = fg[((size_t)z*64 + c)*L + q0 + tx];
  }
  __syncthreads();
  #pragma unroll
  for(int i=0;i<16;i++){
    const int q = ty*16 + i;
    fgT[((size_t)z*L + q0 + q)*64 + tx] = tile[tx][q];
  }
}

__global__ __launch_bounds__(256) void bg_build(const float* __restrict__ fg,
                                                const float* __restrict__ mask,
                                                _Float16* __restrict__ bgH){
  const int row = blockIdx.x, z = blockIdx.y, t = threadIdx.x;
  const int l0 = t*16;
  f16x8 o0, o1;
  if(row < 64){
    const float* fp = fg + ((size_t)z*64 + row)*L + l0;
    const float* mp = mask + (size_t)z*L + l0;
    #pragma unroll
    for(int i=0;i<8;i++){
      o0[i] = (_Float16)(fp[i]*(1.0f-mp[i])*128.0f);
      o1[i] = (_Float16)(fp[8+i]*(1.0f-mp[8+i])*128.0f);
    }
  } else {
    #pragma unroll
    for(int i=0;i<8;i++){ o0[i]=(_Float16)0.f; o1[i]=(_Float16)0.f; }
  }
  _Float16* op = bgH + ((size_t)z*128 + row)*L + l0;
  *(f16x8*)op = o0;
  *(f16x8*)(op+8) = o1;
}

__global__ __launch_bounds__(256) void build_p1(const float* __restrict__ fgT,
                                               const float* __restrict__ mask,
                                               _Float16* __restrict__ BhatH1,
                                               _Float16* __restrict__ PfgH1){
  const int t = threadIdx.x, c = t & 63, sub = t >> 6;
  const int l = blockIdx.x*4 + sub, z = blockIdx.y;
  const float* fgz = fgT + (size_t)z*L*64;
  const float m = mask[(size_t)z*L + l];
  const float K = fgz[(size_t)l*64 + c]*(1.0f-m) + 1e-7f;
  const float ss = wave_sum(K*K);
  BhatH1[((size_t)z*L + l)*NC + c] = (_Float16)(K*rsqrtf(ss));
  const int y = l >> 6, x = l & 63;
  float s = 0.f;
  #pragma unroll
  for(int dy=-1;dy<=1;dy++){
    const int yy = y+dy;
    if(yy<0||yy>=HH) continue;
    #pragma unroll
    for(int dx=-1;dx<=1;dx++){
      const int xx = x+dx;
      if(xx<0||xx>=WW) continue;
      s += fgz[(size_t)(yy*WW+xx)*64 + c];
    }
  }
  PfgH1[((size_t)z*L + l)*NC + c] = (_Float16)s;
}

__global__ __launch_bounds__(256) void build_bhat3(const float* __restrict__ fgT,
                                                   const float* __restrict__ mask,
                                                   _Float16* __restrict__ BhatH3,
                                                   float* __restrict__ rn3){
  const int t = threadIdx.x, c = t & 63, sub = t >> 6;
  const int l = blockIdx.x*4 + sub, z = blockIdx.y;
  const float* fgz = fgT + (size_t)z*L*64;
  const float* mz  = mask + (size_t)z*L;
  const int y = l >> 6, x = l & 63;
  float K[9]; float ss = 0.f;
  #pragma unroll
  for(int i=0;i<3;i++){
    #pragma unroll
    for(int j=0;j<3;j++){
      const int yy = y+i-1, xx = x+j-1;
      float v = 0.f;
      if(yy>=0&&yy<HH&&xx>=0&&xx<WW){
        const int q = yy*WW+xx;
        v = fgz[(size_t)q*64 + c]*(1.0f - mz[q]);
      }
      v += 1e-7f;
      K[i*3+j] = v; ss += v*v;
    }
  }
  ss = wave_sum(ss);
  const float rn = rsqrtf(ss);
  _Float16* outp = BhatH3 + ((size_t)z*L + l)*D3 + c*9;
  #pragma unroll
  for(int k=0;k<9;k++) outp[k] = (_Float16)(K[k]*rn);
  if(c==0) rn3[(size_t)z*L + l] = rn;
}

__global__ __launch_bounds__(256) void build_pfgbox3(const float* __restrict__ fgT,
                                                     _Float16* __restrict__ PfgH3){
  const int t = threadIdx.x, c = t & 63, sub = t >> 6;
  const int l = blockIdx.x*4 + sub, z = blockIdx.y;
  const float* fgz = fgT + (size_t)z*L*64;
  const int y = l >> 6, x = l & 63;
  float Wn[5][5];
  #pragma unroll
  for(int u=0;u<5;u++){
    const int yy = y+u-2;
    #pragma unroll
    for(int v=0;v<5;v++){
      const int xx = x+v-2;
      Wn[u][v] = (yy>=0 && yy<HH && xx>=0 && xx<WW) ? fgz[(size_t)(yy*WW+xx)*64 + c] : 0.f;
    }
  }
  const bool dyok[3] = { y-1>=0, true, y+1<HH };
  const bool dxok[3] = { x-1>=0, true, x+1<WW };
  _Float16* outp = PfgH3 + ((size_t)z*L + l)*D3 + c*9;
  #pragma unroll
  for(int i=0;i<3;i++){
    #pragma unroll
    for(int j=0;j<3;j++){
      float acc = 0.f;
      #pragma unroll
      for(int a=0;a<3;a++){
        if(!dyok[a]) continue;
        #pragma unroll
        for(int b=0;b<3;b++){
          if(!dxok[b]) continue;
          acc += Wn[i+a][j+b];
        }
      }
      outp[i*3+j] = (_Float16)acc;
    }
  }
}

__global__ __launch_bounds__(256) void transpose_h(const ushort* __restrict__ src,
                                                   ushort* __restrict__ dst,
                                                   int C, size_t sSz, size_t sDz){
  __shared__ ushort tile[64][65];
  const int z = blockIdx.z;
  src += z*sSz; dst += z*sDz;
  const int bc = blockIdx.x*64, br = blockIdx.y*64;
  const int tx = threadIdx.x & 15, ty = threadIdx.x >> 4;
  #pragma unroll
  for(int i=0;i<4;i++){
    const ushort4 v = *(const ushort4*)(src + (size_t)(br+ty+16*i)*C + bc + tx*4);
    tile[ty+16*i][tx*4+0] = v.x;
    tile[ty+16*i][tx*4+1] = v.y;
    tile[ty+16*i][tx*4+2] = v.z;
    tile[ty+16*i][tx*4+3] = v.w;
  }
  __syncthreads();
  #pragma unroll
  for(int i=0;i<4;i++){
    ushort4 o;
    o.x = tile[tx*4+0][ty+16*i];
    o.y = tile[tx*4+1][ty+16*i];
    o.z = tile[tx*4+2][ty+16*i];
    o.w = tile[tx*4+3][ty+16*i];
    *(ushort4*)(dst + (size_t)(bc+ty+16*i)*L + br + tx*4) = o;
  }
}

// ---------------- fused flash attention for p=1 branch ----------------
// Q=PfgH1 (LxNC), K=BhatH1 (LxNC), V^T=BhatT1 (NCxL). Writes outs channels 0..63.
__global__ __launch_bounds__(256) void flash_p1(const _Float16* __restrict__ Q,
                                                const _Float16* __restrict__ Km,
                                                const _Float16* __restrict__ Vt,
                                                const float* __restrict__ fgT,
                                                const float* __restrict__ mask,
                                                float* __restrict__ outs){
  __shared__ _Float16 Qs[QB*64];
  __shared__ _Float16 Ks[128*64];
  __shared__ _Float16 Ps[QB*128];
  __shared__ _Float16 Vs[64*128];
  __shared__ float Mx[QB], Ls[QB], Fs[QB];
  __shared__ float mpart[4][QB], spart[4][QB];
  const int z = blockIdx.y, q0 = blockIdx.x*QB;
  const int t = threadIdx.x, lane = t&63, wave = t>>6;
  const int r16 = lane&15, g4 = lane>>4;
  {
    const int row = t>>3, ch = t&7;
    gload16(Q + ((size_t)z*L + q0 + row)*64 + ((ch ^ (row&7))<<3), (char*)Qs + t*16);
  }
  if(t < QB){ Mx[t] = -3.0e38f; Ls[t] = 0.f; }
  const int iw = wave>>1, jp = wave&1;
  f32x4 accO[2] = {};
  __syncthreads();

  for(int tt=0; tt<32; ++tt){
    const size_t l0 = (size_t)tt*128;
    #pragma unroll
    for(int u=0;u<4;u++){
      const int row = u*32 + (t>>3), ch = t&7;
      gload16(Km + ((size_t)z*L + l0 + row)*64 + ((ch ^ (row&7))<<3),
              (char*)Ks + u*4096 + t*16);
    }
    #pragma unroll
    for(int u=0;u<4;u++){
      const int c = u*16 + (t>>4), j = t&15;
      gload16(Vt + ((size_t)z*64 + c)*L + l0 + ((size_t)((j ^ (c&7))<<3)),
              (char*)Vs + u*4096 + t*16);
    }
    __syncthreads();
    // S^T tile: rows l (wave*32 strip), cols q
    f32x4 acc[2][2] = {};
    #pragma unroll
    for(int kk=0;kk<2;kk++){
      f16x8 af[2], bf[2];
      #pragma unroll
      for(int i=0;i<2;i++){
        const int row = wave*32 + i*16 + r16;
        af[i] = *(const f16x8*)((const char*)Ks + (((row<<7) + kk*64 + (g4<<4)) ^ ((row&7)<<4)));
      }
      #pragma unroll
      for(int j=0;j<2;j++){
        const int row = j*16 + r16;
        bf[j] = *(const f16x8*)((const char*)Qs + (((row<<7) + kk*64 + (g4<<4)) ^ ((row&7)<<4)));
      }
      #pragma unroll
      for(int i=0;i<2;i++)
        #pragma unroll
        for(int j=0;j<2;j++)
          acc[i][j] = __builtin_amdgcn_mfma_f32_16x16x32_f16(af[i], bf[j], acc[i][j], 0,0,0);
    }
    // per-q tile max
    #pragma unroll
    for(int j=0;j<2;j++){
      float mv = -3.0e38f;
      #pragma unroll
      for(int i=0;i<2;i++)
        #pragma unroll
        for(int r=0;r<4;r++) mv = fmaxf(mv, acc[i][j][r]);
      mv = fmaxf(mv, __shfl_xor(mv, 16));
      mv = fmaxf(mv, __shfl_xor(mv, 32));
      if(g4==0) mpart[wave][j*16 + r16] = mv;
    }
    __syncthreads();
    if(t < QB){
      const float mt = fmaxf(fmaxf(mpart[0][t],mpart[1][t]),fmaxf(mpart[2][t],mpart[3][t]));
      const float mnew = fmaxf(Mx[t], mt);
      const float f = __expf(Mx[t] - mnew);
      Fs[t] = f; Mx[t] = mnew; Ls[t] *= f;
    }
    __syncthreads();
    // P = exp(S-M) -> Ps[q][l] (swizzled, b64-packed: 4 consecutive l per lane)
    #pragma unroll
    for(int j=0;j<2;j++){
      const int q = j*16 + r16;
      const float Mq = Mx[q];
      float ps = 0.f;
      #pragma unroll
      for(int i=0;i<2;i++){
        f16x4 ph;
        #pragma unroll
        for(int r=0;r<4;r++){
          const float p = __expf(acc[i][j][r] - Mq);
          ps += p; ph[r] = (_Float16)p;
        }
        const int lloc = wave*32 + i*16 + g4*4;
        *(f16x4*)((char*)Ps + (((q<<8) + (lloc<<1)) ^ ((q&7)<<4))) = ph;
      }
      ps += __shfl_xor(ps, 16);
      ps += __shfl_xor(ps, 32);
      if(g4==0) spart[wave][q] = ps;
    }
    __syncthreads();
    if(t < QB) Ls[t] += spart[0][t]+spart[1][t]+spart[2][t]+spart[3][t];
    // rescale O by Fs (rows q = iw*16 + g4*4 + r)
    {
      float fr[4];
      #pragma unroll
      for(int r=0;r<4;r++) fr[r] = Fs[iw*16 + g4*4 + r];
      #pragma unroll
      for(int jj=0;jj<2;jj++)
        #pragma unroll
        for(int r=0;r<4;r++) accO[jj][r] *= fr[r];
    }
    // O += P * V^T
    #pragma unroll
    for(int kk=0;kk<4;kk++){
      const int rowq = iw*16 + r16;
      const f16x8 af = *(const f16x8*)((const char*)Ps + (((rowq<<8) + kk*64 + (g4<<4)) ^ ((rowq&7)<<4)));
      #pragma unroll
      for(int jj=0;jj<2;jj++){
        const int c = jp*32 + jj*16 + r16;
        const f16x8 bf = *(const f16x8*)((const char*)Vs + (((c<<8) + kk*64 + (g4<<4)) ^ ((c&7)<<4)));
        accO[jj] = __builtin_amdgcn_mfma_f32_16x16x32_f16(af, bf, accO[jj], 0,0,0);
      }
    }
    __syncthreads();
  }
  #pragma unroll
  for(int jj=0;jj<2;jj++){
    #pragma unroll
    for(int r=0;r<4;r++){
      const int ql = iw*16 + g4*4 + r;
      const int q = q0 + ql;
      const int c = jp*32 + jj*16 + r16;
      const float m = mask[(size_t)z*L + q];
      const float fv = fgT[((size_t)z*L + q)*64 + c];
      const float o = accO[jj][r] / Ls[ql];
      outs[((size_t)z*L + q)*128 + c] = o*m + fv*(1.0f-m);
    }
  }
}

template<int OM, int KS>
__global__ __launch_bounds__(256) void gemm_h16(const _Float16* __restrict__ A, int lda, size_t sAz,
                                                const _Float16* __restrict__ B, int ldb, size_t sBz,
                                                void* __restrict__ C, int ldc, size_t sCz,
                                                int K, size_t sPart){
  __shared__ _Float16 sh[17408];
  _Float16* As = sh;
  _Float16* Bs = sh + 8192;
  const int zz = blockIdx.z;
  const int z = zz / KS, ks = zz % KS;
  const int Kp = K / KS;
  A += (size_t)z*sAz + (size_t)ks*Kp;
  B += (size_t)z*sBz + (size_t)ks*Kp;
  const int bm = blockIdx.y*128, bn = blockIdx.x*128;
  const int t = threadIdx.x, lane = t & 63, wave = t >> 6;
  const int wr = wave >> 1, wc = wave & 1;
  const int r16 = lane & 15, g4 = lane >> 4;
  const int srow = t >> 3;
  const int schunk = t & 7;
  f32x4 acc[4][4] = {};
  for(int k0=0;k0<Kp;k0+=64){
    #pragma unroll
    for(int u=0;u<4;u++){
      const int rowA = u*32 + srow;
      const int colh = ((schunk ^ (rowA & 7)) << 3);
      gload16(A + (size_t)(bm+rowA)*lda + k0 + colh, (char*)As + u*4096 + wave*1024);
      gload16(B + (size_t)(bn+rowA)*ldb + k0 + colh, (char*)Bs + u*4096 + wave*1024);
    }
    __syncthreads();
    #pragma unroll
    for(int kk=0;kk<2;kk++){
      f16x8 af[4], bf[4];
      #pragma unroll
      for(int i=0;i<4;i++){
        const int row = wr*64 + i*16 + r16;
        const int off = ((row<<7) + kk*64 + (g4<<4)) ^ ((row&7)<<4);
        af[i] = *(const f16x8*)((const char*)As + off);
      }
      #pragma unroll
      for(int j=0;j<4;j++){
        const int row = wc*64 + j*16 + r16;
        const int off = ((row<<7) + kk*64 + (g4<<4)) ^ ((row&7)<<4);
        bf[j] = *(const f16x8*)((const char*)Bs + off);
      }
      #pragma unroll
      for(int i=0;i<4;i++)
        #pragma unroll
        for(int j=0;j<4;j++)
          acc[i][j] = __builtin_amdgcn_mfma_f32_16x16x32_f16(af[i], bf[j], acc[i][j], 0, 0, 0);
    }
    __syncthreads();
  }
  if(OM==0){
    float* Cz = (float*)C + (size_t)ks*sPart + (size_t)z*sCz;
    #pragma unroll
    for(int i=0;i<4;i++){
      const int row0 = bm + wr*64 + i*16 + g4*4;
      #pragma unroll
      for(int j=0;j<4;j++){
        const int col = bn + wc*64 + j*16 + r16;
        #pragma unroll
        for(int r=0;r<4;r++)
          Cz[(size_t)(row0+r)*ldc + col] = acc[i][j][r];
      }
    }
  } else {
    _Float16* Cz = (_Float16*)C + (size_t)z*sCz;
    #pragma unroll
    for(int i=0;i<4;i++){
      const int row0 = wr*64 + i*16 + g4*4;
      #pragma unroll
      for(int j=0;j<4;j++){
        const int col = wc*64 + j*16 + r16;
        #pragma unroll
        for(int r=0;r<4;r++)
          sh[(row0+r)*136 + col] = (_Float16)acc[i][j][r];
      }
    }
    __syncthreads();
    #pragma unroll
    for(int k=0;k<8;k++){
      const int row = k*16 + (t>>4);
      const int cg = (t&15)*8;
      const f16x8 v = *(const f16x8*)(sh + row*136 + cg);
      *(f16x8*)(Cz + (size_t)(bm+row)*ldc + bn + cg) = v;
    }
  }
}

__global__ __launch_bounds__(256) void softmax_rn(_Float16* __restrict__ S,
                                                  const float* __restrict__ rn3,
                                                  float* __restrict__ Tq){
  __shared__ float red[4];
  const int q = blockIdx.x, z = blockIdx.y, t = threadIdx.x;
  _Float16* p = S + ((size_t)z*L + q)*L;
  float v[16];
  {
    const f16x8 a = *(const f16x8*)(p + t*16);
    const f16x8 b = *(const f16x8*)(p + t*16 + 8);
    #pragma unroll
    for(int i=0;i<8;i++){ v[i] = (float)a[i]; v[8+i] = (float)b[i]; }
  }
  float mx = -3.0e38f;
  #pragma unroll
  for(int i=0;i<16;i++) mx = fmaxf(mx, v[i]);
  mx = wave_max(mx);
  if((t&63)==0) red[t>>6]=mx;
  __syncthreads();
  mx = fmaxf(fmaxf(red[0],red[1]), fmaxf(red[2],red[3]));
  __syncthreads();
  float s = 0.f;
  #pragma unroll
  for(int i=0;i<16;i++){ v[i] = __expf(v[i]-mx); s += v[i]; }
  s = wave_sum(s);
  if((t&63)==0) red[t>>6]=s;
  __syncthreads();
  s = red[0]+red[1]+red[2]+red[3];
  __syncthreads();
  const float inv = 1.0f/s;
  const float* rnz = rn3 + (size_t)z*L + t*16;
  float T = 0.f;
  f16x8 a, b;
  #pragma unroll
  for(int i=0;i<8;i++){
    const float w0 = v[i]*inv*rnz[i];
    const float w1 = v[8+i]*inv*rnz[8+i];
    T += w0 + w1;
    a[i] = (_Float16)(w0*ASCALE);
    b[i] = (_Float16)(w1*ASCALE);
  }
  *(f16x8*)(p + t*16) = a;
  *(f16x8*)(p + t*16 + 8) = b;
  T = wave_sum(T);
  if((t&63)==0) red[t>>6]=T;
  __syncthreads();
  if(t==0) Tq[(size_t)z*L + q] = red[0]+red[1]+red[2]+red[3];
}

// ---------------- fused 9-tap diagonal stencil (dx o dy in one pass) ----------------
__global__ __launch_bounds__(256) void d9_pass(const _Float16* __restrict__ in,
                                               _Float16* __restrict__ out){
  __shared__ _Float16 slab[128 + 9*4096 + 128];
  _Float16* rows = slab + 128;
  const int b = blockIdx.x, z = blockIdx.y, t = threadIdx.x;
  const int a = (b&7)*512 + (b>>3);
  const int ya = a>>6, xa = a&63;
  const int DY[9] = {-1,-1,-1, 0,0,0, 1,1,1};
  const int DX[9] = {-1, 0, 1,-1,0,1,-1,0,1};
  bool vr[9];
  #pragma unroll
  for(int k=0;k<9;k++){
    const int yy = ya + DY[k], xx = xa + DX[k];
    vr[k] = (yy>=0 && yy<64 && xx>=0 && xx<64);
    if(vr[k]){
      const int srow = a + DY[k]*64 + DX[k];
      const _Float16* src = in + ((size_t)z*L + srow)*L;
      gload16(src + t*8,        (char*)(rows + k*4096) + t*16);
      gload16(src + 2048 + t*8, (char*)(rows + k*4096) + 4096 + t*16);
    }
  }
  __syncthreads();
  const int m0 = t*16;
  const int ym = m0>>6, x0 = m0&63;
  float o[16] = {0,0,0,0,0,0,0,0,0,0,0,0,0,0,0,0};
  #pragma unroll
  for(int k=0;k<9;k++){
    const int D = DY[k]*64 + DX[k];
    const bool vy = vr[k] && ((unsigned)(ym + DY[k]) < 64u);
    if(!vy) continue;
    const int r = ((D % 8) + 8) % 8;                 // compile-time per k
    const _Float16* A0p = rows + k*4096 + (m0 + D - r);
    _Float16 buf[24];
    *(f16x8*)(buf)    = *(const f16x8*)(A0p);
    *(f16x8*)(buf+8)  = *(const f16x8*)(A0p+8);
    *(f16x8*)(buf+16) = *(const f16x8*)(A0p+16);
    #pragma unroll
    for(int i=0;i<16;i++){
      const bool vx = (unsigned)(x0 + i + DX[k]) < 64u;
      o[i] += vx ? (float)buf[r + i] : 0.f;
    }
  }
  f16x8 w0, w1;
  #pragma unroll
  for(int i=0;i<8;i++){ w0[i] = (_Float16)o[i]; w1[i] = (_Float16)o[8+i]; }
  _Float16* op = out + ((size_t)z*L + a)*L + m0;
  *(f16x8*)op = w0;
  *(f16x8*)(op+8) = w1;
}

__global__ __launch_bounds__(256) void scatter_p3n(const float* __restrict__ Cp,
                                                   const float* __restrict__ Tq,
                                                   const float* __restrict__ fgT,
                                                   const float* __restrict__ mask,
                                                   float* __restrict__ outs,
                                                   size_t sPart){
  const int z = blockIdx.y, t = threadIdx.x;
  const int q = blockIdx.x*4 + (t>>6), c = t & 63;
  const int y = q >> 6, x = q & 63;
  const size_t idx = ((size_t)z*L + q)*128 + c;
  float rec = 0.f;
  #pragma unroll
  for(int k=0;k<8;k++) rec += Cp[(size_t)k*sPart + idx];
  float tb = 0.f;
  #pragma unroll
  for(int dy=-1;dy<=1;dy++){
    const int yy = y+dy;
    if(yy<0||yy>=64) continue;
    #pragma unroll
    for(int dx=-1;dx<=1;dx++){
      const int xx = x+dx;
      if(xx<0||xx>=64) continue;
      tb += Tq[(size_t)z*L + yy*64+xx];
    }
  }
  const float m = mask[(size_t)z*L + q];
  rec += 1e-7f*tb;
  const float f = fgT[((size_t)z*L + q)*64 + c];
  outs[((size_t)z*L + q)*128 + 64 + c] = rec*(m*(1.0f/9.0f)) + f*(1.0f-m);
}

__global__ __launch_bounds__(256) void se_partial(const float* __restrict__ outs,
                                                  float* __restrict__ part){
  const int z = blockIdx.y, t = threadIdx.x;
  const int ch = t & 127, h = t >> 7;
  const int qb = blockIdx.x*128 + h*64;
  float s = 0.f;
  for(int j=0;j<64;j++) s += outs[((size_t)z*L + qb + j)*128 + ch];
  part[((size_t)z*64 + blockIdx.x*2 + h)*128 + ch] = s;
}

__global__ __launch_bounds__(128) void se_mlp(const float* __restrict__ part,
                                              const float* __restrict__ W1, const float* __restrict__ b1,
                                              const float* __restrict__ W2, const float* __restrict__ b2,
                                              float* __restrict__ g){
  __shared__ float s[128], h[128];
  const int z = blockIdx.x, i = threadIdx.x;
  float acc0 = 0.f;
  for(int j=0;j<64;j++) acc0 += part[((size_t)z*64 + j)*128 + i];
  s[i] = acc0*(1.0f/4096.0f);
  __syncthreads();
  float a = b1[i];
  const float* w = W1 + (size_t)i*128;
  for(int j=0;j<128;j++) a = fmaf(w[j], s[j], a);
  h[i] = fmaxf(a, 0.f);
  __syncthreads();
  float o = b2[i];
  w = W2 + (size_t)i*128;
  for(int j=0;j<128;j++) o = fmaf(w[j], h[j], o);
  g[z*128+i] = 1.0f/(1.0f + __expf(-o));
}

__global__ __launch_bounds__(256) void combiner(const float* __restrict__ outs,
                                                const float* __restrict__ g,
                                                const float* __restrict__ Wc,
                                                const float* __restrict__ bc,
                                                float* __restrict__ out){
  const size_t idx = (size_t)blockIdx.x*256 + threadIdx.x;
  const int q = (int)(idx & 4095);
  const int o = (int)((idx >> 12) & 63);
  const int z = (int)(idx >> 18);
  const float* ob = outs + ((size_t)z*L + q)*128;
  const float* gz = g + z*128;
  const float* wr = Wc + (size_t)o*128;
  float acc = bc[o];
  for(int ch=0; ch<128; ++ch) acc = fmaf(ob[ch]*gz[ch], wr[ch], acc);
  out[idx] = acc;
}

extern "C" void kernel_launch(void* const* d_in, const int* in_sizes, int n_in,
                              void* d_out, int out_size, void* d_ws, size_t ws_size,
                              hipStream_t stream){
  const float* fg   = (const float*)d_in[0];
  const float* mask = (const float*)d_in[1];
  const float* W1   = (const float*)d_in[2];
  const float* b1   = (const float*)d_in[3];
  const float* W2   = (const float*)d_in[4];
  const float* b2   = (const float*)d_in[5];
  const float* Wc   = (const float*)d_in[6];
  const float* bc   = (const float*)d_in[7];
  float* out = (float*)d_out;

  char* w = (char*)d_ws;
  size_t off = 0;
  auto alloc = [&](size_t bytes)->void*{
    void* p = (void*)(w + off);
    off += (bytes + 255) & ~(size_t)255;
    return p;
  };
  _Float16* S    = (_Float16*)alloc(2ull*L*L*2);   // p3 scores / A''
  _Float16* DxB  = (_Float16*)alloc(2ull*L*L*2);   // d9 output G
  float* Cp    = (float*)alloc(8ull*2*L*128*4);    // split-K partials (p3 PV)
  float* outs  = (float*)alloc(2ull*L*128*4);
  float* fgT   = (float*)alloc(2ull*L*64*4);
  _Float16* BhatH1 = (_Float16*)alloc(2ull*L*64*2);
  _Float16* BhatT1 = (_Float16*)alloc(2ull*64*L*2);
  _Float16* PfgH1  = (_Float16*)alloc(2ull*L*64*2);
  _Float16* BhatH3 = (_Float16*)alloc(2ull*L*D3*2);
  _Float16* PfgH3  = (_Float16*)alloc(2ull*L*D3*2);
  _Float16* bgH    = (_Float16*)alloc(2ull*128*L*2);
  float* rn3v = (float*)alloc(2ull*L*4);
  float* Tq   = (float*)alloc(2ull*L*4);
  float* part = (float*)alloc(2ull*64*128*4);
  float* gbuf = (float*)alloc(1024);
  const size_t sPart = 2ull*L*128;

  transpose_fg<<<dim3(64,2),256,0,stream>>>(fg, fgT);

  // ================= p=1 branch (fused flash) =================
  build_p1<<<dim3(L/4,2),256,0,stream>>>(fgT, mask, BhatH1, PfgH1);
  transpose_h<<<dim3(1,64,2),256,0,stream>>>((const ushort*)BhatH1, (ushort*)BhatT1,
                                             64, (size_t)L*64, (size_t)64*L);
  flash_p1<<<dim3(L/QB,2),256,0,stream>>>(PfgH1, BhatH1, BhatT1, fgT, mask, outs);

  // ================= p=3 branch =================
  build_bhat3  <<<dim3(L/4,2),256,0,stream>>>(fgT, mask, BhatH3, rn3v);
  build_pfgbox3<<<dim3(L/4,2),256,0,stream>>>(fgT, PfgH3);
  bg_build<<<dim3(128,2),256,0,stream>>>(fg, mask, bgH);
  gemm_h16<2,1><<<dim3(32,32,2),256,0,stream>>>(
      PfgH3, D3, (size_t)L*D3,
      BhatH3, D3, (size_t)L*D3,
      (void*)S, L, (size_t)L*L, D3, 0);
  softmax_rn<<<dim3(L,2),256,0,stream>>>(S, rn3v, Tq);
  d9_pass<<<dim3(L,2),256,0,stream>>>(S, DxB);
  gemm_h16<0,8><<<dim3(1,32,16),256,0,stream>>>(
      DxB, L, (size_t)L*L,
      bgH, L, (size_t)128*L,
      (void*)Cp, 128, (size_t)L*128, L, sPart);
  scatter_p3n<<<dim3(L/4,2),256,0,stream>>>(Cp, Tq, fgT, mask, outs, sPart);

  // ================= SE + combiner =================
  se_partial<<<dim3(32,2),256,0,stream>>>(outs, part);
  se_mlp<<<2,128,0,stream>>>(part, W1, b1, W2, b2, gbuf);
  combiner<<<(2*64*L)/256,256,0,stream>>>(outs, gbuf, Wc, bc, out);
}

// Round 9
// 274.051 us; speedup vs baseline: 3.1942x; 1.0611x over previous
//
#include <hip/hip_runtime.h>
#include <math.h>

#define WW 64
#define HH 64
#define L 4096
#define NC 64
#define D3 576
#define ASCALE (1.0f/128.0f)
#define QB 32
#define NSPLIT 4

typedef _Float16 f16x8 __attribute__((ext_vector_type(8)));
typedef _Float16 f16x4 __attribute__((ext_vector_type(4)));
typedef float    f32x4 __attribute__((ext_vector_type(4)));

__device__ __forceinline__ float wave_max(float v){
  #pragma unroll
  for(int o=32;o;o>>=1) v = fmaxf(v, __shfl_xor(v,o));
  return v;
}
__device__ __forceinline__ float wave_sum(float v){
  #pragma unroll
  for(int o=32;o;o>>=1) v += __shfl_xor(v,o);
  return v;
}
__device__ __forceinline__ void gload16(const void* g, void* l){
  __builtin_amdgcn_global_load_lds((const __attribute__((address_space(1))) unsigned int*)g,
                                   (__attribute__((address_space(3))) unsigned int*)l,
                                   16, 0, 0);
}

__global__ __launch_bounds__(256) void transpose_fg(const float* __restrict__ fg,
                                                    float* __restrict__ fgT){
  __shared__ float tile[64][65];
  const int z = blockIdx.y;
  const int q0 = blockIdx.x*64;
  const int tx = threadIdx.x & 63, ty = threadIdx.x >> 6;
  #pragma unroll
  for(int i=0;i<16;i++){
    const int c = ty*16 + i;
    tile[c][tx] = fg[((size_t)z*64 + c)*L + q0 + tx];
  }
  __syncthreads();
  #pragma unroll
  for(int i=0;i<16;i++){
    const int q = ty*16 + i;
    fgT[((size_t)z*L + q0 + q)*64 + tx] = tile[tx][q];
  }
}

__global__ __launch_bounds__(256) void bg_build(const float* __restrict__ fg,
                                                const float* __restrict__ mask,
                                                _Float16* __restrict__ bgH){
  const int row = blockIdx.x, z = blockIdx.y, t = threadIdx.x;
  const int l0 = t*16;
  f16x8 o0, o1;
  if(row < 64){
    const float* fp = fg + ((size_t)z*64 + row)*L + l0;
    const float* mp = mask + (size_t)z*L + l0;
    #pragma unroll
    for(int i=0;i<8;i++){
      o0[i] = (_Float16)(fp[i]*(1.0f-mp[i])*128.0f);
      o1[i] = (_Float16)(fp[8+i]*(1.0f-mp[8+i])*128.0f);
    }
  } else {
    #pragma unroll
    for(int i=0;i<8;i++){ o0[i]=(_Float16)0.f; o1[i]=(_Float16)0.f; }
  }
  _Float16* op = bgH + ((size_t)z*128 + row)*L + l0;
  *(f16x8*)op = o0;
  *(f16x8*)(op+8) = o1;
}

__global__ __launch_bounds__(256) void build_p1(const float* __restrict__ fgT,
                                               const float* __restrict__ mask,
                                               _Float16* __restrict__ BhatH1,
                                               _Float16* __restrict__ PfgH1){
  const int t = threadIdx.x, c = t & 63, sub = t >> 6;
  const int l = blockIdx.x*4 + sub, z = blockIdx.y;
  const float* fgz = fgT + (size_t)z*L*64;
  const float m = mask[(size_t)z*L + l];
  const float K = fgz[(size_t)l*64 + c]*(1.0f-m) + 1e-7f;
  const float ss = wave_sum(K*K);
  BhatH1[((size_t)z*L + l)*NC + c] = (_Float16)(K*rsqrtf(ss));
  const int y = l >> 6, x = l & 63;
  float s = 0.f;
  #pragma unroll
  for(int dy=-1;dy<=1;dy++){
    const int yy = y+dy;
    if(yy<0||yy>=HH) continue;
    #pragma unroll
    for(int dx=-1;dx<=1;dx++){
      const int xx = x+dx;
      if(xx<0||xx>=WW) continue;
      s += fgz[(size_t)(yy*WW+xx)*64 + c];
    }
  }
  PfgH1[((size_t)z*L + l)*NC + c] = (_Float16)s;
}

__global__ __launch_bounds__(256) void build_bhat3(const float* __restrict__ fgT,
                                                   const float* __restrict__ mask,
                                                   _Float16* __restrict__ BhatH3,
                                                   float* __restrict__ rn3){
  const int t = threadIdx.x, c = t & 63, sub = t >> 6;
  const int l = blockIdx.x*4 + sub, z = blockIdx.y;
  const float* fgz = fgT + (size_t)z*L*64;
  const float* mz  = mask + (size_t)z*L;
  const int y = l >> 6, x = l & 63;
  float K[9]; float ss = 0.f;
  #pragma unroll
  for(int i=0;i<3;i++){
    #pragma unroll
    for(int j=0;j<3;j++){
      const int yy = y+i-1, xx = x+j-1;
      float v = 0.f;
      if(yy>=0&&yy<HH&&xx>=0&&xx<WW){
        const int q = yy*WW+xx;
        v = fgz[(size_t)q*64 + c]*(1.0f - mz[q]);
      }
      v += 1e-7f;
      K[i*3+j] = v; ss += v*v;
    }
  }
  ss = wave_sum(ss);
  const float rn = rsqrtf(ss);
  _Float16* outp = BhatH3 + ((size_t)z*L + l)*D3 + c*9;
  #pragma unroll
  for(int k=0;k<9;k++) outp[k] = (_Float16)(K[k]*rn);
  if(c==0) rn3[(size_t)z*L + l] = rn;
}

__global__ __launch_bounds__(256) void build_pfgbox3(const float* __restrict__ fgT,
                                                     _Float16* __restrict__ PfgH3){
  const int t = threadIdx.x, c = t & 63, sub = t >> 6;
  const int l = blockIdx.x*4 + sub, z = blockIdx.y;
  const float* fgz = fgT + (size_t)z*L*64;
  const int y = l >> 6, x = l & 63;
  float Wn[5][5];
  #pragma unroll
  for(int u=0;u<5;u++){
    const int yy = y+u-2;
    #pragma unroll
    for(int v=0;v<5;v++){
      const int xx = x+v-2;
      Wn[u][v] = (yy>=0 && yy<HH && xx>=0 && xx<WW) ? fgz[(size_t)(yy*WW+xx)*64 + c] : 0.f;
    }
  }
  const bool dyok[3] = { y-1>=0, true, y+1<HH };
  const bool dxok[3] = { x-1>=0, true, x+1<WW };
  _Float16* outp = PfgH3 + ((size_t)z*L + l)*D3 + c*9;
  #pragma unroll
  for(int i=0;i<3;i++){
    #pragma unroll
    for(int j=0;j<3;j++){
      float acc = 0.f;
      #pragma unroll
      for(int a=0;a<3;a++){
        if(!dyok[a]) continue;
        #pragma unroll
        for(int b=0;b<3;b++){
          if(!dxok[b]) continue;
          acc += Wn[i+a][j+b];
        }
      }
      outp[i*3+j] = (_Float16)acc;
    }
  }
}

__global__ __launch_bounds__(256) void transpose_h(const ushort* __restrict__ src,
                                                   ushort* __restrict__ dst,
                                                   int C, size_t sSz, size_t sDz){
  __shared__ ushort tile[64][65];
  const int z = blockIdx.z;
  src += z*sSz; dst += z*sDz;
  const int bc = blockIdx.x*64, br = blockIdx.y*64;
  const int tx = threadIdx.x & 15, ty = threadIdx.x >> 4;
  #pragma unroll
  for(int i=0;i<4;i++){
    const ushort4 v = *(const ushort4*)(src + (size_t)(br+ty+16*i)*C + bc + tx*4);
    tile[ty+16*i][tx*4+0] = v.x;
    tile[ty+16*i][tx*4+1] = v.y;
    tile[ty+16*i][tx*4+2] = v.z;
    tile[ty+16*i][tx*4+3] = v.w;
  }
  __syncthreads();
  #pragma unroll
  for(int i=0;i<4;i++){
    ushort4 o;
    o.x = tile[tx*4+0][ty+16*i];
    o.y = tile[tx*4+1][ty+16*i];
    o.z = tile[tx*4+2][ty+16*i];
    o.w = tile[tx*4+3][ty+16*i];
    *(ushort4*)(dst + (size_t)(bc+ty+16*i)*L + br + tx*4) = o;
  }
}

// ---------------- fused flash attention (p=1), split-L flash-decoding ----------------
// Each block: q-tile of 32, key slice of 1024. Emits partial O (f32), running max M, sum Lsum.
__global__ __launch_bounds__(256) void flash_p1(const _Float16* __restrict__ Q,
                                                const _Float16* __restrict__ Km,
                                                const _Float16* __restrict__ Vt,
                                                float* __restrict__ Op,
                                                float* __restrict__ Ml,
                                                float* __restrict__ Ll){
  __shared__ _Float16 Qs[QB*64];
  __shared__ _Float16 Ks[128*64];
  __shared__ _Float16 Ps[QB*128];
  __shared__ _Float16 Vs[64*128];
  __shared__ float Mx[QB], Ls[QB], Fs[QB];
  __shared__ float mpart[4][QB], spart[4][QB];
  const int z = blockIdx.z, sp = blockIdx.y, q0 = blockIdx.x*QB;
  const int t = threadIdx.x, lane = t&63, wave = t>>6;
  const int r16 = lane&15, g4 = lane>>4;
  {
    const int row = t>>3, ch = t&7;
    gload16(Q + ((size_t)z*L + q0 + row)*64 + ((ch ^ (row&7))<<3), (char*)Qs + t*16);
  }
  if(t < QB){ Mx[t] = -3.0e38f; Ls[t] = 0.f; }
  const int iw = wave>>1, jp = wave&1;
  f32x4 accO[2] = {};
  __syncthreads();

  for(int tt=0; tt<1024/128; ++tt){
    const size_t l0 = (size_t)sp*1024 + (size_t)tt*128;
    #pragma unroll
    for(int u=0;u<4;u++){
      const int row = u*32 + (t>>3), ch = t&7;
      gload16(Km + ((size_t)z*L + l0 + row)*64 + ((ch ^ (row&7))<<3),
              (char*)Ks + u*4096 + t*16);
    }
    #pragma unroll
    for(int u=0;u<4;u++){
      const int c = u*16 + (t>>4), j = t&15;
      gload16(Vt + ((size_t)z*64 + c)*L + l0 + ((size_t)((j ^ (c&7))<<3)),
              (char*)Vs + u*4096 + t*16);
    }
    __syncthreads();
    // S^T tile: rows l (wave*32 strip), cols q
    f32x4 acc[2][2] = {};
    #pragma unroll
    for(int kk=0;kk<2;kk++){
      f16x8 af[2], bf[2];
      #pragma unroll
      for(int i=0;i<2;i++){
        const int row = wave*32 + i*16 + r16;
        af[i] = *(const f16x8*)((const char*)Ks + (((row<<7) + kk*64 + (g4<<4)) ^ ((row&7)<<4)));
      }
      #pragma unroll
      for(int j=0;j<2;j++){
        const int row = j*16 + r16;
        bf[j] = *(const f16x8*)((const char*)Qs + (((row<<7) + kk*64 + (g4<<4)) ^ ((row&7)<<4)));
      }
      #pragma unroll
      for(int i=0;i<2;i++)
        #pragma unroll
        for(int j=0;j<2;j++)
          acc[i][j] = __builtin_amdgcn_mfma_f32_16x16x32_f16(af[i], bf[j], acc[i][j], 0,0,0);
    }
    #pragma unroll
    for(int j=0;j<2;j++){
      float mv = -3.0e38f;
      #pragma unroll
      for(int i=0;i<2;i++)
        #pragma unroll
        for(int r=0;r<4;r++) mv = fmaxf(mv, acc[i][j][r]);
      mv = fmaxf(mv, __shfl_xor(mv, 16));
      mv = fmaxf(mv, __shfl_xor(mv, 32));
      if(g4==0) mpart[wave][j*16 + r16] = mv;
    }
    __syncthreads();
    if(t < QB){
      const float mt = fmaxf(fmaxf(mpart[0][t],mpart[1][t]),fmaxf(mpart[2][t],mpart[3][t]));
      const float mnew = fmaxf(Mx[t], mt);
      const float f = __expf(Mx[t] - mnew);
      Fs[t] = f; Mx[t] = mnew; Ls[t] *= f;
    }
    __syncthreads();
    #pragma unroll
    for(int j=0;j<2;j++){
      const int q = j*16 + r16;
      const float Mq = Mx[q];
      float ps = 0.f;
      #pragma unroll
      for(int i=0;i<2;i++){
        f16x4 ph;
        #pragma unroll
        for(int r=0;r<4;r++){
          const float p = __expf(acc[i][j][r] - Mq);
          ps += p; ph[r] = (_Float16)p;
        }
        const int lloc = wave*32 + i*16 + g4*4;
        *(f16x4*)((char*)Ps + (((q<<8) + (lloc<<1)) ^ ((q&7)<<4))) = ph;
      }
      ps += __shfl_xor(ps, 16);
      ps += __shfl_xor(ps, 32);
      if(g4==0) spart[wave][q] = ps;
    }
    __syncthreads();
    if(t < QB) Ls[t] += spart[0][t]+spart[1][t]+spart[2][t]+spart[3][t];
    {
      float fr[4];
      #pragma unroll
      for(int r=0;r<4;r++) fr[r] = Fs[iw*16 + g4*4 + r];
      #pragma unroll
      for(int jj=0;jj<2;jj++)
        #pragma unroll
        for(int r=0;r<4;r++) accO[jj][r] *= fr[r];
    }
    #pragma unroll
    for(int kk=0;kk<4;kk++){
      const int rowq = iw*16 + r16;
      const f16x8 af = *(const f16x8*)((const char*)Ps + (((rowq<<8) + kk*64 + (g4<<4)) ^ ((rowq&7)<<4)));
      #pragma unroll
      for(int jj=0;jj<2;jj++){
        const int c = jp*32 + jj*16 + r16;
        const f16x8 bf = *(const f16x8*)((const char*)Vs + (((c<<8) + kk*64 + (g4<<4)) ^ ((c&7)<<4)));
        accO[jj] = __builtin_amdgcn_mfma_f32_16x16x32_f16(af, bf, accO[jj], 0,0,0);
      }
    }
    __syncthreads();
  }
  const int base = z*NSPLIT + sp;
  #pragma unroll
  for(int jj=0;jj<2;jj++){
    #pragma unroll
    for(int r=0;r<4;r++){
      const int ql = iw*16 + g4*4 + r;
      const int c = jp*32 + jj*16 + r16;
      Op[((size_t)base*L + q0 + ql)*64 + c] = accO[jj][r];
    }
  }
  if(t < QB){
    Ml[(size_t)base*L + q0 + t] = Mx[t];
    Ll[(size_t)base*L + q0 + t] = Ls[t];
  }
}

// combine split-L partials + mask mix -> outs channels 0..63
__global__ __launch_bounds__(256) void flash_comb(const float* __restrict__ Op,
                                                  const float* __restrict__ Ml,
                                                  const float* __restrict__ Ll,
                                                  const float* __restrict__ fgT,
                                                  const float* __restrict__ mask,
                                                  float* __restrict__ outs){
  const int z = blockIdx.y, t = threadIdx.x;
  const int q = blockIdx.x*4 + (t>>6), c = t & 63;
  float mv[NSPLIT];
  float ms = -3.0e38f;
  #pragma unroll
  for(int s=0;s<NSPLIT;s++){
    mv[s] = Ml[(size_t)(z*NSPLIT+s)*L + q];
    ms = fmaxf(ms, mv[s]);
  }
  float acc = 0.f, Lt = 0.f;
  #pragma unroll
  for(int s=0;s<NSPLIT;s++){
    const float w0 = __expf(mv[s] - ms);
    acc += w0 * Op[((size_t)(z*NSPLIT+s)*L + q)*64 + c];
    Lt  += w0 * Ll[(size_t)(z*NSPLIT+s)*L + q];
  }
  const float o = acc/Lt;
  const float m = mask[(size_t)z*L + q];
  const float f = fgT[((size_t)z*L + q)*64 + c];
  outs[((size_t)z*L + q)*128 + c] = o*m + f*(1.0f-m);
}

template<int OM, int KS>
__global__ __launch_bounds__(256) void gemm_h16(const _Float16* __restrict__ A, int lda, size_t sAz,
                                                const _Float16* __restrict__ B, int ldb, size_t sBz,
                                                void* __restrict__ C, int ldc, size_t sCz,
                                                int K, size_t sPart){
  __shared__ _Float16 sh[17408];
  _Float16* As = sh;
  _Float16* Bs = sh + 8192;
  const int zz = blockIdx.z;
  const int z = zz / KS, ks = zz % KS;
  const int Kp = K / KS;
  A += (size_t)z*sAz + (size_t)ks*Kp;
  B += (size_t)z*sBz + (size_t)ks*Kp;
  const int bm = blockIdx.y*128, bn = blockIdx.x*128;
  const int t = threadIdx.x, lane = t & 63, wave = t >> 6;
  const int wr = wave >> 1, wc = wave & 1;
  const int r16 = lane & 15, g4 = lane >> 4;
  const int srow = t >> 3;
  const int schunk = t & 7;
  f32x4 acc[4][4] = {};
  for(int k0=0;k0<Kp;k0+=64){
    #pragma unroll
    for(int u=0;u<4;u++){
      const int rowA = u*32 + srow;
      const int colh = ((schunk ^ (rowA & 7)) << 3);
      gload16(A + (size_t)(bm+rowA)*lda + k0 + colh, (char*)As + u*4096 + wave*1024);
      gload16(B + (size_t)(bn+rowA)*ldb + k0 + colh, (char*)Bs + u*4096 + wave*1024);
    }
    __syncthreads();
    #pragma unroll
    for(int kk=0;kk<2;kk++){
      f16x8 af[4], bf[4];
      #pragma unroll
      for(int i=0;i<4;i++){
        const int row = wr*64 + i*16 + r16;
        const int off = ((row<<7) + kk*64 + (g4<<4)) ^ ((row&7)<<4);
        af[i] = *(const f16x8*)((const char*)As + off);
      }
      #pragma unroll
      for(int j=0;j<4;j++){
        const int row = wc*64 + j*16 + r16;
        const int off = ((row<<7) + kk*64 + (g4<<4)) ^ ((row&7)<<4);
        bf[j] = *(const f16x8*)((const char*)Bs + off);
      }
      #pragma unroll
      for(int i=0;i<4;i++)
        #pragma unroll
        for(int j=0;j<4;j++)
          acc[i][j] = __builtin_amdgcn_mfma_f32_16x16x32_f16(af[i], bf[j], acc[i][j], 0, 0, 0);
    }
    __syncthreads();
  }
  if(OM==0){
    float* Cz = (float*)C + (size_t)ks*sPart + (size_t)z*sCz;
    #pragma unroll
    for(int i=0;i<4;i++){
      const int row0 = bm + wr*64 + i*16 + g4*4;
      #pragma unroll
      for(int j=0;j<4;j++){
        const int col = bn + wc*64 + j*16 + r16;
        #pragma unroll
        for(int r=0;r<4;r++)
          Cz[(size_t)(row0+r)*ldc + col] = acc[i][j][r];
      }
    }
  } else {
    _Float16* Cz = (_Float16*)C + (size_t)z*sCz;
    #pragma unroll
    for(int i=0;i<4;i++){
      const int row0 = wr*64 + i*16 + g4*4;
      #pragma unroll
      for(int j=0;j<4;j++){
        const int col = wc*64 + j*16 + r16;
        #pragma unroll
        for(int r=0;r<4;r++)
          sh[(row0+r)*136 + col] = (_Float16)acc[i][j][r];
      }
    }
    __syncthreads();
    #pragma unroll
    for(int k=0;k<8;k++){
      const int row = k*16 + (t>>4);
      const int cg = (t&15)*8;
      const f16x8 v = *(const f16x8*)(sh + row*136 + cg);
      *(f16x8*)(Cz + (size_t)(bm+row)*ldc + bn + cg) = v;
    }
  }
}

__global__ __launch_bounds__(256) void softmax_rn(_Float16* __restrict__ S,
                                                  const float* __restrict__ rn3,
                                                  float* __restrict__ Tq){
  __shared__ float red[4];
  const int q = blockIdx.x, z = blockIdx.y, t = threadIdx.x;
  _Float16* p = S + ((size_t)z*L + q)*L;
  float v[16];
  {
    const f16x8 a = *(const f16x8*)(p + t*16);
    const f16x8 b = *(const f16x8*)(p + t*16 + 8);
    #pragma unroll
    for(int i=0;i<8;i++){ v[i] = (float)a[i]; v[8+i] = (float)b[i]; }
  }
  float mx = -3.0e38f;
  #pragma unroll
  for(int i=0;i<16;i++) mx = fmaxf(mx, v[i]);
  mx = wave_max(mx);
  if((t&63)==0) red[t>>6]=mx;
  __syncthreads();
  mx = fmaxf(fmaxf(red[0],red[1]), fmaxf(red[2],red[3]));
  __syncthreads();
  float s = 0.f;
  #pragma unroll
  for(int i=0;i<16;i++){ v[i] = __expf(v[i]-mx); s += v[i]; }
  s = wave_sum(s);
  if((t&63)==0) red[t>>6]=s;
  __syncthreads();
  s = red[0]+red[1]+red[2]+red[3];
  __syncthreads();
  const float inv = 1.0f/s;
  const float* rnz = rn3 + (size_t)z*L + t*16;
  float T = 0.f;
  f16x8 a, b;
  #pragma unroll
  for(int i=0;i<8;i++){
    const float w0 = v[i]*inv*rnz[i];
    const float w1 = v[8+i]*inv*rnz[8+i];
    T += w0 + w1;
    a[i] = (_Float16)(w0*ASCALE);
    b[i] = (_Float16)(w1*ASCALE);
  }
  *(f16x8*)(p + t*16) = a;
  *(f16x8*)(p + t*16 + 8) = b;
  T = wave_sum(T);
  if((t&63)==0) red[t>>6]=T;
  __syncthreads();
  if(t==0) Tq[(size_t)z*L + q] = red[0]+red[1]+red[2]+red[3];
}

__global__ __launch_bounds__(256) void d9_pass(const _Float16* __restrict__ in,
                                               _Float16* __restrict__ out){
  __shared__ _Float16 slab[128 + 9*4096 + 128];
  _Float16* rows = slab + 128;
  const int b = blockIdx.x, z = blockIdx.y, t = threadIdx.x;
  const int a = (b&7)*512 + (b>>3);
  const int ya = a>>6, xa = a&63;
  const int DY[9] = {-1,-1,-1, 0,0,0, 1,1,1};
  const int DX[9] = {-1, 0, 1,-1,0,1,-1,0,1};
  bool vr[9];
  #pragma unroll
  for(int k=0;k<9;k++){
    const int yy = ya + DY[k], xx = xa + DX[k];
    vr[k] = (yy>=0 && yy<64 && xx>=0 && xx<64);
    if(vr[k]){
      const int srow = a + DY[k]*64 + DX[k];
      const _Float16* src = in + ((size_t)z*L + srow)*L;
      gload16(src + t*8,        (char*)(rows + k*4096) + t*16);
      gload16(src + 2048 + t*8, (char*)(rows + k*4096) + 4096 + t*16);
    }
  }
  __syncthreads();
  const int m0 = t*16;
  const int ym = m0>>6, x0 = m0&63;
  float o[16] = {0,0,0,0,0,0,0,0,0,0,0,0,0,0,0,0};
  #pragma unroll
  for(int k=0;k<9;k++){
    const int D = DY[k]*64 + DX[k];
    const bool vy = vr[k] && ((unsigned)(ym + DY[k]) < 64u);
    if(!vy) continue;
    const int r = ((D % 8) + 8) % 8;
    const _Float16* A0p = rows + k*4096 + (m0 + D - r);
    _Float16 buf[24];
    *(f16x8*)(buf)    = *(const f16x8*)(A0p);
    *(f16x8*)(buf+8)  = *(const f16x8*)(A0p+8);
    *(f16x8*)(buf+16) = *(const f16x8*)(A0p+16);
    #pragma unroll
    for(int i=0;i<16;i++){
      const bool vx = (unsigned)(x0 + i + DX[k]) < 64u;
      o[i] += vx ? (float)buf[r + i] : 0.f;
    }
  }
  f16x8 w0, w1;
  #pragma unroll
  for(int i=0;i<8;i++){ w0[i] = (_Float16)o[i]; w1[i] = (_Float16)o[8+i]; }
  _Float16* op = out + ((size_t)z*L + a)*L + m0;
  *(f16x8*)op = w0;
  *(f16x8*)(op+8) = w1;
}

__global__ __launch_bounds__(256) void scatter_p3n(const float* __restrict__ Cp,
                                                   const float* __restrict__ Tq,
                                                   const float* __restrict__ fgT,
                                                   const float* __restrict__ mask,
                                                   float* __restrict__ outs,
                                                   size_t sPart){
  const int z = blockIdx.y, t = threadIdx.x;
  const int q = blockIdx.x*4 + (t>>6), c = t & 63;
  const int y = q >> 6, x = q & 63;
  const size_t idx = ((size_t)z*L + q)*128 + c;
  float rec = 0.f;
  #pragma unroll
  for(int k=0;k<8;k++) rec += Cp[(size_t)k*sPart + idx];
  float tb = 0.f;
  #pragma unroll
  for(int dy=-1;dy<=1;dy++){
    const int yy = y+dy;
    if(yy<0||yy>=64) continue;
    #pragma unroll
    for(int dx=-1;dx<=1;dx++){
      const int xx = x+dx;
      if(xx<0||xx>=64) continue;
      tb += Tq[(size_t)z*L + yy*64+xx];
    }
  }
  const float m = mask[(size_t)z*L + q];
  rec += 1e-7f*tb;
  const float f = fgT[((size_t)z*L + q)*64 + c];
  outs[((size_t)z*L + q)*128 + 64 + c] = rec*(m*(1.0f/9.0f)) + f*(1.0f-m);
}

__global__ __launch_bounds__(256) void se_partial(const float* __restrict__ outs,
                                                  float* __restrict__ part){
  const int z = blockIdx.y, t = threadIdx.x;
  const int ch = t & 127, h = t >> 7;
  const int qb = blockIdx.x*128 + h*64;
  float s = 0.f;
  for(int j=0;j<64;j++) s += outs[((size_t)z*L + qb + j)*128 + ch];
  part[((size_t)z*64 + blockIdx.x*2 + h)*128 + ch] = s;
}

__global__ __launch_bounds__(128) void se_mlp(const float* __restrict__ part,
                                              const float* __restrict__ W1, const float* __restrict__ b1,
                                              const float* __restrict__ W2, const float* __restrict__ b2,
                                              float* __restrict__ g){
  __shared__ float s[128], h[128];
  const int z = blockIdx.x, i = threadIdx.x;
  float acc0 = 0.f;
  for(int j=0;j<64;j++) acc0 += part[((size_t)z*64 + j)*128 + i];
  s[i] = acc0*(1.0f/4096.0f);
  __syncthreads();
  float a = b1[i];
  const float* w = W1 + (size_t)i*128;
  for(int j=0;j<128;j++) a = fmaf(w[j], s[j], a);
  h[i] = fmaxf(a, 0.f);
  __syncthreads();
  float o = b2[i];
  w = W2 + (size_t)i*128;
  for(int j=0;j<128;j++) o = fmaf(w[j], h[j], o);
  g[z*128+i] = 1.0f/(1.0f + __expf(-o));
}

__global__ __launch_bounds__(256) void combiner(const float* __restrict__ outs,
                                                const float* __restrict__ g,
                                                const float* __restrict__ Wc,
                                                const float* __restrict__ bc,
                                                float* __restrict__ out){
  const size_t idx = (size_t)blockIdx.x*256 + threadIdx.x;
  const int q = (int)(idx & 4095);
  const int o = (int)((idx >> 12) & 63);
  const int z = (int)(idx >> 18);
  const float* ob = outs + ((size_t)z*L + q)*128;
  const float* gz = g + z*128;
  const float* wr = Wc + (size_t)o*128;
  float acc = bc[o];
  for(int ch=0; ch<128; ++ch) acc = fmaf(ob[ch]*gz[ch], wr[ch], acc);
  out[idx] = acc;
}

extern "C" void kernel_launch(void* const* d_in, const int* in_sizes, int n_in,
                              void* d_out, int out_size, void* d_ws, size_t ws_size,
                              hipStream_t stream){
  const float* fg   = (const float*)d_in[0];
  const float* mask = (const float*)d_in[1];
  const float* W1   = (const float*)d_in[2];
  const float* b1   = (const float*)d_in[3];
  const float* W2   = (const float*)d_in[4];
  const float* b2   = (const float*)d_in[5];
  const float* Wc   = (const float*)d_in[6];
  const float* bc   = (const float*)d_in[7];
  float* out = (float*)d_out;

  char* w = (char*)d_ws;
  size_t off = 0;
  auto alloc = [&](size_t bytes)->void*{
    void* p = (void*)(w + off);
    off += (bytes + 255) & ~(size_t)255;
    return p;
  };
  _Float16* S    = (_Float16*)alloc(2ull*L*L*2);   // p3 scores / A''
  _Float16* DxB  = (_Float16*)alloc(2ull*L*L*2);   // d9 output G
  float* Cp    = (float*)alloc(8ull*2*L*128*4);    // split-K partials (p3 PV)
  float* outs  = (float*)alloc(2ull*L*128*4);
  float* fgT   = (float*)alloc(2ull*L*64*4);
  _Float16* BhatH1 = (_Float16*)alloc(2ull*L*64*2);
  _Float16* BhatT1 = (_Float16*)alloc(2ull*64*L*2);
  _Float16* PfgH1  = (_Float16*)alloc(2ull*L*64*2);
  _Float16* BhatH3 = (_Float16*)alloc(2ull*L*D3*2);
  _Float16* PfgH3  = (_Float16*)alloc(2ull*L*D3*2);
  _Float16* bgH    = (_Float16*)alloc(2ull*128*L*2);
  float* Opb  = (float*)alloc((size_t)2*NSPLIT*L*64*4);  // flash partials
  float* Mlb  = (float*)alloc((size_t)2*NSPLIT*L*4);
  float* Llb  = (float*)alloc((size_t)2*NSPLIT*L*4);
  float* rn3v = (float*)alloc(2ull*L*4);
  float* Tq   = (float*)alloc(2ull*L*4);
  float* part = (float*)alloc(2ull*64*128*4);
  float* gbuf = (float*)alloc(1024);
  const size_t sPart = 2ull*L*128;

  transpose_fg<<<dim3(64,2),256,0,stream>>>(fg, fgT);

  // ================= p=1 branch (fused flash, split-L) =================
  build_p1<<<dim3(L/4,2),256,0,stream>>>(fgT, mask, BhatH1, PfgH1);
  transpose_h<<<dim3(1,64,2),256,0,stream>>>((const ushort*)BhatH1, (ushort*)BhatT1,
                                             64, (size_t)L*64, (size_t)64*L);
  flash_p1<<<dim3(L/QB,NSPLIT,2),256,0,stream>>>(PfgH1, BhatH1, BhatT1, Opb, Mlb, Llb);
  flash_comb<<<dim3(L/4,2),256,0,stream>>>(Opb, Mlb, Llb, fgT, mask, outs);

  // ================= p=3 branch =================
  build_bhat3  <<<dim3(L/4,2),256,0,stream>>>(fgT, mask, BhatH3, rn3v);
  build_pfgbox3<<<dim3(L/4,2),256,0,stream>>>(fgT, PfgH3);
  bg_build<<<dim3(128,2),256,0,stream>>>(fg, mask, bgH);
  gemm_h16<2,1><<<dim3(32,32,2),256,0,stream>>>(
      PfgH3, D3, (size_t)L*D3,
      BhatH3, D3, (size_t)L*D3,
      (void*)S, L, (size_t)L*L, D3, 0);
  softmax_rn<<<dim3(L,2),256,0,stream>>>(S, rn3v, Tq);
  d9_pass<<<dim3(L,2),256,0,stream>>>(S, DxB);
  gemm_h16<0,8><<<dim3(1,32,16),256,0,stream>>>(
      DxB, L, (size_t)L*L,
      bgH, L, (size_t)128*L,
      (void*)Cp, 128, (size_t)L*128, L, sPart);
  scatter_p3n<<<dim3(L/4,2),256,0,stream>>>(Cp, Tq, fgT, mask, outs, sPart);

  // ================= SE + combiner =================
  se_partial<<<dim3(32,2),256,0,stream>>>(outs, part);
  se_mlp<<<2,128,0,stream>>>(part, W1, b1, W2, b2, gbuf);
  combiner<<<(2*64*L)/256,256,0,stream>>>(outs, gbuf, Wc, bc, out);
}

// Round 10
// 266.839 us; speedup vs baseline: 3.2806x; 1.0270x over previous
//
#include <hip/hip_runtime.h>
#include <math.h>

#define WW 64
#define HH 64
#define L 4096
#define NC 64
#define D3 576
#define ASCALE (1.0f/128.0f)
#define QB 32
#define NSPLIT 4          // key-slices per z; 4 waves each -> 16 partial sets per z

typedef _Float16 f16x8 __attribute__((ext_vector_type(8)));
typedef _Float16 f16x4 __attribute__((ext_vector_type(4)));
typedef float    f32x4 __attribute__((ext_vector_type(4)));

__device__ __forceinline__ float wave_max(float v){
  #pragma unroll
  for(int o=32;o;o>>=1) v = fmaxf(v, __shfl_xor(v,o));
  return v;
}
__device__ __forceinline__ float wave_sum(float v){
  #pragma unroll
  for(int o=32;o;o>>=1) v += __shfl_xor(v,o);
  return v;
}
__device__ __forceinline__ void gload16(const void* g, void* l){
  __builtin_amdgcn_global_load_lds((const __attribute__((address_space(1))) unsigned int*)g,
                                   (__attribute__((address_space(3))) unsigned int*)l,
                                   16, 0, 0);
}

__global__ __launch_bounds__(256) void transpose_fg(const float* __restrict__ fg,
                                                    float* __restrict__ fgT){
  __shared__ float tile[64][65];
  const int z = blockIdx.y;
  const int q0 = blockIdx.x*64;
  const int tx = threadIdx.x & 63, ty = threadIdx.x >> 6;
  #pragma unroll
  for(int i=0;i<16;i++){
    const int c = ty*16 + i;
    tile[c][tx] = fg[((size_t)z*64 + c)*L + q0 + tx];
  }
  __syncthreads();
  #pragma unroll
  for(int i=0;i<16;i++){
    const int q = ty*16 + i;
    fgT[((size_t)z*L + q0 + q)*64 + tx] = tile[tx][q];
  }
}

__global__ __launch_bounds__(256) void bg_build(const float* __restrict__ fg,
                                                const float* __restrict__ mask,
                                                _Float16* __restrict__ bgH){
  const int row = blockIdx.x, z = blockIdx.y, t = threadIdx.x;
  const int l0 = t*16;
  f16x8 o0, o1;
  if(row < 64){
    const float* fp = fg + ((size_t)z*64 + row)*L + l0;
    const float* mp = mask + (size_t)z*L + l0;
    #pragma unroll
    for(int i=0;i<8;i++){
      o0[i] = (_Float16)(fp[i]*(1.0f-mp[i])*128.0f);
      o1[i] = (_Float16)(fp[8+i]*(1.0f-mp[8+i])*128.0f);
    }
  } else {
    #pragma unroll
    for(int i=0;i<8;i++){ o0[i]=(_Float16)0.f; o1[i]=(_Float16)0.f; }
  }
  _Float16* op = bgH + ((size_t)z*128 + row)*L + l0;
  *(f16x8*)op = o0;
  *(f16x8*)(op+8) = o1;
}

// ---------------- fused builder: p1 (Bhat,Pfg) + p3 (Bhat,rn3,PfgBox) ----------------
__global__ __launch_bounds__(256) void build_all(const float* __restrict__ fgT,
                                                 const float* __restrict__ mask,
                                                 _Float16* __restrict__ BhatH1,
                                                 _Float16* __restrict__ PfgH1,
                                                 _Float16* __restrict__ BhatH3,
                                                 _Float16* __restrict__ PfgH3,
                                                 float* __restrict__ rn3){
  const int t = threadIdx.x, c = t & 63, sub = t >> 6;
  const int l = blockIdx.x*4 + sub, z = blockIdx.y;
  const float* fgz = fgT + (size_t)z*L*64;
  const float* mz  = mask + (size_t)z*L;
  const int y = l >> 6, x = l & 63;
  float Wn[5][5];
  #pragma unroll
  for(int u=0;u<5;u++){
    const int yy = y+u-2;
    #pragma unroll
    for(int v=0;v<5;v++){
      const int xx = x+v-2;
      Wn[u][v] = (yy>=0 && yy<HH && xx>=0 && xx<WW) ? fgz[(size_t)(yy*WW+xx)*64 + c] : 0.f;
    }
  }
  float m3[3][3];
  #pragma unroll
  for(int i=0;i<3;i++){
    #pragma unroll
    for(int j=0;j<3;j++){
      const int yy = y+i-1, xx = x+j-1;
      m3[i][j] = (yy>=0&&yy<HH&&xx>=0&&xx<WW) ? mz[yy*WW+xx] : 0.f;
    }
  }
  // ---- p1 ----
  {
    const float K1 = Wn[2][2]*(1.0f - m3[1][1]) + 1e-7f;
    const float ss = wave_sum(K1*K1);
    BhatH1[((size_t)z*L + l)*NC + c] = (_Float16)(K1*rsqrtf(ss));
    float s = 0.f;
    #pragma unroll
    for(int a=0;a<3;a++)
      #pragma unroll
      for(int b=0;b<3;b++) s += Wn[1+a][1+b];
    PfgH1[((size_t)z*L + l)*NC + c] = (_Float16)s;
  }
  // ---- p3 Bhat + rn3 ----
  {
    float K[9]; float ss = 0.f;
    #pragma unroll
    for(int i=0;i<3;i++)
      #pragma unroll
      for(int j=0;j<3;j++){
        const float v = Wn[1+i][1+j]*(1.0f - m3[i][j]) + 1e-7f;
        K[i*3+j] = v; ss += v*v;
      }
    ss = wave_sum(ss);
    const float rn = rsqrtf(ss);
    _Float16* outp = BhatH3 + ((size_t)z*L + l)*D3 + c*9;
    #pragma unroll
    for(int k=0;k<9;k++) outp[k] = (_Float16)(K[k]*rn);
    if(c==0) rn3[(size_t)z*L + l] = rn;
  }
  // ---- p3 PfgBox ----
  {
    const bool dyok[3] = { y-1>=0, true, y+1<HH };
    const bool dxok[3] = { x-1>=0, true, x+1<WW };
    _Float16* outp = PfgH3 + ((size_t)z*L + l)*D3 + c*9;
    #pragma unroll
    for(int i=0;i<3;i++)
      #pragma unroll
      for(int j=0;j<3;j++){
        float acc = 0.f;
        #pragma unroll
        for(int a=0;a<3;a++){
          if(!dyok[a]) continue;
          #pragma unroll
          for(int b=0;b<3;b++){
            if(!dxok[b]) continue;
            acc += Wn[i+a][j+b];
          }
        }
        outp[i*3+j] = (_Float16)acc;
      }
  }
}

__global__ __launch_bounds__(256) void transpose_h(const ushort* __restrict__ src,
                                                   ushort* __restrict__ dst,
                                                   int C, size_t sSz, size_t sDz){
  __shared__ ushort tile[64][65];
  const int z = blockIdx.z;
  src += z*sSz; dst += z*sDz;
  const int bc = blockIdx.x*64, br = blockIdx.y*64;
  const int tx = threadIdx.x & 15, ty = threadIdx.x >> 4;
  #pragma unroll
  for(int i=0;i<4;i++){
    const ushort4 v = *(const ushort4*)(src + (size_t)(br+ty+16*i)*C + bc + tx*4);
    tile[ty+16*i][tx*4+0] = v.x;
    tile[ty+16*i][tx*4+1] = v.y;
    tile[ty+16*i][tx*4+2] = v.z;
    tile[ty+16*i][tx*4+3] = v.w;
  }
  __syncthreads();
  #pragma unroll
  for(int i=0;i<4;i++){
    ushort4 o;
    o.x = tile[tx*4+0][ty+16*i];
    o.y = tile[tx*4+1][ty+16*i];
    o.z = tile[tx*4+2][ty+16*i];
    o.w = tile[tx*4+3][ty+16*i];
    *(ushort4*)(dst + (size_t)(bc+ty+16*i)*L + br + tx*4) = o;
  }
}

// ---------------- barrier-free per-wave flash attention (p=1) ----------------
// Each wave owns a 32-key strip per iteration with private LDS K/V/P, register M/L.
// Emits per-wave partials (O, M, Lsum); 16 partial sets per z.
__global__ __launch_bounds__(256) void flash_p1(const _Float16* __restrict__ Q,
                                                const _Float16* __restrict__ Km,
                                                const _Float16* __restrict__ Vt,
                                                float* __restrict__ Op,
                                                float* __restrict__ Ml,
                                                float* __restrict__ Ll){
  __shared__ _Float16 Qs[QB*64];        // 32 q rows x 128B, swz (row&7)<<4
  __shared__ _Float16 KsA[4][QB*64];    // per-wave: 32 l rows x 128B
  __shared__ _Float16 VsA[4][64*32];    // per-wave: 64 c rows x 64B, swz (c&3)<<4
  __shared__ _Float16 PsA[4][QB*32];    // per-wave: 32 q rows x 64B, swz (q&3)<<4
  __shared__ float    FwA[4][QB];
  const int z = blockIdx.z, sp = blockIdx.y, q0 = blockIdx.x*QB;
  const int t = threadIdx.x, lane = t&63, wave = t>>6;
  const int r16 = lane&15, g4 = lane>>4;
  _Float16* Ks = KsA[wave];
  _Float16* Vs = VsA[wave];
  _Float16* Ps = PsA[wave];
  float* Fw = FwA[wave];
  {
    const int row = t>>3, ch = t&7;
    gload16(Q + ((size_t)z*L + q0 + row)*64 + ((ch ^ (row&7))<<3), (char*)Qs + t*16);
  }
  asm volatile("s_waitcnt vmcnt(0)" ::: "memory");
  __syncthreads();    // Qs staged cooperatively -> one-time barrier

  float Mreg[2] = {-3.0e38f, -3.0e38f};
  float Lreg[2] = {0.f, 0.f};
  f32x4 accO[2][4] = {};

  for(int tt=0; tt<8; ++tt){
    const int lbase = sp*1024 + tt*128 + wave*32;
    #pragma unroll
    for(int u=0;u<4;u++){
      const int row = u*8 + (lane>>3), ch = lane&7;
      gload16(Km + ((size_t)z*L + lbase + row)*64 + ((ch ^ (row&7))<<3),
              (char*)Ks + u*1024 + lane*16);
    }
    #pragma unroll
    for(int u=0;u<4;u++){
      const int cst = u*16 + (lane>>2), slot = lane&3;
      gload16(Vt + ((size_t)z*64 + cst)*L + lbase + ((slot ^ (cst&3))<<3),
              (char*)Vs + u*1024 + lane*16);
    }
    asm volatile("s_waitcnt vmcnt(0)" ::: "memory");
    __builtin_amdgcn_sched_barrier(0);
    // S^T[32 l][32 q] = K_strip * Q^T
    f32x4 acc[2][2] = {};
    #pragma unroll
    for(int kk=0;kk<2;kk++){
      f16x8 af[2], bf[2];
      #pragma unroll
      for(int i=0;i<2;i++){
        const int row = i*16 + r16;
        af[i] = *(const f16x8*)((const char*)Ks + (((row<<7) + kk*64 + (g4<<4)) ^ ((row&7)<<4)));
      }
      #pragma unroll
      for(int j=0;j<2;j++){
        const int row = j*16 + r16;
        bf[j] = *(const f16x8*)((const char*)Qs + (((row<<7) + kk*64 + (g4<<4)) ^ ((row&7)<<4)));
      }
      #pragma unroll
      for(int i=0;i<2;i++)
        #pragma unroll
        for(int j=0;j<2;j++)
          acc[i][j] = __builtin_amdgcn_mfma_f32_16x16x32_f16(af[i], bf[j], acc[i][j], 0,0,0);
    }
    // per-lane online softmax over this wave's 32 l's (q = j*16 + r16)
    float fs[2];
    #pragma unroll
    for(int j=0;j<2;j++){
      float mv = -3.0e38f;
      #pragma unroll
      for(int i=0;i<2;i++)
        #pragma unroll
        for(int r=0;r<4;r++) mv = fmaxf(mv, acc[i][j][r]);
      mv = fmaxf(mv, __shfl_xor(mv, 16));
      mv = fmaxf(mv, __shfl_xor(mv, 32));
      const float mnew = fmaxf(Mreg[j], mv);
      fs[j] = __expf(Mreg[j] - mnew);
      Mreg[j] = mnew;
      float ps = 0.f;
      const int q = j*16 + r16;
      #pragma unroll
      for(int i=0;i<2;i++){
        f16x4 ph;
        #pragma unroll
        for(int r=0;r<4;r++){
          const float p = __expf(acc[i][j][r] - mnew);
          ps += p; ph[r] = (_Float16)p;
        }
        *(f16x4*)((char*)Ps + (q<<6) + ((i*32 + g4*8) ^ ((q&3)<<4))) = ph;
      }
      ps += __shfl_xor(ps, 16);
      ps += __shfl_xor(ps, 32);
      Lreg[j] = Lreg[j]*fs[j] + ps;
    }
    if(g4==0){ Fw[r16] = fs[0]; Fw[16+r16] = fs[1]; }
    // rescale accO (rows q = qb*16 + g4*4 + r)
    #pragma unroll
    for(int qb=0;qb<2;qb++){
      float f4[4];
      #pragma unroll
      for(int r=0;r<4;r++) f4[r] = Fw[qb*16 + g4*4 + r];
      #pragma unroll
      for(int cb=0;cb<4;cb++)
        #pragma unroll
        for(int r=0;r<4;r++) accO[qb][cb][r] *= f4[r];
    }
    // O += P * V^T (K=32)
    #pragma unroll
    for(int qb=0;qb<2;qb++){
      const int qrow = qb*16 + r16;
      const f16x8 af = *(const f16x8*)((const char*)Ps + (qrow<<6) + ((g4<<4) ^ ((qrow&3)<<4)));
      #pragma unroll
      for(int cb=0;cb<4;cb++){
        const int crow = cb*16 + r16;
        const f16x8 bf = *(const f16x8*)((const char*)Vs + (crow<<6) + ((g4<<4) ^ ((crow&3)<<4)));
        accO[qb][cb] = __builtin_amdgcn_mfma_f32_16x16x32_f16(af, bf, accO[qb][cb], 0,0,0);
      }
    }
  }
  const int sidx = (z*NSPLIT + sp)*4 + wave;   // 0..31 (16 per z)
  #pragma unroll
  for(int qb=0;qb<2;qb++){
    #pragma unroll
    for(int cb=0;cb<4;cb++){
      #pragma unroll
      for(int r=0;r<4;r++){
        const int ql = qb*16 + g4*4 + r;
        Op[((size_t)sidx*L + q0 + ql)*64 + cb*16 + r16] = accO[qb][cb][r];
      }
    }
  }
  if(g4==0){
    Ml[(size_t)sidx*L + q0 + r16]      = Mreg[0];
    Ml[(size_t)sidx*L + q0 + 16 + r16] = Mreg[1];
    Ll[(size_t)sidx*L + q0 + r16]      = Lreg[0];
    Ll[(size_t)sidx*L + q0 + 16 + r16] = Lreg[1];
  }
}

// combine 16 per-z partial sets + mask mix -> outs channels 0..63
__global__ __launch_bounds__(256) void flash_comb(const float* __restrict__ Op,
                                                  const float* __restrict__ Ml,
                                                  const float* __restrict__ Ll,
                                                  const float* __restrict__ fgT,
                                                  const float* __restrict__ mask,
                                                  float* __restrict__ outs){
  const int z = blockIdx.y, t = threadIdx.x;
  const int q = blockIdx.x*4 + (t>>6), c = t & 63;
  float mv[16];
  float ms = -3.0e38f;
  #pragma unroll
  for(int s=0;s<16;s++){
    mv[s] = Ml[(size_t)(z*16+s)*L + q];
    ms = fmaxf(ms, mv[s]);
  }
  float acc = 0.f, Lt = 0.f;
  #pragma unroll
  for(int s=0;s<16;s++){
    const float w0 = __expf(mv[s] - ms);
    acc += w0 * Op[((size_t)(z*16+s)*L + q)*64 + c];
    Lt  += w0 * Ll[(size_t)(z*16+s)*L + q];
  }
  const float o = acc/Lt;
  const float m = mask[(size_t)z*L + q];
  const float f = fgT[((size_t)z*L + q)*64 + c];
  outs[((size_t)z*L + q)*128 + c] = o*m + f*(1.0f-m);
}

// OM=0: f32 split-K partials; OM=2: fp16 out + LDS-transpose epilogue + XCD swizzle
template<int OM, int KS>
__global__ __launch_bounds__(256) void gemm_h16(const _Float16* __restrict__ A, int lda, size_t sAz,
                                                const _Float16* __restrict__ B, int ldb, size_t sBz,
                                                void* __restrict__ C, int ldc, size_t sCz,
                                                int K, size_t sPart){
  __shared__ _Float16 sh[17408];
  _Float16* As = sh;
  _Float16* Bs = sh + 8192;
  const int zz = blockIdx.z;
  const int z = zz / KS, ks = zz % KS;
  const int Kp = K / KS;
  A += (size_t)z*sAz + (size_t)ks*Kp;
  B += (size_t)z*sBz + (size_t)ks*Kp;
  int bxi = blockIdx.x, byi = blockIdx.y;
  if(OM==2){
    // bijective XCD swizzle over the 32x32 plane (1024 % 8 == 0)
    const int b = byi*32 + bxi;
    const int s = ((b&7)<<7) + (b>>3);
    bxi = s & 31; byi = s >> 5;
  }
  const int bm = byi*128, bn = bxi*128;
  const int t = threadIdx.x, lane = t & 63, wave = t >> 6;
  const int wr = wave >> 1, wc = wave & 1;
  const int r16 = lane & 15, g4 = lane >> 4;
  const int srow = t >> 3;
  const int schunk = t & 7;
  f32x4 acc[4][4] = {};
  for(int k0=0;k0<Kp;k0+=64){
    #pragma unroll
    for(int u=0;u<4;u++){
      const int rowA = u*32 + srow;
      const int colh = ((schunk ^ (rowA & 7)) << 3);
      gload16(A + (size_t)(bm+rowA)*lda + k0 + colh, (char*)As + u*4096 + wave*1024);
      gload16(B + (size_t)(bn+rowA)*ldb + k0 + colh, (char*)Bs + u*4096 + wave*1024);
    }
    __syncthreads();
    #pragma unroll
    for(int kk=0;kk<2;kk++){
      f16x8 af[4], bf[4];
      #pragma unroll
      for(int i=0;i<4;i++){
        const int row = wr*64 + i*16 + r16;
        const int off = ((row<<7) + kk*64 + (g4<<4)) ^ ((row&7)<<4);
        af[i] = *(const f16x8*)((const char*)As + off);
      }
      #pragma unroll
      for(int j=0;j<4;j++){
        const int row = wc*64 + j*16 + r16;
        const int off = ((row<<7) + kk*64 + (g4<<4)) ^ ((row&7)<<4);
        bf[j] = *(const f16x8*)((const char*)Bs + off);
      }
      #pragma unroll
      for(int i=0;i<4;i++)
        #pragma unroll
        for(int j=0;j<4;j++)
          acc[i][j] = __builtin_amdgcn_mfma_f32_16x16x32_f16(af[i], bf[j], acc[i][j], 0, 0, 0);
    }
    __syncthreads();
  }
  if(OM==0){
    float* Cz = (float*)C + (size_t)ks*sPart + (size_t)z*sCz;
    #pragma unroll
    for(int i=0;i<4;i++){
      const int row0 = bm + wr*64 + i*16 + g4*4;
      #pragma unroll
      for(int j=0;j<4;j++){
        const int col = bn + wc*64 + j*16 + r16;
        #pragma unroll
        for(int r=0;r<4;r++)
          Cz[(size_t)(row0+r)*ldc + col] = acc[i][j][r];
      }
    }
  } else {
    _Float16* Cz = (_Float16*)C + (size_t)z*sCz;
    #pragma unroll
    for(int i=0;i<4;i++){
      const int row0 = wr*64 + i*16 + g4*4;
      #pragma unroll
      for(int j=0;j<4;j++){
        const int col = wc*64 + j*16 + r16;
        #pragma unroll
        for(int r=0;r<4;r++)
          sh[(row0+r)*136 + col] = (_Float16)acc[i][j][r];
      }
    }
    __syncthreads();
    #pragma unroll
    for(int k=0;k<8;k++){
      const int row = k*16 + (t>>4);
      const int cg = (t&15)*8;
      const f16x8 v = *(const f16x8*)(sh + row*136 + cg);
      *(f16x8*)(Cz + (size_t)(bm+row)*ldc + bn + cg) = v;
    }
  }
}

__global__ __launch_bounds__(256) void softmax_rn(_Float16* __restrict__ S,
                                                  const float* __restrict__ rn3,
                                                  float* __restrict__ Tq){
  __shared__ float red[4];
  const int q = blockIdx.x, z = blockIdx.y, t = threadIdx.x;
  _Float16* p = S + ((size_t)z*L + q)*L;
  float v[16];
  {
    const f16x8 a = *(const f16x8*)(p + t*16);
    const f16x8 b = *(const f16x8*)(p + t*16 + 8);
    #pragma unroll
    for(int i=0;i<8;i++){ v[i] = (float)a[i]; v[8+i] = (float)b[i]; }
  }
  float mx = -3.0e38f;
  #pragma unroll
  for(int i=0;i<16;i++) mx = fmaxf(mx, v[i]);
  mx = wave_max(mx);
  if((t&63)==0) red[t>>6]=mx;
  __syncthreads();
  mx = fmaxf(fmaxf(red[0],red[1]), fmaxf(red[2],red[3]));
  __syncthreads();
  float s = 0.f;
  #pragma unroll
  for(int i=0;i<16;i++){ v[i] = __expf(v[i]-mx); s += v[i]; }
  s = wave_sum(s);
  if((t&63)==0) red[t>>6]=s;
  __syncthreads();
  s = red[0]+red[1]+red[2]+red[3];
  __syncthreads();
  const float inv = 1.0f/s;
  const float* rnz = rn3 + (size_t)z*L + t*16;
  float T = 0.f;
  f16x8 a, b;
  #pragma unroll
  for(int i=0;i<8;i++){
    const float w0 = v[i]*inv*rnz[i];
    const float w1 = v[8+i]*inv*rnz[8+i];
    T += w0 + w1;
    a[i] = (_Float16)(w0*ASCALE);
    b[i] = (_Float16)(w1*ASCALE);
  }
  *(f16x8*)(p + t*16) = a;
  *(f16x8*)(p + t*16 + 8) = b;
  T = wave_sum(T);
  if((t&63)==0) red[t>>6]=T;
  __syncthreads();
  if(t==0) Tq[(size_t)z*L + q] = red[0]+red[1]+red[2]+red[3];
}

__global__ __launch_bounds__(256) void d9_pass(const _Float16* __restrict__ in,
                                               _Float16* __restrict__ out){
  __shared__ _Float16 slab[128 + 9*4096 + 128];
  _Float16* rows = slab + 128;
  const int b = blockIdx.x, z = blockIdx.y, t = threadIdx.x;
  const int a = (b&7)*512 + (b>>3);
  const int ya = a>>6, xa = a&63;
  const int DY[9] = {-1,-1,-1, 0,0,0, 1,1,1};
  const int DX[9] = {-1, 0, 1,-1,0,1,-1,0,1};
  bool vr[9];
  #pragma unroll
  for(int k=0;k<9;k++){
    const int yy = ya + DY[k], xx = xa + DX[k];
    vr[k] = (yy>=0 && yy<64 && xx>=0 && xx<64);
    if(vr[k]){
      const int srow = a + DY[k]*64 + DX[k];
      const _Float16* src = in + ((size_t)z*L + srow)*L;
      gload16(src + t*8,        (char*)(rows + k*4096) + t*16);
      gload16(src + 2048 + t*8, (char*)(rows + k*4096) + 4096 + t*16);
    }
  }
  __syncthreads();
  const int m0 = t*16;
  const int ym = m0>>6, x0 = m0&63;
  float o[16] = {0,0,0,0,0,0,0,0,0,0,0,0,0,0,0,0};
  #pragma unroll
  for(int k=0;k<9;k++){
    const int D = DY[k]*64 + DX[k];
    const bool vy = vr[k] && ((unsigned)(ym + DY[k]) < 64u);
    if(!vy) continue;
    const int r = ((D % 8) + 8) % 8;
    const _Float16* A0p = rows + k*4096 + (m0 + D - r);
    _Float16 buf[24];
    *(f16x8*)(buf)    = *(const f16x8*)(A0p);
    *(f16x8*)(buf+8)  = *(const f16x8*)(A0p+8);
    *(f16x8*)(buf+16) = *(const f16x8*)(A0p+16);
    #pragma unroll
    for(int i=0;i<16;i++){
      const bool vx = (unsigned)(x0 + i + DX[k]) < 64u;
      o[i] += vx ? (float)buf[r + i] : 0.f;
    }
  }
  f16x8 w0, w1;
  #pragma unroll
  for(int i=0;i<8;i++){ w0[i] = (_Float16)o[i]; w1[i] = (_Float16)o[8+i]; }
  _Float16* op = out + ((size_t)z*L + a)*L + m0;
  *(f16x8*)op = w0;
  *(f16x8*)(op+8) = w1;
}

__global__ __launch_bounds__(256) void scatter_p3n(const float* __restrict__ Cp,
                                                   const float* __restrict__ Tq,
                                                   const float* __restrict__ fgT,
                                                   const float* __restrict__ mask,
                                                   float* __restrict__ outs,
                                                   size_t sPart){
  const int z = blockIdx.y, t = threadIdx.x;
  const int q = blockIdx.x*4 + (t>>6), c = t & 63;
  const int y = q >> 6, x = q & 63;
  const size_t idx = ((size_t)z*L + q)*128 + c;
  float rec = 0.f;
  #pragma unroll
  for(int k=0;k<8;k++) rec += Cp[(size_t)k*sPart + idx];
  float tb = 0.f;
  #pragma unroll
  for(int dy=-1;dy<=1;dy++){
    const int yy = y+dy;
    if(yy<0||yy>=64) continue;
    #pragma unroll
    for(int dx=-1;dx<=1;dx++){
      const int xx = x+dx;
      if(xx<0||xx>=64) continue;
      tb += Tq[(size_t)z*L + yy*64+xx];
    }
  }
  const float m = mask[(size_t)z*L + q];
  rec += 1e-7f*tb;
  const float f = fgT[((size_t)z*L + q)*64 + c];
  outs[((size_t)z*L + q)*128 + 64 + c] = rec*(m*(1.0f/9.0f)) + f*(1.0f-m);
}

__global__ __launch_bounds__(256) void se_partial(const float* __restrict__ outs,
                                                  float* __restrict__ part){
  const int z = blockIdx.y, t = threadIdx.x;
  const int ch = t & 127, h = t >> 7;
  const int qb = blockIdx.x*128 + h*64;
  float s = 0.f;
  for(int j=0;j<64;j++) s += outs[((size_t)z*L + qb + j)*128 + ch];
  part[((size_t)z*64 + blockIdx.x*2 + h)*128 + ch] = s;
}

__global__ __launch_bounds__(128) void se_mlp(const float* __restrict__ part,
                                              const float* __restrict__ W1, const float* __restrict__ b1,
                                              const float* __restrict__ W2, const float* __restrict__ b2,
                                              float* __restrict__ g){
  __shared__ float s[128], h[128];
  const int z = blockIdx.x, i = threadIdx.x;
  float acc0 = 0.f;
  for(int j=0;j<64;j++) acc0 += part[((size_t)z*64 + j)*128 + i];
  s[i] = acc0*(1.0f/4096.0f);
  __syncthreads();
  float a = b1[i];
  const float* w = W1 + (size_t)i*128;
  for(int j=0;j<128;j++) a = fmaf(w[j], s[j], a);
  h[i] = fmaxf(a, 0.f);
  __syncthreads();
  float o = b2[i];
  w = W2 + (size_t)i*128;
  for(int j=0;j<128;j++) o = fmaf(w[j], h[j], o);
  g[z*128+i] = 1.0f/(1.0f + __expf(-o));
}

__global__ __launch_bounds__(256) void combiner(const float* __restrict__ outs,
                                                const float* __restrict__ g,
                                                const float* __restrict__ Wc,
                                                const float* __restrict__ bc,
                                                float* __restrict__ out){
  const size_t idx = (size_t)blockIdx.x*256 + threadIdx.x;
  const int q = (int)(idx & 4095);
  const int o = (int)((idx >> 12) & 63);
  const int z = (int)(idx >> 18);
  const float* ob = outs + ((size_t)z*L + q)*128;
  const float* gz = g + z*128;
  const float* wr = Wc + (size_t)o*128;
  float acc = bc[o];
  for(int ch=0; ch<128; ++ch) acc = fmaf(ob[ch]*gz[ch], wr[ch], acc);
  out[idx] = acc;
}

extern "C" void kernel_launch(void* const* d_in, const int* in_sizes, int n_in,
                              void* d_out, int out_size, void* d_ws, size_t ws_size,
                              hipStream_t stream){
  const float* fg   = (const float*)d_in[0];
  const float* mask = (const float*)d_in[1];
  const float* W1   = (const float*)d_in[2];
  const float* b1   = (const float*)d_in[3];
  const float* W2   = (const float*)d_in[4];
  const float* b2   = (const float*)d_in[5];
  const float* Wc   = (const float*)d_in[6];
  const float* bc   = (const float*)d_in[7];
  float* out = (float*)d_out;

  char* w = (char*)d_ws;
  size_t off = 0;
  auto alloc = [&](size_t bytes)->void*{
    void* p = (void*)(w + off);
    off += (bytes + 255) & ~(size_t)255;
    return p;
  };
  _Float16* S    = (_Float16*)alloc(2ull*L*L*2);   // p3 scores / A''
  _Float16* DxB  = (_Float16*)alloc(2ull*L*L*2);   // d9 output G
  float* Cp    = (float*)alloc(8ull*2*L*128*4);    // split-K partials (p3 PV)
  float* outs  = (float*)alloc(2ull*L*128*4);
  float* fgT   = (float*)alloc(2ull*L*64*4);
  _Float16* BhatH1 = (_Float16*)alloc(2ull*L*64*2);
  _Float16* BhatT1 = (_Float16*)alloc(2ull*64*L*2);
  _Float16* PfgH1  = (_Float16*)alloc(2ull*L*64*2);
  _Float16* BhatH3 = (_Float16*)alloc(2ull*L*D3*2);
  _Float16* PfgH3  = (_Float16*)alloc(2ull*L*D3*2);
  _Float16* bgH    = (_Float16*)alloc(2ull*128*L*2);
  float* Opb  = (float*)alloc((size_t)32*L*64*4);  // 16 partial sets per z
  float* Mlb  = (float*)alloc((size_t)32*L*4);
  float* Llb  = (float*)alloc((size_t)32*L*4);
  float* rn3v = (float*)alloc(2ull*L*4);
  float* Tq   = (float*)alloc(2ull*L*4);
  float* part = (float*)alloc(2ull*64*128*4);
  float* gbuf = (float*)alloc(1024);
  const size_t sPart = 2ull*L*128;

  transpose_fg<<<dim3(64,2),256,0,stream>>>(fg, fgT);

  // ================= builders (fused) =================
  build_all<<<dim3(L/4,2),256,0,stream>>>(fgT, mask, BhatH1, PfgH1, BhatH3, PfgH3, rn3v);
  transpose_h<<<dim3(1,64,2),256,0,stream>>>((const ushort*)BhatH1, (ushort*)BhatT1,
                                             64, (size_t)L*64, (size_t)64*L);
  bg_build<<<dim3(128,2),256,0,stream>>>(fg, mask, bgH);

  // ================= p=1 branch (barrier-free flash, 16-way split) =================
  flash_p1<<<dim3(L/QB,NSPLIT,2),256,0,stream>>>(PfgH1, BhatH1, BhatT1, Opb, Mlb, Llb);
  flash_comb<<<dim3(L/4,2),256,0,stream>>>(Opb, Mlb, Llb, fgT, mask, outs);

  // ================= p=3 branch =================
  gemm_h16<2,1><<<dim3(32,32,2),256,0,stream>>>(
      PfgH3, D3, (size_t)L*D3,
      BhatH3, D3, (size_t)L*D3,
      (void*)S, L, (size_t)L*L, D3, 0);
  softmax_rn<<<dim3(L,2),256,0,stream>>>(S, rn3v, Tq);
  d9_pass<<<dim3(L,2),256,0,stream>>>(S, DxB);
  gemm_h16<0,8><<<dim3(1,32,16),256,0,stream>>>(
      DxB, L, (size_t)L*L,
      bgH, L, (size_t)128*L,
      (void*)Cp, 128, (size_t)L*128, L, sPart);
  scatter_p3n<<<dim3(L/4,2),256,0,stream>>>(Cp, Tq, fgT, mask, outs, sPart);

  // ================= SE + combiner =================
  se_partial<<<dim3(32,2),256,0,stream>>>(outs, part);
  se_mlp<<<2,128,0,stream>>>(part, W1, b1, W2, b2, gbuf);
  combiner<<<(2*64*L)/256,256,0,stream>>>(outs, gbuf, Wc, bc, out);
}

// Round 12
// 256.503 us; speedup vs baseline: 3.4127x; 1.0403x over previous
//
#include <hip/hip_runtime.h>
#include <math.h>

#define WW 64
#define HH 64
#define L 4096
#define NC 64
#define D3 576
#define ASCALE (1.0f/128.0f)
#define QB 32
#define NSPLIT 4          // key-slices per z; 4 waves each -> 16 partial sets per z
#define D9W 2200          // staged cols per row-half (2192 used + pad)

typedef _Float16 f16x8 __attribute__((ext_vector_type(8)));
typedef _Float16 f16x4 __attribute__((ext_vector_type(4)));
typedef float    f32x4 __attribute__((ext_vector_type(4)));

__device__ __forceinline__ float wave_max(float v){
  #pragma unroll
  for(int o=32;o;o>>=1) v = fmaxf(v, __shfl_xor(v,o));
  return v;
}
__device__ __forceinline__ float wave_sum(float v){
  #pragma unroll
  for(int o=32;o;o>>=1) v += __shfl_xor(v,o);
  return v;
}
__device__ __forceinline__ void gload16(const void* g, void* l){
  __builtin_amdgcn_global_load_lds((const __attribute__((address_space(1))) unsigned int*)g,
                                   (__attribute__((address_space(3))) unsigned int*)l,
                                   16, 0, 0);
}

__global__ __launch_bounds__(256) void transpose_fg(const float* __restrict__ fg,
                                                    float* __restrict__ fgT){
  __shared__ float tile[64][65];
  const int z = blockIdx.y;
  const int q0 = blockIdx.x*64;
  const int tx = threadIdx.x & 63, ty = threadIdx.x >> 6;
  #pragma unroll
  for(int i=0;i<16;i++){
    const int c = ty*16 + i;
    tile[c][tx] = fg[((size_t)z*64 + c)*L + q0 + tx];
  }
  __syncthreads();
  #pragma unroll
  for(int i=0;i<16;i++){
    const int q = ty*16 + i;
    fgT[((size_t)z*L + q0 + q)*64 + tx] = tile[tx][q];
  }
}

__global__ __launch_bounds__(256) void bg_build(const float* __restrict__ fg,
                                                const float* __restrict__ mask,
                                                _Float16* __restrict__ bgH){
  const int row = blockIdx.x, z = blockIdx.y, t = threadIdx.x;
  const int l0 = t*16;
  f16x8 o0, o1;
  if(row < 64){
    const float* fp = fg + ((size_t)z*64 + row)*L + l0;
    const float* mp = mask + (size_t)z*L + l0;
    #pragma unroll
    for(int i=0;i<8;i++){
      o0[i] = (_Float16)(fp[i]*(1.0f-mp[i])*128.0f);
      o1[i] = (_Float16)(fp[8+i]*(1.0f-mp[8+i])*128.0f);
    }
  } else {
    #pragma unroll
    for(int i=0;i<8;i++){ o0[i]=(_Float16)0.f; o1[i]=(_Float16)0.f; }
  }
  _Float16* op = bgH + ((size_t)z*128 + row)*L + l0;
  *(f16x8*)op = o0;
  *(f16x8*)(op+8) = o1;
}

// ---------------- fused builder: p1 (Bhat,Pfg) + p3 (Bhat,rn3,PfgBox) ----------------
__global__ __launch_bounds__(256) void build_all(const float* __restrict__ fgT,
                                                 const float* __restrict__ mask,
                                                 _Float16* __restrict__ BhatH1,
                                                 _Float16* __restrict__ PfgH1,
                                                 _Float16* __restrict__ BhatH3,
                                                 _Float16* __restrict__ PfgH3,
                                                 float* __restrict__ rn3){
  const int t = threadIdx.x, c = t & 63, sub = t >> 6;
  const int l = blockIdx.x*4 + sub, z = blockIdx.y;
  const float* fgz = fgT + (size_t)z*L*64;
  const float* mz  = mask + (size_t)z*L;
  const int y = l >> 6, x = l & 63;
  float Wn[5][5];
  #pragma unroll
  for(int u=0;u<5;u++){
    const int yy = y+u-2;
    #pragma unroll
    for(int v=0;v<5;v++){
      const int xx = x+v-2;
      Wn[u][v] = (yy>=0 && yy<HH && xx>=0 && xx<WW) ? fgz[(size_t)(yy*WW+xx)*64 + c] : 0.f;
    }
  }
  float m3[3][3];
  #pragma unroll
  for(int i=0;i<3;i++){
    #pragma unroll
    for(int j=0;j<3;j++){
      const int yy = y+i-1, xx = x+j-1;
      m3[i][j] = (yy>=0&&yy<HH&&xx>=0&&xx<WW) ? mz[yy*WW+xx] : 0.f;
    }
  }
  // ---- p1 ----
  {
    const float K1 = Wn[2][2]*(1.0f - m3[1][1]) + 1e-7f;
    const float ss = wave_sum(K1*K1);
    BhatH1[((size_t)z*L + l)*NC + c] = (_Float16)(K1*rsqrtf(ss));
    float s = 0.f;
    #pragma unroll
    for(int a=0;a<3;a++)
      #pragma unroll
      for(int b=0;b<3;b++) s += Wn[1+a][1+b];
    PfgH1[((size_t)z*L + l)*NC + c] = (_Float16)s;
  }
  // ---- p3 Bhat + rn3 ----
  {
    float K[9]; float ss = 0.f;
    #pragma unroll
    for(int i=0;i<3;i++)
      #pragma unroll
      for(int j=0;j<3;j++){
        const float v = Wn[1+i][1+j]*(1.0f - m3[i][j]) + 1e-7f;
        K[i*3+j] = v; ss += v*v;
      }
    ss = wave_sum(ss);
    const float rn = rsqrtf(ss);
    _Float16* outp = BhatH3 + ((size_t)z*L + l)*D3 + c*9;
    #pragma unroll
    for(int k=0;k<9;k++) outp[k] = (_Float16)(K[k]*rn);
    if(c==0) rn3[(size_t)z*L + l] = rn;
  }
  // ---- p3 PfgBox ----
  {
    const bool dyok[3] = { y-1>=0, true, y+1<HH };
    const bool dxok[3] = { x-1>=0, true, x+1<WW };
    _Float16* outp = PfgH3 + ((size_t)z*L + l)*D3 + c*9;
    #pragma unroll
    for(int i=0;i<3;i++)
      #pragma unroll
      for(int j=0;j<3;j++){
        float acc = 0.f;
        #pragma unroll
        for(int a=0;a<3;a++){
          if(!dyok[a]) continue;
          #pragma unroll
          for(int b=0;b<3;b++){
            if(!dxok[b]) continue;
            acc += Wn[i+a][j+b];
          }
        }
        outp[i*3+j] = (_Float16)acc;
      }
  }
}

__global__ __launch_bounds__(256) void transpose_h(const ushort* __restrict__ src,
                                                   ushort* __restrict__ dst,
                                                   int C, size_t sSz, size_t sDz){
  __shared__ ushort tile[64][65];
  const int z = blockIdx.z;
  src += z*sSz; dst += z*sDz;
  const int bc = blockIdx.x*64, br = blockIdx.y*64;
  const int tx = threadIdx.x & 15, ty = threadIdx.x >> 4;
  #pragma unroll
  for(int i=0;i<4;i++){
    const ushort4 v = *(const ushort4*)(src + (size_t)(br+ty+16*i)*C + bc + tx*4);
    tile[ty+16*i][tx*4+0] = v.x;
    tile[ty+16*i][tx*4+1] = v.y;
    tile[ty+16*i][tx*4+2] = v.z;
    tile[ty+16*i][tx*4+3] = v.w;
  }
  __syncthreads();
  #pragma unroll
  for(int i=0;i<4;i++){
    ushort4 o;
    o.x = tile[tx*4+0][ty+16*i];
    o.y = tile[tx*4+1][ty+16*i];
    o.z = tile[tx*4+2][ty+16*i];
    o.w = tile[tx*4+3][ty+16*i];
    *(ushort4*)(dst + (size_t)(bc+ty+16*i)*L + br + tx*4) = o;
  }
}

// ---------------- barrier-free per-wave flash attention (p=1) ----------------
__global__ __launch_bounds__(256) void flash_p1(const _Float16* __restrict__ Q,
                                                const _Float16* __restrict__ Km,
                                                const _Float16* __restrict__ Vt,
                                                float* __restrict__ Op,
                                                float* __restrict__ Ml,
                                                float* __restrict__ Ll){
  __shared__ _Float16 Qs[QB*64];
  __shared__ _Float16 KsA[4][QB*64];
  __shared__ _Float16 VsA[4][64*32];
  __shared__ _Float16 PsA[4][QB*32];
  __shared__ float    FwA[4][QB];
  const int z = blockIdx.z, sp = blockIdx.y, q0 = blockIdx.x*QB;
  const int t = threadIdx.x, lane = t&63, wave = t>>6;
  const int r16 = lane&15, g4 = lane>>4;
  _Float16* Ks = KsA[wave];
  _Float16* Vs = VsA[wave];
  _Float16* Ps = PsA[wave];
  float* Fw = FwA[wave];
  {
    const int row = t>>3, ch = t&7;
    gload16(Q + ((size_t)z*L + q0 + row)*64 + ((ch ^ (row&7))<<3), (char*)Qs + t*16);
  }
  asm volatile("s_waitcnt vmcnt(0)" ::: "memory");
  __syncthreads();

  float Mreg[2] = {-3.0e38f, -3.0e38f};
  float Lreg[2] = {0.f, 0.f};
  f32x4 accO[2][4] = {};

  for(int tt=0; tt<8; ++tt){
    const int lbase = sp*1024 + tt*128 + wave*32;
    #pragma unroll
    for(int u=0;u<4;u++){
      const int row = u*8 + (lane>>3), ch = lane&7;
      gload16(Km + ((size_t)z*L + lbase + row)*64 + ((ch ^ (row&7))<<3),
              (char*)Ks + u*1024 + lane*16);
    }
    #pragma unroll
    for(int u=0;u<4;u++){
      const int cst = u*16 + (lane>>2), slot = lane&3;
      gload16(Vt + ((size_t)z*64 + cst)*L + lbase + ((slot ^ (cst&3))<<3),
              (char*)Vs + u*1024 + lane*16);
    }
    asm volatile("s_waitcnt vmcnt(0)" ::: "memory");
    __builtin_amdgcn_sched_barrier(0);
    f32x4 acc[2][2] = {};
    #pragma unroll
    for(int kk=0;kk<2;kk++){
      f16x8 af[2], bf[2];
      #pragma unroll
      for(int i=0;i<2;i++){
        const int row = i*16 + r16;
        af[i] = *(const f16x8*)((const char*)Ks + (((row<<7) + kk*64 + (g4<<4)) ^ ((row&7)<<4)));
      }
      #pragma unroll
      for(int j=0;j<2;j++){
        const int row = j*16 + r16;
        bf[j] = *(const f16x8*)((const char*)Qs + (((row<<7) + kk*64 + (g4<<4)) ^ ((row&7)<<4)));
      }
      #pragma unroll
      for(int i=0;i<2;i++)
        #pragma unroll
        for(int j=0;j<2;j++)
          acc[i][j] = __builtin_amdgcn_mfma_f32_16x16x32_f16(af[i], bf[j], acc[i][j], 0,0,0);
    }
    float fs[2];
    #pragma unroll
    for(int j=0;j<2;j++){
      float mv = -3.0e38f;
      #pragma unroll
      for(int i=0;i<2;i++)
        #pragma unroll
        for(int r=0;r<4;r++) mv = fmaxf(mv, acc[i][j][r]);
      mv = fmaxf(mv, __shfl_xor(mv, 16));
      mv = fmaxf(mv, __shfl_xor(mv, 32));
      const float mnew = fmaxf(Mreg[j], mv);
      fs[j] = __expf(Mreg[j] - mnew);
      Mreg[j] = mnew;
      float ps = 0.f;
      const int q = j*16 + r16;
      #pragma unroll
      for(int i=0;i<2;i++){
        f16x4 ph;
        #pragma unroll
        for(int r=0;r<4;r++){
          const float p = __expf(acc[i][j][r] - mnew);
          ps += p; ph[r] = (_Float16)p;
        }
        *(f16x4*)((char*)Ps + (q<<6) + ((i*32 + g4*8) ^ ((q&3)<<4))) = ph;
      }
      ps += __shfl_xor(ps, 16);
      ps += __shfl_xor(ps, 32);
      Lreg[j] = Lreg[j]*fs[j] + ps;
    }
    if(g4==0){ Fw[r16] = fs[0]; Fw[16+r16] = fs[1]; }
    #pragma unroll
    for(int qb=0;qb<2;qb++){
      float f4[4];
      #pragma unroll
      for(int r=0;r<4;r++) f4[r] = Fw[qb*16 + g4*4 + r];
      #pragma unroll
      for(int cb=0;cb<4;cb++)
        #pragma unroll
        for(int r=0;r<4;r++) accO[qb][cb][r] *= f4[r];
    }
    #pragma unroll
    for(int qb=0;qb<2;qb++){
      const int qrow = qb*16 + r16;
      const f16x8 af = *(const f16x8*)((const char*)Ps + (qrow<<6) + ((g4<<4) ^ ((qrow&3)<<4)));
      #pragma unroll
      for(int cb=0;cb<4;cb++){
        const int crow = cb*16 + r16;
        const f16x8 bf = *(const f16x8*)((const char*)Vs + (crow<<6) + ((g4<<4) ^ ((crow&3)<<4)));
        accO[qb][cb] = __builtin_amdgcn_mfma_f32_16x16x32_f16(af, bf, accO[qb][cb], 0,0,0);
      }
    }
  }
  const int sidx = (z*NSPLIT + sp)*4 + wave;
  #pragma unroll
  for(int qb=0;qb<2;qb++){
    #pragma unroll
    for(int cb=0;cb<4;cb++){
      #pragma unroll
      for(int r=0;r<4;r++){
        const int ql = qb*16 + g4*4 + r;
        Op[((size_t)sidx*L + q0 + ql)*64 + cb*16 + r16] = accO[qb][cb][r];
      }
    }
  }
  if(g4==0){
    Ml[(size_t)sidx*L + q0 + r16]      = Mreg[0];
    Ml[(size_t)sidx*L + q0 + 16 + r16] = Mreg[1];
    Ll[(size_t)sidx*L + q0 + r16]      = Lreg[0];
    Ll[(size_t)sidx*L + q0 + 16 + r16] = Lreg[1];
  }
}

__global__ __launch_bounds__(256) void flash_comb(const float* __restrict__ Op,
                                                  const float* __restrict__ Ml,
                                                  const float* __restrict__ Ll,
                                                  const float* __restrict__ fgT,
                                                  const float* __restrict__ mask,
                                                  float* __restrict__ outs){
  const int z = blockIdx.y, t = threadIdx.x;
  const int q = blockIdx.x*4 + (t>>6), c = t & 63;
  float mv[16];
  float ms = -3.0e38f;
  #pragma unroll
  for(int s=0;s<16;s++){
    mv[s] = Ml[(size_t)(z*16+s)*L + q];
    ms = fmaxf(ms, mv[s]);
  }
  float acc = 0.f, Lt = 0.f;
  #pragma unroll
  for(int s=0;s<16;s++){
    const float w0 = __expf(mv[s] - ms);
    acc += w0 * Op[((size_t)(z*16+s)*L + q)*64 + c];
    Lt  += w0 * Ll[(size_t)(z*16+s)*L + q];
  }
  const float o = acc/Lt;
  const float m = mask[(size_t)z*L + q];
  const float f = fgT[((size_t)z*L + q)*64 + c];
  outs[((size_t)z*L + q)*128 + c] = o*m + f*(1.0f-m);
}

// OM=2: fp16 output via LDS-transpose epilogue (KS=1)
// OM=3: fp16 split-K partials via LDS-transpose epilogue
template<int OM, int KS>
__global__ __launch_bounds__(256) void gemm_h16(const _Float16* __restrict__ A, int lda, size_t sAz,
                                                const _Float16* __restrict__ B, int ldb, size_t sBz,
                                                void* __restrict__ C, int ldc, size_t sCz,
                                                int K, size_t sPart){
  __shared__ _Float16 sh[17408];
  _Float16* As = sh;
  _Float16* Bs = sh + 8192;
  const int zz = blockIdx.z;
  const int z = zz / KS, ks = zz % KS;
  const int Kp = K / KS;
  A += (size_t)z*sAz + (size_t)ks*Kp;
  B += (size_t)z*sBz + (size_t)ks*Kp;
  const int bm = blockIdx.y*128, bn = blockIdx.x*128;
  const int t = threadIdx.x, lane = t & 63, wave = t >> 6;
  const int wr = wave >> 1, wc = wave & 1;
  const int r16 = lane & 15, g4 = lane >> 4;
  const int srow = t >> 3;
  const int schunk = t & 7;
  f32x4 acc[4][4] = {};
  for(int k0=0;k0<Kp;k0+=64){
    #pragma unroll
    for(int u=0;u<4;u++){
      const int rowA = u*32 + srow;
      const int colh = ((schunk ^ (rowA & 7)) << 3);
      gload16(A + (size_t)(bm+rowA)*lda + k0 + colh, (char*)As + u*4096 + wave*1024);
      gload16(B + (size_t)(bn+rowA)*ldb + k0 + colh, (char*)Bs + u*4096 + wave*1024);
    }
    __syncthreads();
    #pragma unroll
    for(int kk=0;kk<2;kk++){
      f16x8 af[4], bf[4];
      #pragma unroll
      for(int i=0;i<4;i++){
        const int row = wr*64 + i*16 + r16;
        const int off = ((row<<7) + kk*64 + (g4<<4)) ^ ((row&7)<<4);
        af[i] = *(const f16x8*)((const char*)As + off);
      }
      #pragma unroll
      for(int j=0;j<4;j++){
        const int row = wc*64 + j*16 + r16;
        const int off = ((row<<7) + kk*64 + (g4<<4)) ^ ((row&7)<<4);
        bf[j] = *(const f16x8*)((const char*)Bs + off);
      }
      #pragma unroll
      for(int i=0;i<4;i++)
        #pragma unroll
        for(int j=0;j<4;j++)
          acc[i][j] = __builtin_amdgcn_mfma_f32_16x16x32_f16(af[i], bf[j], acc[i][j], 0, 0, 0);
    }
    __syncthreads();
  }
  // LDS-transpose fp16 epilogue (OM=2 or OM=3)
  #pragma unroll
  for(int i=0;i<4;i++){
    const int row0 = wr*64 + i*16 + g4*4;
    #pragma unroll
    for(int j=0;j<4;j++){
      const int col = wc*64 + j*16 + r16;
      #pragma unroll
      for(int r=0;r<4;r++)
        sh[(row0+r)*136 + col] = (_Float16)acc[i][j][r];
    }
  }
  __syncthreads();
  _Float16* Cz = (_Float16*)C + (OM==2 ? (size_t)z*sCz
                                       : (size_t)ks*sPart + (size_t)z*sCz);
  #pragma unroll
  for(int k=0;k<8;k++){
    const int row = k*16 + (t>>4);
    const int cg = (t&15)*8;
    const f16x8 v = *(const f16x8*)(sh + row*136 + cg);
    *(f16x8*)(Cz + (size_t)(bm+row)*ldc + bn + cg) = v;
  }
}

__global__ __launch_bounds__(256) void softmax_rn(_Float16* __restrict__ S,
                                                  const float* __restrict__ rn3,
                                                  float* __restrict__ Tq){
  __shared__ float red[4];
  const int q = blockIdx.x, z = blockIdx.y, t = threadIdx.x;
  _Float16* p = S + ((size_t)z*L + q)*L;
  float v[16];
  {
    const f16x8 a = *(const f16x8*)(p + t*16);
    const f16x8 b = *(const f16x8*)(p + t*16 + 8);
    #pragma unroll
    for(int i=0;i<8;i++){ v[i] = (float)a[i]; v[8+i] = (float)b[i]; }
  }
  float mx = -3.0e38f;
  #pragma unroll
  for(int i=0;i<16;i++) mx = fmaxf(mx, v[i]);
  mx = wave_max(mx);
  if((t&63)==0) red[t>>6]=mx;
  __syncthreads();
  mx = fmaxf(fmaxf(red[0],red[1]), fmaxf(red[2],red[3]));
  __syncthreads();
  float s = 0.f;
  #pragma unroll
  for(int i=0;i<16;i++){ v[i] = __expf(v[i]-mx); s += v[i]; }
  s = wave_sum(s);
  if((t&63)==0) red[t>>6]=s;
  __syncthreads();
  s = red[0]+red[1]+red[2]+red[3];
  __syncthreads();
  const float inv = 1.0f/s;
  const float* rnz = rn3 + (size_t)z*L + t*16;
  float T = 0.f;
  f16x8 a, b;
  #pragma unroll
  for(int i=0;i<8;i++){
    const float w0 = v[i]*inv*rnz[i];
    const float w1 = v[8+i]*inv*rnz[8+i];
    T += w0 + w1;
    a[i] = (_Float16)(w0*ASCALE);
    b[i] = (_Float16)(w1*ASCALE);
  }
  *(f16x8*)(p + t*16) = a;
  *(f16x8*)(p + t*16 + 8) = b;
  T = wave_sum(T);
  if((t&63)==0) red[t>>6]=T;
  __syncthreads();
  if(t==0) Tq[(size_t)z*L + q] = red[0]+red[1]+red[2]+red[3];
}

// ---------------- 9-tap diagonal stencil, half-width staged (4 blocks/CU) --------
// Staging is FULL-EXEC with clamped global source (global_load_lds requires the
// first lane of each wave active so the uniform LDS base is correct).
__global__ __launch_bounds__(256) void d9_pass(const _Float16* __restrict__ in,
                                               _Float16* __restrict__ out){
  __shared__ _Float16 rows[9*D9W];
  const int bx = blockIdx.x, by = blockIdx.y, t = threadIdx.x;
  const int a = (bx&7)*512 + (bx>>3);
  const int z = by & 1, h = by >> 1;
  const int cbase = h*2048 - 72;
  const int ya = a>>6, xa = a&63;
  const int DY[9] = {-1,-1,-1, 0,0,0, 1,1,1};
  const int DX[9] = {-1, 0, 1,-1,0,1,-1,0,1};
  bool vr[9];
  #pragma unroll
  for(int k=0;k<9;k++){
    const int yy = ya + DY[k], xx = xa + DX[k];
    vr[k] = (yy>=0 && yy<64 && xx>=0 && xx<64);
    if(vr[k]){   // block-uniform condition: full wave exec inside
      const _Float16* src = in + ((size_t)z*L + a + DY[k]*64 + DX[k])*L;
      // full-exec, clamp source (slots for cols <0 / >=L are masked in compute)
      int g0 = cbase + t*8;
      g0 = g0 < 0 ? 0 : g0;
      gload16(src + g0, (char*)rows + k*(D9W*2) + t*16);
      // tail 18 chunks: leading lanes of wave 0 active (lane 0 active -> base ok)
      const int g1 = cbase + (256+t)*8;
      if(t < 18 && g1 < L)
        gload16(src + g1, (char*)rows + k*(D9W*2) + 4096 + t*16);
    }
  }
  __syncthreads();
  const int m0 = h*2048 + t*8;
  const int ym = m0>>6, x0 = m0&63;
  float o[8] = {0,0,0,0,0,0,0,0};
  #pragma unroll
  for(int k=0;k<9;k++){
    const int D = DY[k]*64 + DX[k];
    const bool vy = vr[k] && ((unsigned)(ym + DY[k]) < 64u);
    if(!vy) continue;
    const int r = ((D % 8) + 8) % 8;
    const int loff = t*8 + 72 + D - r;     // 16B-aligned staged offset
    const _Float16* p = rows + k*D9W + loff;
    _Float16 buf[16];
    *(f16x8*)(buf)   = *(const f16x8*)(p);
    *(f16x8*)(buf+8) = *(const f16x8*)(p+8);
    #pragma unroll
    for(int i=0;i<8;i++){
      const bool vx = (unsigned)(x0 + i + DX[k]) < 64u;
      o[i] += vx ? (float)buf[r + i] : 0.f;
    }
  }
  f16x8 w0;
  #pragma unroll
  for(int i=0;i<8;i++) w0[i] = (_Float16)o[i];
  *(f16x8*)(out + ((size_t)z*L + a)*L + m0) = w0;
}

__global__ __launch_bounds__(256) void scatter_p3n(const _Float16* __restrict__ Cp,
                                                   const float* __restrict__ Tq,
                                                   const float* __restrict__ fgT,
                                                   const float* __restrict__ mask,
                                                   float* __restrict__ outs,
                                                   size_t sPart){
  const int z = blockIdx.y, t = threadIdx.x;
  const int q = blockIdx.x*4 + (t>>6), c = t & 63;
  const int y = q >> 6, x = q & 63;
  const size_t idx = ((size_t)z*L + q)*128 + c;
  float rec = 0.f;
  #pragma unroll
  for(int k=0;k<8;k++) rec += (float)Cp[(size_t)k*sPart + idx];
  float tb = 0.f;
  #pragma unroll
  for(int dy=-1;dy<=1;dy++){
    const int yy = y+dy;
    if(yy<0||yy>=64) continue;
    #pragma unroll
    for(int dx=-1;dx<=1;dx++){
      const int xx = x+dx;
      if(xx<0||xx>=64) continue;
      tb += Tq[(size_t)z*L + yy*64+xx];
    }
  }
  const float m = mask[(size_t)z*L + q];
  rec += 1e-7f*tb;
  const float f = fgT[((size_t)z*L + q)*64 + c];
  outs[((size_t)z*L + q)*128 + 64 + c] = rec*(m*(1.0f/9.0f)) + f*(1.0f-m);
}

__global__ __launch_bounds__(256) void se_partial(const float* __restrict__ outs,
                                                  float* __restrict__ part){
  const int z = blockIdx.y, t = threadIdx.x;
  const int ch = t & 127, h = t >> 7;
  const int qb = blockIdx.x*128 + h*64;
  float s = 0.f;
  for(int j=0;j<64;j++) s += outs[((size_t)z*L + qb + j)*128 + ch];
  part[((size_t)z*64 + blockIdx.x*2 + h)*128 + ch] = s;
}

__global__ __launch_bounds__(128) void se_mlp(const float* __restrict__ part,
                                              const float* __restrict__ W1, const float* __restrict__ b1,
                                              const float* __restrict__ W2, const float* __restrict__ b2,
                                              float* __restrict__ g){
  __shared__ float s[128], h[128];
  const int z = blockIdx.x, i = threadIdx.x;
  float acc0 = 0.f;
  for(int j=0;j<64;j++) acc0 += part[((size_t)z*64 + j)*128 + i];
  s[i] = acc0*(1.0f/4096.0f);
  __syncthreads();
  float a = b1[i];
  const float* w = W1 + (size_t)i*128;
  for(int j=0;j<128;j++) a = fmaf(w[j], s[j], a);
  h[i] = fmaxf(a, 0.f);
  __syncthreads();
  float o = b2[i];
  w = W2 + (size_t)i*128;
  for(int j=0;j<128;j++) o = fmaf(w[j], h[j], o);
  g[z*128+i] = 1.0f/(1.0f + __expf(-o));
}

__global__ __launch_bounds__(256) void combiner(const float* __restrict__ outs,
                                                const float* __restrict__ g,
                                                const float* __restrict__ Wc,
                                                const float* __restrict__ bc,
                                                float* __restrict__ out){
  const size_t idx = (size_t)blockIdx.x*256 + threadIdx.x;
  const int q = (int)(idx & 4095);
  const int o = (int)((idx >> 12) & 63);
  const int z = (int)(idx >> 18);
  const float* ob = outs + ((size_t)z*L + q)*128;
  const float* gz = g + z*128;
  const float* wr = Wc + (size_t)o*128;
  float acc = bc[o];
  for(int ch=0; ch<128; ++ch) acc = fmaf(ob[ch]*gz[ch], wr[ch], acc);
  out[idx] = acc;
}

extern "C" void kernel_launch(void* const* d_in, const int* in_sizes, int n_in,
                              void* d_out, int out_size, void* d_ws, size_t ws_size,
                              hipStream_t stream){
  const float* fg   = (const float*)d_in[0];
  const float* mask = (const float*)d_in[1];
  const float* W1   = (const float*)d_in[2];
  const float* b1   = (const float*)d_in[3];
  const float* W2   = (const float*)d_in[4];
  const float* b2   = (const float*)d_in[5];
  const float* Wc   = (const float*)d_in[6];
  const float* bc   = (const float*)d_in[7];
  float* out = (float*)d_out;

  char* w = (char*)d_ws;
  size_t off = 0;
  auto alloc = [&](size_t bytes)->void*{
    void* p = (void*)(w + off);
    off += (bytes + 255) & ~(size_t)255;
    return p;
  };
  _Float16* S    = (_Float16*)alloc(2ull*L*L*2);   // p3 scores / A''
  _Float16* DxB  = (_Float16*)alloc(2ull*L*L*2);   // d9 output G
  _Float16* Cp16 = (_Float16*)alloc(8ull*2*L*128*2); // fp16 split-K partials
  float* outs  = (float*)alloc(2ull*L*128*4);
  float* fgT   = (float*)alloc(2ull*L*64*4);
  _Float16* BhatH1 = (_Float16*)alloc(2ull*L*64*2);
  _Float16* BhatT1 = (_Float16*)alloc(2ull*64*L*2);
  _Float16* PfgH1  = (_Float16*)alloc(2ull*L*64*2);
  _Float16* BhatH3 = (_Float16*)alloc(2ull*L*D3*2);
  _Float16* PfgH3  = (_Float16*)alloc(2ull*L*D3*2);
  _Float16* bgH    = (_Float16*)alloc(2ull*128*L*2);
  float* Opb  = (float*)alloc((size_t)32*L*64*4);
  float* Mlb  = (float*)alloc((size_t)32*L*4);
  float* Llb  = (float*)alloc((size_t)32*L*4);
  float* rn3v = (float*)alloc(2ull*L*4);
  float* Tq   = (float*)alloc(2ull*L*4);
  float* part = (float*)alloc(2ull*64*128*4);
  float* gbuf = (float*)alloc(1024);
  const size_t sPart = 2ull*L*128;   // elements per split (fp16)

  transpose_fg<<<dim3(64,2),256,0,stream>>>(fg, fgT);

  // ================= builders (fused) =================
  build_all<<<dim3(L/4,2),256,0,stream>>>(fgT, mask, BhatH1, PfgH1, BhatH3, PfgH3, rn3v);
  transpose_h<<<dim3(1,64,2),256,0,stream>>>((const ushort*)BhatH1, (ushort*)BhatT1,
                                             64, (size_t)L*64, (size_t)64*L);
  bg_build<<<dim3(128,2),256,0,stream>>>(fg, mask, bgH);

  // ================= p=1 branch (barrier-free flash, 16-way split) =================
  flash_p1<<<dim3(L/QB,NSPLIT,2),256,0,stream>>>(PfgH1, BhatH1, BhatT1, Opb, Mlb, Llb);
  flash_comb<<<dim3(L/4,2),256,0,stream>>>(Opb, Mlb, Llb, fgT, mask, outs);

  // ================= p=3 branch =================
  gemm_h16<2,1><<<dim3(32,32,2),256,0,stream>>>(
      PfgH3, D3, (size_t)L*D3,
      BhatH3, D3, (size_t)L*D3,
      (void*)S, L, (size_t)L*L, D3, 0);
  softmax_rn<<<dim3(L,2),256,0,stream>>>(S, rn3v, Tq);
  d9_pass<<<dim3(L,4),256,0,stream>>>(S, DxB);
  gemm_h16<3,8><<<dim3(1,32,16),256,0,stream>>>(
      DxB, L, (size_t)L*L,
      bgH, L, (size_t)128*L,
      (void*)Cp16, 128, (size_t)L*128, L, sPart);
  scatter_p3n<<<dim3(L/4,2),256,0,stream>>>(Cp16, Tq, fgT, mask, outs, sPart);

  // ================= SE + combiner =================
  se_partial<<<dim3(32,2),256,0,stream>>>(outs, part);
  se_mlp<<<2,128,0,stream>>>(part, W1, b1, W2, b2, gbuf);
  combiner<<<(2*64*L)/256,256,0,stream>>>(outs, gbuf, Wc, bc, out);
}